// Round 7
// baseline (368.946 us; speedup 1.0000x reference)
//
#include <hip/hip_runtime.h>
#include <math.h>

// GraphRespiratory: 2-layer GAT (edge features, concat=False) + factor graph.
// N=50000, E=800000, IN=128, HID=OUT=64, H=2, NC=5, EC=2, NUM_ITER=2, GAMMA=1.
//
// R6 changes vs R5:
//  - k_gemm_att: k-chunked LDS (25.6KB -> ~75% occupancy vs 17%), 64x128 block
//    tile, 8x4 register tile. Attention dots fused as 4 extra GEMM columns via
//    wext = W @ att^T (k_prep_wext). Epilogue emits h16 (bf16-packed) + asd
//    directly: k_att_nodes and the f32 h buffer are deleted.
//  - k_gat_pull: self-loop row from h16; phase-A alphas packed bf16x2 -> phase B
//    does 2 shuffles/edge instead of 3.

static inline int cdiv_i(long long a, long long b) { return (int)((a + b - 1) / b); }

#define BSH 8           // bucket shift: 256 nodes per bucket
#define CBK 8           // edges per thread in bucket scatter (2048/block)

__device__ __forceinline__ unsigned pack_bf2(float a, float b) {
  unsigned ua = __float_as_uint(a), ub = __float_as_uint(b);
  unsigned ra = (ua + 0x7fffu + ((ua >> 16) & 1u)) >> 16;
  unsigned rb = (ub + 0x7fffu + ((ub >> 16) & 1u)) & 0xffff0000u;
  return ra | rb;
}
__device__ __forceinline__ float bf_lo(unsigned v) { return __uint_as_float(v << 16); }
__device__ __forceinline__ float bf_hi(unsigned v) { return __uint_as_float(v & 0xffff0000u); }

// consts: [0..3] w_e1[h][k], [4..7] w_e2[h][k], [8] avg_ef, [9] avg_nf, [10] dbec
__global__ void k_prep_consts(const float* __restrict__ We1, const float* __restrict__ att_e1,
                              const float* __restrict__ We2, const float* __restrict__ att_e2,
                              const float* __restrict__ node_fw, const float* __restrict__ edge_fw,
                              const float* __restrict__ bec, float* __restrict__ consts) {
  if (blockIdx.x != 0 || threadIdx.x != 0) return;
  for (int h = 0; h < 2; ++h) {
    for (int k = 0; k < 2; ++k) {
      float s1 = 0.f, s2 = 0.f;
      for (int c = 0; c < 64; ++c) {
        s1 += We1[k * 128 + h * 64 + c] * att_e1[h * 64 + c];
        s2 += We2[k * 128 + h * 64 + c] * att_e2[h * 64 + c];
      }
      consts[h * 2 + k] = s1;
      consts[4 + h * 2 + k] = s2;
    }
  }
  float ef = 0.f;                      // edge_fw is [EC=2, NC=5]; mean of [1:,1:]
  for (int j = 1; j < 5; ++j) ef += edge_fw[5 + j];
  consts[8] = ef * 0.25f;
  float nf = 0.f;                      // node_fw is [NC=5, EC=2]; mean of [1:,1:]
  for (int i = 1; i < 5; ++i) nf += node_fw[i * 2 + 1];
  consts[9] = nf * 0.25f;
  consts[10] = bec[1] - bec[0];
}

// wext[k][ac]: ac 0/1 = att_src head0/1, 2/3 = att_dst head0/1. One block.
__global__ void k_prep_wext(const float* __restrict__ W1, const float* __restrict__ as1,
                            const float* __restrict__ ad1,
                            const float* __restrict__ W2, const float* __restrict__ as2,
                            const float* __restrict__ ad2,
                            float* __restrict__ wext1, float* __restrict__ wext2) {
  int t = threadIdx.x;
  for (int o = t; o < 128 * 4; o += 256) {
    int k = o >> 2, j = o & 3;
    const float* att = (j < 2 ? as1 : ad1) + (j & 1) * 64;
    const float* wr = W1 + k * 128 + (j & 1) * 64;
    float s = 0.f;
    for (int c = 0; c < 64; ++c) s += wr[c] * att[c];
    wext1[o] = s;
  }
  for (int o = t; o < 64 * 4; o += 256) {
    int k = o >> 2, j = o & 3;
    const float* att = (j < 2 ? as2 : ad2) + (j & 1) * 64;
    const float* wr = W2 + k * 128 + (j & 1) * 64;
    float s = 0.f;
    for (int c = 0; c < 64; ++c) s += wr[c] * att[c];
    wext2[o] = s;
  }
}

// ---- bucketed CSR build ----
__global__ void k_bkt_hist(const int* __restrict__ src, const int* __restrict__ dst,
                           int* __restrict__ hist_d, int* __restrict__ hist_s,
                           int nbkt, int E) {
  __shared__ int hd[256], hs[256];
  int t = threadIdx.x;
  hd[t] = 0; hs[t] = 0;
  __syncthreads();
  for (int e = blockIdx.x * blockDim.x + t; e < E; e += gridDim.x * blockDim.x) {
    atomicAdd(&hd[dst[e] >> BSH], 1);
    atomicAdd(&hs[src[e] >> BSH], 1);
  }
  __syncthreads();
  if (t < nbkt) {
    if (hd[t]) atomicAdd(&hist_d[t], hd[t]);
    if (hs[t]) atomicAdd(&hist_s[t], hs[t]);
  }
}

// one block: exclusive-scan both histograms -> bases (nbkt+1) and cursors (in place)
__global__ void k_bkt_scan(int* __restrict__ cur_d, int* __restrict__ base_d,
                           int* __restrict__ cur_s, int* __restrict__ base_s, int nbkt) {
  __shared__ int l[256];
  int t = threadIdx.x;
  int v = (t < nbkt) ? cur_d[t] : 0;
  l[t] = v; __syncthreads();
  for (int off = 1; off < 256; off <<= 1) {
    int x = (t >= off) ? l[t - off] : 0; __syncthreads();
    l[t] += x; __syncthreads();
  }
  int incl = l[t];
  if (t < nbkt) { base_d[t] = incl - v; cur_d[t] = incl - v; }
  if (t == nbkt - 1) base_d[nbkt] = incl;
  __syncthreads();
  v = (t < nbkt) ? cur_s[t] : 0;
  l[t] = v; __syncthreads();
  for (int off = 1; off < 256; off <<= 1) {
    int x = (t >= off) ? l[t - off] : 0; __syncthreads();
    l[t] += x; __syncthreads();
  }
  incl = l[t];
  if (t < nbkt) { base_s[t] = incl - v; cur_s[t] = incl - v; }
  if (t == nbkt - 1) base_s[nbkt] = incl;
}

// block-staged bucket scatter: 2048 edges/block in regs; LDS per-bucket counts;
// one global atomicAdd per (bucket,block) to reserve; chunky tail writes.
__global__ __launch_bounds__(256)
void k_bkt_scatter(const int* __restrict__ src, const int* __restrict__ dst,
                   const float* __restrict__ eattr2,
                   int* __restrict__ cur_d, int* __restrict__ cur_s,
                   int4* __restrict__ stage_d, int2* __restrict__ stage_s,
                   int nbkt, int E) {
  __shared__ int cd[256], cs[256], bd[256], bs[256];
  int t = threadIdx.x;
  cd[t] = 0; cs[t] = 0;
  __syncthreads();
  int base = blockIdx.x * 256 * CBK;
  int s[CBK], d[CBK]; unsigned ep[CBK];
#pragma unroll
  for (int c = 0; c < CBK; ++c) {
    int e = base + c * 256 + t;
    if (e < E) {
      s[c] = src[e]; d[c] = dst[e];
      float2 ev = *(const float2*)&eattr2[2 * e];
      ep[c] = pack_bf2(ev.x, ev.y);
      atomicAdd(&cd[d[c] >> BSH], 1);
      atomicAdd(&cs[s[c] >> BSH], 1);
    } else s[c] = -1;
  }
  __syncthreads();
  if (t < nbkt) {
    bd[t] = cd[t] ? atomicAdd(&cur_d[t], cd[t]) : 0;
    bs[t] = cs[t] ? atomicAdd(&cur_s[t], cs[t]) : 0;
    cd[t] = 0; cs[t] = 0;
  }
  __syncthreads();
#pragma unroll
  for (int c = 0; c < CBK; ++c) {
    if (s[c] < 0) continue;
    int db = d[c] >> BSH, sb = s[c] >> BSH;
    int pos = bd[db] + atomicAdd(&cd[db], 1);
    stage_d[pos] = make_int4(s[c], d[c], (int)ep[c], 0);
    int pos2 = bs[sb] + atomicAdd(&cs[sb], 1);
    stage_s[pos2] = make_int2(s[c], d[c]);
  }
}

// per-bucket counting sort (dst side): emits rowptr_d + final rec {src, bf16x2 eattr}.
__global__ __launch_bounds__(256)
void k_bkt_sort_d(const int4* __restrict__ stage, const int* __restrict__ base,
                  int* __restrict__ rowptr, int2* __restrict__ rec, int N) {
  int b = blockIdx.x, t = threadIdx.x;
  int nlo = b << BSH;
  int b0 = base[b], b1 = base[b + 1];
  __shared__ int cnt[256], cur[256], l[256];
  cnt[t] = 0;
  __syncthreads();
  for (int j = b0 + t; j < b1; j += 256)
    atomicAdd(&cnt[stage[j].y - nlo], 1);
  __syncthreads();
  int v = cnt[t];
  l[t] = v; __syncthreads();
  for (int off = 1; off < 256; off <<= 1) {
    int x = (t >= off) ? l[t - off] : 0; __syncthreads();
    l[t] += x; __syncthreads();
  }
  int excl = l[t] - v;
  if (nlo + t < N) rowptr[nlo + t] = b0 + excl;
  cur[t] = excl;
  __syncthreads();
  for (int j = b0 + t; j < b1; j += 256) {
    int4 r = stage[j];
    int pos = b0 + atomicAdd(&cur[r.y - nlo], 1);
    rec[pos] = make_int2(r.x, r.z);
  }
}

// per-bucket counting sort (src side): emits rowptr_s + srcnbr (payload = dst).
__global__ __launch_bounds__(256)
void k_bkt_sort_s(const int2* __restrict__ stage, const int* __restrict__ base,
                  int* __restrict__ rowptr, int* __restrict__ srcnbr, int N) {
  int b = blockIdx.x, t = threadIdx.x;
  int nlo = b << BSH;
  int b0 = base[b], b1 = base[b + 1];
  __shared__ int cnt[256], cur[256], l[256];
  cnt[t] = 0;
  __syncthreads();
  for (int j = b0 + t; j < b1; j += 256)
    atomicAdd(&cnt[stage[j].x - nlo], 1);
  __syncthreads();
  int v = cnt[t];
  l[t] = v; __syncthreads();
  for (int off = 1; off < 256; off <<= 1) {
    int x = (t >= off) ? l[t - off] : 0; __syncthreads();
    l[t] += x; __syncthreads();
  }
  int excl = l[t] - v;
  if (nlo + t < N) rowptr[nlo + t] = b0 + excl;
  cur[t] = excl;
  __syncthreads();
  for (int j = b0 + t; j < b1; j += 256) {
    int2 r = stage[j];
    int pos = b0 + atomicAdd(&cur[r.x - nlo], 1);
    srcnbr[pos] = r.y;
  }
}

// Fused GEMM + attention columns. A[N][K] f32, W[K][128] f32, wext[K][4].
// Block: 64 rows x 128 cols, 256 threads, 8x4 register tile, k-chunk 32.
// Outputs: h16[n][64] (bf16-packed head pairs), asd[n][4] = {as0,as1,ad0,ad1}.
template<int K>
__global__ __launch_bounds__(256)
void k_gemm_att(const float* __restrict__ A, const float* __restrict__ W,
                const float* __restrict__ wext,
                unsigned* __restrict__ h16, float* __restrict__ asd, int N) {
  constexpr int KC = 32;
  __shared__ float Al[64][KC + 2];   // +2 pad keeps float2 alignment, breaks bank stride
  __shared__ float Wl[KC][128];
  __shared__ float Wx[KC][4];
  int tid = threadIdx.x;
  int row0 = blockIdx.x * 64;
  int cg = tid & 31;                 // col group: cols c0, c0+1 (both heads)
  int rg = tid >> 5;                 // row group: rows rg*8 .. rg*8+7
  int c0 = cg * 2;
  int r_att = rg * 8 + (cg >> 2);    // block-local row for att duty
  int ac = cg & 3;                   // att column {as0,as1,ad0,ad1}
  float acc[8][4];
#pragma unroll
  for (int i = 0; i < 8; ++i)
#pragma unroll
    for (int j = 0; j < 4; ++j) acc[i][j] = 0.f;
  float aacc = 0.f;

  for (int kc = 0; kc < K; kc += KC) {
    for (int i = tid; i < 64 * (KC / 4); i += 256) {
      int r = i / (KC / 4), k4 = i % (KC / 4);
      int gr = row0 + r;
      float4 v = make_float4(0.f, 0.f, 0.f, 0.f);
      if (gr < N) v = *(const float4*)&A[(long long)gr * K + kc + k4 * 4];
      float* dp = &Al[r][k4 * 4];
      *(float2*)dp = make_float2(v.x, v.y);
      *(float2*)(dp + 2) = make_float2(v.z, v.w);
    }
    for (int i = tid; i < KC * 32; i += 256)
      *(float4*)&Wl[0][i * 4] = *(const float4*)&W[kc * 128 + i * 4];
    if (tid < KC * 4) Wx[tid >> 2][tid & 3] = wext[(kc + (tid >> 2)) * 4 + (tid & 3)];
    __syncthreads();
#pragma unroll
    for (int kk = 0; kk < KC; kk += 2) {
      float2 a[8];
#pragma unroll
      for (int i = 0; i < 8; ++i) a[i] = *(const float2*)&Al[rg * 8 + i][kk];
      float2 wA0 = *(const float2*)&Wl[kk][c0];
      float2 wB0 = *(const float2*)&Wl[kk][64 + c0];
      float2 wA1 = *(const float2*)&Wl[kk + 1][c0];
      float2 wB1 = *(const float2*)&Wl[kk + 1][64 + c0];
#pragma unroll
      for (int i = 0; i < 8; ++i) {
        acc[i][0] += a[i].x * wA0.x + a[i].y * wA1.x;   // (c0,   h0)
        acc[i][1] += a[i].x * wB0.x + a[i].y * wB1.x;   // (c0,   h1)
        acc[i][2] += a[i].x * wA0.y + a[i].y * wA1.y;   // (c0+1, h0)
        acc[i][3] += a[i].x * wB0.y + a[i].y * wB1.y;   // (c0+1, h1)
      }
      float2 av = *(const float2*)&Al[r_att][kk];
      aacc += av.x * Wx[kk][ac] + av.y * Wx[kk + 1][ac];
    }
    __syncthreads();
  }
#pragma unroll
  for (int i = 0; i < 8; ++i) {
    int gr = row0 + rg * 8 + i;
    if (gr < N) {
      uint2 u;
      u.x = pack_bf2(acc[i][0], acc[i][1]);
      u.y = pack_bf2(acc[i][2], acc[i][3]);
      *(uint2*)&h16[((long long)gr << 6) | c0] = u;
    }
  }
  int gra = row0 + r_att;
  if (gra < N) asd[4 * gra + ac] = aacc;
}

// Fused GAT edge phase, pull-mode. One wave per dst node.
// HEAD: fuse classification/edge heads into the epilogue (no emb store).
template<bool RELU, bool HEAD>
__global__ __launch_bounds__(256)
void k_gat_pull(const int* __restrict__ rowptr, const int2* __restrict__ rec,
                const float* __restrict__ asd, const unsigned* __restrict__ h16,
                const float* __restrict__ we, const float* __restrict__ bias,
                const float* __restrict__ Wn, const float* __restrict__ bn,
                const float* __restrict__ Wec,
                float* __restrict__ out, float* __restrict__ p_n,
                float* __restrict__ fgn, int N, int E) {
  int wv = threadIdx.x >> 6, lane = threadIdx.x & 63;
  int d = blockIdx.x * 4 + wv;
  if (d >= N) return;
  int r0 = rowptr[d];
  int r1 = (d + 1 < N) ? rowptr[d + 1] : E;
  int deg = r1 - r0;
  float4 Ad = *(const float4*)&asd[4 * d];
  float w0 = we[0], w1 = we[1], w2 = we[2], w3 = we[3];
  float den0 = 0.f, den1 = 0.f, acc0 = 0.f, acc1 = 0.f, se0 = 0.f, se1 = 0.f;
  for (int cb = 0; cb < deg; cb += 64) {
    int j = cb + lane;
    int s = 0; unsigned eapk = 0; float e0 = 0.f, e1 = 0.f, ea0 = 0.f, ea1 = 0.f;
    if (j < deg) {
      int2 rc = rec[r0 + j];
      s = rc.x;
      unsigned ep = (unsigned)rc.y;
      e0 = bf_lo(ep); e1 = bf_hi(ep);
      float4 As = *(const float4*)&asd[4 * s];
      float x0 = As.x + Ad.z + e0 * w0 + e1 * w1;
      float x1 = As.y + Ad.w + e0 * w2 + e1 * w3;
      x0 = x0 >= 0.f ? x0 : 0.2f * x0;
      x1 = x1 >= 0.f ? x1 : 0.2f * x1;
      ea0 = expf(x0); ea1 = expf(x1);
      eapk = pack_bf2(ea0, ea1);
    }
    float t0 = ea0, t1 = ea1, t2 = e0, t3 = e1;
    for (int off = 32; off; off >>= 1) {
      t0 += __shfl_xor(t0, off); t1 += __shfl_xor(t1, off);
      t2 += __shfl_xor(t2, off); t3 += __shfl_xor(t3, off);
    }
    den0 += t0; den1 += t1; se0 += t2; se1 += t3;
    int m = min(64, deg - cb);
    int j2 = 0;
    for (; j2 + 4 <= m; j2 += 4) {
      int s0 = __shfl(s, j2),     s1 = __shfl(s, j2 + 1);
      int s2 = __shfl(s, j2 + 2), s3 = __shfl(s, j2 + 3);
      unsigned p0 = __shfl(eapk, j2),     p1 = __shfl(eapk, j2 + 1);
      unsigned p2 = __shfl(eapk, j2 + 2), p3 = __shfl(eapk, j2 + 3);
      unsigned q0 = h16[((long long)s0 << 6) | lane];
      unsigned q1 = h16[((long long)s1 << 6) | lane];
      unsigned q2 = h16[((long long)s2 << 6) | lane];
      unsigned q3 = h16[((long long)s3 << 6) | lane];
      acc0 += bf_lo(p0) * bf_lo(q0); acc1 += bf_hi(p0) * bf_hi(q0);
      acc0 += bf_lo(p1) * bf_lo(q1); acc1 += bf_hi(p1) * bf_hi(q1);
      acc0 += bf_lo(p2) * bf_lo(q2); acc1 += bf_hi(p2) * bf_hi(q2);
      acc0 += bf_lo(p3) * bf_lo(q3); acc1 += bf_hi(p3) * bf_hi(q3);
    }
    for (; j2 < m; ++j2) {
      int sj = __shfl(s, j2);
      unsigned pj = __shfl(eapk, j2);
      unsigned q = h16[((long long)sj << 6) | lane];
      acc0 += bf_lo(pj) * bf_lo(q);
      acc1 += bf_hi(pj) * bf_hi(q);
    }
  }
  // self-loop: edge_attr = mean of incident (by dst) eattr; h row from h16.
  float id = 1.0f / fmaxf((float)deg, 1.0f);
  float le0 = se0 * id, le1 = se1 * id;
  float x0 = Ad.x + Ad.z + le0 * w0 + le1 * w1;
  float x1 = Ad.y + Ad.w + le0 * w2 + le1 * w3;
  x0 = x0 >= 0.f ? x0 : 0.2f * x0;
  x1 = x1 >= 0.f ? x1 : 0.2f * x1;
  float eas0 = expf(x0), eas1 = expf(x1);
  den0 += eas0; den1 += eas1;
  unsigned qd = h16[((long long)d << 6) | lane];
  acc0 += eas0 * bf_lo(qd);
  acc1 += eas1 * bf_hi(qd);
  float v = 0.5f * (acc0 / (den0 + 1e-16f) + acc1 / (den1 + 1e-16f)) + bias[lane];
  if (HEAD) {
    float pv[7];
#pragma unroll
    for (int j = 0; j < 5; ++j) pv[j] = v * Wn[lane * 5 + j];
    pv[5] = v * Wec[lane * 2];
    pv[6] = v * Wec[lane * 2 + 1];
    for (int off = 32; off; off >>= 1) {
#pragma unroll
      for (int j = 0; j < 7; ++j) pv[j] += __shfl_down(pv[j], off);
    }
    if (lane == 0) {
      float l[5]; float m = -1e30f;
#pragma unroll
      for (int j = 0; j < 5; ++j) { l[j] = pv[j] + bn[j]; m = fmaxf(m, l[j]); }
      float ssum = 0.f;
#pragma unroll
      for (int j = 0; j < 5; ++j) { l[j] = expf(l[j] - m); ssum += l[j]; }
      float inv = 1.0f / ssum;
#pragma unroll
      for (int j = 0; j < 5; ++j) p_n[5 * d + j] = l[j] * inv;
      fgn[4 * d]     = pv[6] - pv[5];          // q = r1 - r0
      fgn[4 * d + 1] = (ssum - l[0]) * inv;    // nab0 = 1 - p_n[:,0]
      fgn[4 * d + 2] = 0.f;
      fgn[4 * d + 3] = 0.f;
    }
  } else {
    if (RELU) v = fmaxf(v, 0.f);
    out[(long long)d * 64 + lane] = v;
  }
}

// eab after iteration chain: 1 / (1 + exp(-t)/c), c = prod of factors.
__device__ __forceinline__ float fg_eab(float t, float c) {
  return 1.0f / (1.0f + expf(-t) / c);
}

// factor-graph node-pull iteration. One thread per node.
template<int ITER>
__global__ void k_fg_pull(const int* __restrict__ rowptr_d, const int2* __restrict__ rec,
                          const int* __restrict__ rowptr_s, const int* __restrict__ srcnbr,
                          float* __restrict__ p_n, float* __restrict__ fgn,
                          const float* __restrict__ consts, float* __restrict__ out_n,
                          int N, int E) {
  int n = blockIdx.x * blockDim.x + threadIdx.x;
  if (n >= N) return;
  float4 F = *(const float4*)&fgn[4 * n];
  float q = F.x, nab0 = F.y, nab1 = F.z;
  float avg_ef = consts[8], avg_nf = consts[9], dbec = consts[10];
  int rd0 = rowptr_d[n], rd1 = (n + 1 < N) ? rowptr_d[n + 1] : E;
  int rs0 = rowptr_s[n], rs1 = (n + 1 < N) ? rowptr_s[n + 1] : E;
  float s_eab = 0.f;
  for (int j = rd0; j < rd1; ++j) {
    float4 Fo = *(const float4*)&fgn[4 * rec[j].x];
    float t = 0.5f * (q + Fo.x) + dbec;
    float c = 1.0f + fmaxf(nab0, Fo.y) * avg_ef;
    if (ITER == 2) c *= 1.0f + fmaxf(nab1, Fo.z) * avg_ef;
    s_eab += fg_eab(t, c);
  }
  for (int j = rs0; j < rs1; ++j) {
    float4 Fo = *(const float4*)&fgn[4 * srcnbr[j]];
    float t = 0.5f * (q + Fo.x) + dbec;
    float c = 1.0f + fmaxf(nab0, Fo.y) * avg_ef;
    if (ITER == 2) c *= 1.0f + fmaxf(nab1, Fo.z) * avg_ef;
    s_eab += fg_eab(t, c);
  }
  float deg = (float)((rd1 - rd0) + (rs1 - rs0));
  float mean = s_eab / (deg + 1e-6f);
  float f = 1.0f + mean * avg_nf;
  float p0 = p_n[5 * n], p1 = p_n[5 * n + 1], p2 = p_n[5 * n + 2],
        p3 = p_n[5 * n + 3], p4 = p_n[5 * n + 4];
  float rest = (p1 + p2 + p3 + p4) * f;
  float inv = 1.0f / (p0 + rest);
  if (ITER == 1) {
    p_n[5 * n]     = p0 * inv;
    p_n[5 * n + 1] = p1 * f * inv;
    p_n[5 * n + 2] = p2 * f * inv;
    p_n[5 * n + 3] = p3 * f * inv;
    p_n[5 * n + 4] = p4 * f * inv;
    fgn[4 * n + 2] = rest * inv;   // nab1 = 1 - p0'
  } else {
    out_n[5 * n]     = logf(p0 * inv + 1e-9f);
    out_n[5 * n + 1] = logf(p1 * f * inv + 1e-9f);
    out_n[5 * n + 2] = logf(p2 * f * inv + 1e-9f);
    out_n[5 * n + 3] = logf(p3 * f * inv + 1e-9f);
    out_n[5 * n + 4] = logf(p4 * f * inv + 1e-9f);
  }
}

// final edge output: recompute full odds-chain, write log p_e^2. Coalesced.
__global__ void k_fg_edge_out(const int* __restrict__ src, const int* __restrict__ dst,
                              const float* __restrict__ fgn, const float* __restrict__ consts,
                              float* __restrict__ out_e, int E) {
  int e = blockIdx.x * blockDim.x + threadIdx.x;
  if (e >= E) return;
  float avg_ef = consts[8], dbec = consts[10];
  float4 Fs = *(const float4*)&fgn[4 * src[e]];
  float4 Fd = *(const float4*)&fgn[4 * dst[e]];
  float t = 0.5f * (Fs.x + Fd.x) + dbec;
  float c = (1.0f + fmaxf(Fs.y, Fd.y) * avg_ef) * (1.0f + fmaxf(Fs.z, Fd.z) * avg_ef);
  float pe1 = 1.0f / (1.0f + expf(-t) / c);
  float pe0 = 1.0f / (1.0f + c * expf(t));
  *(float2*)&out_e[2 * e] = make_float2(logf(pe0 + 1e-9f), logf(pe1 + 1e-9f));
}

extern "C" void kernel_launch(void* const* d_in, const int* in_sizes, int n_in,
                              void* d_out, int out_size, void* d_ws, size_t ws_size,
                              hipStream_t stream) {
  const float* x      = (const float*)d_in[0];
  const int*   ei     = (const int*)d_in[1];
  const float* eattr  = (const float*)d_in[2];
  const float* W1     = (const float*)d_in[3];
  const float* atts1  = (const float*)d_in[4];
  const float* attd1  = (const float*)d_in[5];
  const float* We1    = (const float*)d_in[6];
  const float* atte1  = (const float*)d_in[7];
  const float* b1     = (const float*)d_in[8];
  const float* W2     = (const float*)d_in[9];
  const float* atts2  = (const float*)d_in[10];
  const float* attd2  = (const float*)d_in[11];
  const float* We2    = (const float*)d_in[12];
  const float* atte2  = (const float*)d_in[13];
  const float* b2     = (const float*)d_in[14];
  const float* Wn     = (const float*)d_in[15];
  const float* bn     = (const float*)d_in[16];
  const float* Wec    = (const float*)d_in[17];
  const float* bec    = (const float*)d_in[18];
  const float* nodefw = (const float*)d_in[19];
  const float* edgefw = (const float*)d_in[20];

  const int N = in_sizes[0] / 128;
  const int E = in_sizes[1] / 2;
  const int* src = ei;
  const int* dst = ei + E;
  const int nbkt = (N + 255) >> BSH;   // 196 (assumes N <= 65536)

  float* out_n = (float*)d_out;
  float* out_e = out_n + (long long)N * 5;

  // ---- workspace carve (f32 units, 16B aligned) ----
  size_t off = 0;
  float* base = (float*)d_ws;
  auto carve = [&](size_t nelem) { float* p = base + off; off += (nelem + 3) & ~(size_t)3; return p; };
  unsigned* h16      = (unsigned*)carve((size_t)N * 64);  // aliases stage_d during prep
  float*    x2       = carve((size_t)N * 64);             // aliases stage_s during prep
  float*    asd      = carve((size_t)N * 4);
  int2*     rec      = (int2*)carve((size_t)E * 2);       // {src, bf16x2 eattr}
  int*      srcnbr   = (int*)carve((size_t)E);
  int*      rowptr_d = (int*)carve((size_t)N);
  int*      rowptr_s = (int*)carve((size_t)N);
  int*      bktcur_d = (int*)carve(256);
  int*      bktcur_s = (int*)carve(256);
  int*      bktbas_d = (int*)carve(260);
  int*      bktbas_s = (int*)carve(260);
  float*    p_n      = carve((size_t)N * 5);
  float*    fgn      = carve((size_t)N * 4);
  float*    consts   = carve(16);
  float*    wext1    = carve(128 * 4);
  float*    wext2    = carve(64 * 4);
  if (off * sizeof(float) > ws_size) return;  // insufficient scratch: fail loudly

  // bucket staging aliases h16/x2 (CSR build completes before they're written):
  // stage_d = E*16B = N*64*4B exactly; stage_s = E*8B <= N*64*4B.
  int4* stage_d = (int4*)h16;
  int2* stage_s = (int2*)x2;

  const int B = 256;
  const int gE  = cdiv_i(E, B);
  const int gN  = cdiv_i(N, B);

  // ---- graph prep: bucketed CSR build (both directions) ----
  hipMemsetAsync(bktcur_d, 0, 256 * 4, stream);
  hipMemsetAsync(bktcur_s, 0, 256 * 4, stream);
  k_prep_consts<<<1, 64, 0, stream>>>(We1, atte1, We2, atte2, nodefw, edgefw, bec, consts);
  k_prep_wext<<<1, 256, 0, stream>>>(W1, atts1, attd1, W2, atts2, attd2, wext1, wext2);
  k_bkt_hist<<<256, 256, 0, stream>>>(src, dst, bktcur_d, bktcur_s, nbkt, E);
  k_bkt_scan<<<1, 256, 0, stream>>>(bktcur_d, bktbas_d, bktcur_s, bktbas_s, nbkt);
  k_bkt_scatter<<<cdiv_i(E, 256 * CBK), 256, 0, stream>>>(src, dst, eattr, bktcur_d, bktcur_s,
                                                          stage_d, stage_s, nbkt, E);
  k_bkt_sort_d<<<nbkt, 256, 0, stream>>>(stage_d, bktbas_d, rowptr_d, rec, N);
  k_bkt_sort_s<<<nbkt, 256, 0, stream>>>(stage_s, bktbas_s, rowptr_s, srcnbr, N);

  // ---- GAT layer 1 (gemm writes h16+asd; pull writes x2) ----
  k_gemm_att<128><<<cdiv_i(N, 64), 256, 0, stream>>>(x, W1, wext1, h16, asd, N);
  k_gat_pull<true, false><<<cdiv_i(N, 4), 256, 0, stream>>>(
      rowptr_d, rec, asd, h16, consts, b1,
      nullptr, nullptr, nullptr, x2, nullptr, nullptr, N, E);

  // ---- GAT layer 2 (+ fused heads) ----
  k_gemm_att<64><<<cdiv_i(N, 64), 256, 0, stream>>>(x2, W2, wext2, h16, asd, N);
  k_gat_pull<false, true><<<cdiv_i(N, 4), 256, 0, stream>>>(
      rowptr_d, rec, asd, h16, consts + 4, b2,
      Wn, bn, Wec, nullptr, p_n, fgn, N, E);

  // ---- factor graph: 2 pull iterations + edge output ----
  k_fg_pull<1><<<gN, B, 0, stream>>>(rowptr_d, rec, rowptr_s, srcnbr,
                                     p_n, fgn, consts, nullptr, N, E);
  k_fg_pull<2><<<gN, B, 0, stream>>>(rowptr_d, rec, rowptr_s, srcnbr,
                                     p_n, fgn, consts, out_n, N, E);
  k_fg_edge_out<<<gE, B, 0, stream>>>(src, dst, fgn, consts, out_e, E);
}

// Round 8
// 324.077 us; speedup vs baseline: 1.1385x; 1.1385x over previous
//
#include <hip/hip_runtime.h>
#include <math.h>

// GraphRespiratory: 2-layer GAT (edge features, concat=False) + factor graph.
// N=50000, E=800000, IN=128, HID=OUT=64, H=2, NC=5, EC=2, NUM_ITER=2, GAMMA=1.
//
// R7 changes vs R6:
//  - k_gemm_att rewritten back to the R5-verified inner pattern (scalar-k,
//    broadcast A-reads, coalesced W-reads) with: KC=32 chunks (25.3KB LDS ->
//    6 blocks/CU), 16 rows x 2 cols per thread (cols cg & cg+64 = the h16 head
//    pair), acc=32 VGPR, limited unroll. Attention columns stay fused.
//  - k_gat_pull: denominator/self-loop butterfly reduction deferred to after
//    the chunk loop (per-lane partials) - 24 fewer shuffles per 64 edges.

static inline int cdiv_i(long long a, long long b) { return (int)((a + b - 1) / b); }

#define BSH 8           // bucket shift: 256 nodes per bucket
#define CBK 8           // edges per thread in bucket scatter (2048/block)

__device__ __forceinline__ unsigned pack_bf2(float a, float b) {
  unsigned ua = __float_as_uint(a), ub = __float_as_uint(b);
  unsigned ra = (ua + 0x7fffu + ((ua >> 16) & 1u)) >> 16;
  unsigned rb = (ub + 0x7fffu + ((ub >> 16) & 1u)) & 0xffff0000u;
  return ra | rb;
}
__device__ __forceinline__ float bf_lo(unsigned v) { return __uint_as_float(v << 16); }
__device__ __forceinline__ float bf_hi(unsigned v) { return __uint_as_float(v & 0xffff0000u); }

// consts: [0..3] w_e1[h][k], [4..7] w_e2[h][k], [8] avg_ef, [9] avg_nf, [10] dbec
__global__ void k_prep_consts(const float* __restrict__ We1, const float* __restrict__ att_e1,
                              const float* __restrict__ We2, const float* __restrict__ att_e2,
                              const float* __restrict__ node_fw, const float* __restrict__ edge_fw,
                              const float* __restrict__ bec, float* __restrict__ consts) {
  if (blockIdx.x != 0 || threadIdx.x != 0) return;
  for (int h = 0; h < 2; ++h) {
    for (int k = 0; k < 2; ++k) {
      float s1 = 0.f, s2 = 0.f;
      for (int c = 0; c < 64; ++c) {
        s1 += We1[k * 128 + h * 64 + c] * att_e1[h * 64 + c];
        s2 += We2[k * 128 + h * 64 + c] * att_e2[h * 64 + c];
      }
      consts[h * 2 + k] = s1;
      consts[4 + h * 2 + k] = s2;
    }
  }
  float ef = 0.f;                      // edge_fw is [EC=2, NC=5]; mean of [1:,1:]
  for (int j = 1; j < 5; ++j) ef += edge_fw[5 + j];
  consts[8] = ef * 0.25f;
  float nf = 0.f;                      // node_fw is [NC=5, EC=2]; mean of [1:,1:]
  for (int i = 1; i < 5; ++i) nf += node_fw[i * 2 + 1];
  consts[9] = nf * 0.25f;
  consts[10] = bec[1] - bec[0];
}

// wext[k][ac]: ac 0/1 = att_src head0/1, 2/3 = att_dst head0/1. One block.
__global__ void k_prep_wext(const float* __restrict__ W1, const float* __restrict__ as1,
                            const float* __restrict__ ad1,
                            const float* __restrict__ W2, const float* __restrict__ as2,
                            const float* __restrict__ ad2,
                            float* __restrict__ wext1, float* __restrict__ wext2) {
  int t = threadIdx.x;
  for (int o = t; o < 128 * 4; o += 256) {
    int k = o >> 2, j = o & 3;
    const float* att = (j < 2 ? as1 : ad1) + (j & 1) * 64;
    const float* wr = W1 + k * 128 + (j & 1) * 64;
    float s = 0.f;
    for (int c = 0; c < 64; ++c) s += wr[c] * att[c];
    wext1[o] = s;
  }
  for (int o = t; o < 64 * 4; o += 256) {
    int k = o >> 2, j = o & 3;
    const float* att = (j < 2 ? as2 : ad2) + (j & 1) * 64;
    const float* wr = W2 + k * 128 + (j & 1) * 64;
    float s = 0.f;
    for (int c = 0; c < 64; ++c) s += wr[c] * att[c];
    wext2[o] = s;
  }
}

// ---- bucketed CSR build ----
__global__ void k_bkt_hist(const int* __restrict__ src, const int* __restrict__ dst,
                           int* __restrict__ hist_d, int* __restrict__ hist_s,
                           int nbkt, int E) {
  __shared__ int hd[256], hs[256];
  int t = threadIdx.x;
  hd[t] = 0; hs[t] = 0;
  __syncthreads();
  for (int e = blockIdx.x * blockDim.x + t; e < E; e += gridDim.x * blockDim.x) {
    atomicAdd(&hd[dst[e] >> BSH], 1);
    atomicAdd(&hs[src[e] >> BSH], 1);
  }
  __syncthreads();
  if (t < nbkt) {
    if (hd[t]) atomicAdd(&hist_d[t], hd[t]);
    if (hs[t]) atomicAdd(&hist_s[t], hs[t]);
  }
}

// one block: exclusive-scan both histograms -> bases (nbkt+1) and cursors (in place)
__global__ void k_bkt_scan(int* __restrict__ cur_d, int* __restrict__ base_d,
                           int* __restrict__ cur_s, int* __restrict__ base_s, int nbkt) {
  __shared__ int l[256];
  int t = threadIdx.x;
  int v = (t < nbkt) ? cur_d[t] : 0;
  l[t] = v; __syncthreads();
  for (int off = 1; off < 256; off <<= 1) {
    int x = (t >= off) ? l[t - off] : 0; __syncthreads();
    l[t] += x; __syncthreads();
  }
  int incl = l[t];
  if (t < nbkt) { base_d[t] = incl - v; cur_d[t] = incl - v; }
  if (t == nbkt - 1) base_d[nbkt] = incl;
  __syncthreads();
  v = (t < nbkt) ? cur_s[t] : 0;
  l[t] = v; __syncthreads();
  for (int off = 1; off < 256; off <<= 1) {
    int x = (t >= off) ? l[t - off] : 0; __syncthreads();
    l[t] += x; __syncthreads();
  }
  incl = l[t];
  if (t < nbkt) { base_s[t] = incl - v; cur_s[t] = incl - v; }
  if (t == nbkt - 1) base_s[nbkt] = incl;
}

// block-staged bucket scatter: 2048 edges/block in regs; LDS per-bucket counts;
// one global atomicAdd per (bucket,block) to reserve; chunky tail writes.
__global__ __launch_bounds__(256)
void k_bkt_scatter(const int* __restrict__ src, const int* __restrict__ dst,
                   const float* __restrict__ eattr2,
                   int* __restrict__ cur_d, int* __restrict__ cur_s,
                   int4* __restrict__ stage_d, int2* __restrict__ stage_s,
                   int nbkt, int E) {
  __shared__ int cd[256], cs[256], bd[256], bs[256];
  int t = threadIdx.x;
  cd[t] = 0; cs[t] = 0;
  __syncthreads();
  int base = blockIdx.x * 256 * CBK;
  int s[CBK], d[CBK]; unsigned ep[CBK];
#pragma unroll
  for (int c = 0; c < CBK; ++c) {
    int e = base + c * 256 + t;
    if (e < E) {
      s[c] = src[e]; d[c] = dst[e];
      float2 ev = *(const float2*)&eattr2[2 * e];
      ep[c] = pack_bf2(ev.x, ev.y);
      atomicAdd(&cd[d[c] >> BSH], 1);
      atomicAdd(&cs[s[c] >> BSH], 1);
    } else s[c] = -1;
  }
  __syncthreads();
  if (t < nbkt) {
    bd[t] = cd[t] ? atomicAdd(&cur_d[t], cd[t]) : 0;
    bs[t] = cs[t] ? atomicAdd(&cur_s[t], cs[t]) : 0;
    cd[t] = 0; cs[t] = 0;
  }
  __syncthreads();
#pragma unroll
  for (int c = 0; c < CBK; ++c) {
    if (s[c] < 0) continue;
    int db = d[c] >> BSH, sb = s[c] >> BSH;
    int pos = bd[db] + atomicAdd(&cd[db], 1);
    stage_d[pos] = make_int4(s[c], d[c], (int)ep[c], 0);
    int pos2 = bs[sb] + atomicAdd(&cs[sb], 1);
    stage_s[pos2] = make_int2(s[c], d[c]);
  }
}

// per-bucket counting sort (dst side): emits rowptr_d + final rec {src, bf16x2 eattr}.
__global__ __launch_bounds__(256)
void k_bkt_sort_d(const int4* __restrict__ stage, const int* __restrict__ base,
                  int* __restrict__ rowptr, int2* __restrict__ rec, int N) {
  int b = blockIdx.x, t = threadIdx.x;
  int nlo = b << BSH;
  int b0 = base[b], b1 = base[b + 1];
  __shared__ int cnt[256], cur[256], l[256];
  cnt[t] = 0;
  __syncthreads();
  for (int j = b0 + t; j < b1; j += 256)
    atomicAdd(&cnt[stage[j].y - nlo], 1);
  __syncthreads();
  int v = cnt[t];
  l[t] = v; __syncthreads();
  for (int off = 1; off < 256; off <<= 1) {
    int x = (t >= off) ? l[t - off] : 0; __syncthreads();
    l[t] += x; __syncthreads();
  }
  int excl = l[t] - v;
  if (nlo + t < N) rowptr[nlo + t] = b0 + excl;
  cur[t] = excl;
  __syncthreads();
  for (int j = b0 + t; j < b1; j += 256) {
    int4 r = stage[j];
    int pos = b0 + atomicAdd(&cur[r.y - nlo], 1);
    rec[pos] = make_int2(r.x, r.z);
  }
}

// per-bucket counting sort (src side): emits rowptr_s + srcnbr (payload = dst).
__global__ __launch_bounds__(256)
void k_bkt_sort_s(const int2* __restrict__ stage, const int* __restrict__ base,
                  int* __restrict__ rowptr, int* __restrict__ srcnbr, int N) {
  int b = blockIdx.x, t = threadIdx.x;
  int nlo = b << BSH;
  int b0 = base[b], b1 = base[b + 1];
  __shared__ int cnt[256], cur[256], l[256];
  cnt[t] = 0;
  __syncthreads();
  for (int j = b0 + t; j < b1; j += 256)
    atomicAdd(&cnt[stage[j].x - nlo], 1);
  __syncthreads();
  int v = cnt[t];
  l[t] = v; __syncthreads();
  for (int off = 1; off < 256; off <<= 1) {
    int x = (t >= off) ? l[t - off] : 0; __syncthreads();
    l[t] += x; __syncthreads();
  }
  int excl = l[t] - v;
  if (nlo + t < N) rowptr[nlo + t] = b0 + excl;
  cur[t] = excl;
  __syncthreads();
  for (int j = b0 + t; j < b1; j += 256) {
    int2 r = stage[j];
    int pos = b0 + atomicAdd(&cur[r.x - nlo], 1);
    srcnbr[pos] = r.y;
  }
}

// Fused GEMM + attention columns. A[N][K] f32, W[K][128] f32, wext[K][4].
// Block: 64 rows x 128 cols, 256 threads. Thread (rg=tid>>6, cg=tid&63) owns
// 16 rows (rg*16..+15) x 2 cols (cg, cg+64 = the h16 head pair).
// Per k: 2 coalesced W-reads + 16 broadcast A-reads + 1 att A-read -> 32 FMA.
// Outputs: h16[n][64] (bf16-packed head pairs), asd[n][4] = {as0,as1,ad0,ad1}.
template<int K>
__global__ __launch_bounds__(256)
void k_gemm_att(const float* __restrict__ A, const float* __restrict__ W,
                const float* __restrict__ wext,
                unsigned* __restrict__ h16, float* __restrict__ asd, int N) {
  constexpr int KC = 32;
  __shared__ float Al[64][KC + 1];
  __shared__ float Wl[KC][128];
  __shared__ float Wx[KC][4];
  int tid = threadIdx.x;
  int row0 = blockIdx.x * 64;
  int cg = tid & 63;
  int rg = tid >> 6;
  int r_att = tid >> 2, ac = tid & 3;
  float acc0[16], acc1[16];
#pragma unroll
  for (int i = 0; i < 16; ++i) { acc0[i] = 0.f; acc1[i] = 0.f; }
  float aacc = 0.f;

  for (int kc = 0; kc < K; kc += KC) {
    // stage A: 64 rows x KC (coalesced float4 reads, scalar LDS writes)
    for (int i = tid; i < 64 * (KC / 4); i += 256) {
      int r = i >> 3, k4 = (i & 7) * 4;
      int gr = row0 + r;
      float4 v = make_float4(0.f, 0.f, 0.f, 0.f);
      if (gr < N) v = *(const float4*)&A[(long long)gr * K + kc + k4];
      Al[r][k4] = v.x; Al[r][k4 + 1] = v.y; Al[r][k4 + 2] = v.z; Al[r][k4 + 3] = v.w;
    }
    // stage W: KC x 128 (contiguous float4)
    for (int i = tid; i < KC * 32; i += 256)
      *(float4*)&Wl[i >> 5][(i & 31) * 4] = *(const float4*)&W[(kc + (i >> 5)) * 128 + (i & 31) * 4];
    if (tid < KC * 4) Wx[tid >> 2][tid & 3] = wext[(kc + (tid >> 2)) * 4 + (tid & 3)];
    __syncthreads();
#pragma unroll 8
    for (int k = 0; k < KC; ++k) {
      float w0 = Wl[k][cg];
      float w1 = Wl[k][64 + cg];
      aacc += Al[r_att][k] * Wx[k][ac];
#pragma unroll
      for (int i = 0; i < 16; ++i) {
        float a = Al[rg * 16 + i][k];
        acc0[i] += a * w0;
        acc1[i] += a * w1;
      }
    }
    __syncthreads();
  }
#pragma unroll
  for (int i = 0; i < 16; ++i) {
    int gr = row0 + rg * 16 + i;
    if (gr < N) h16[((long long)gr << 6) | cg] = pack_bf2(acc0[i], acc1[i]);
  }
  int gra = row0 + r_att;
  if (gra < N) asd[4 * gra + ac] = aacc;
}

// Fused GAT edge phase, pull-mode. One wave per dst node.
// HEAD: fuse classification/edge heads into the epilogue (no emb store).
template<bool RELU, bool HEAD>
__global__ __launch_bounds__(256)
void k_gat_pull(const int* __restrict__ rowptr, const int2* __restrict__ rec,
                const float* __restrict__ asd, const unsigned* __restrict__ h16,
                const float* __restrict__ we, const float* __restrict__ bias,
                const float* __restrict__ Wn, const float* __restrict__ bn,
                const float* __restrict__ Wec,
                float* __restrict__ out, float* __restrict__ p_n,
                float* __restrict__ fgn, int N, int E) {
  int wv = threadIdx.x >> 6, lane = threadIdx.x & 63;
  int d = blockIdx.x * 4 + wv;
  if (d >= N) return;
  int r0 = rowptr[d];
  int r1 = (d + 1 < N) ? rowptr[d + 1] : E;
  int deg = r1 - r0;
  float4 Ad = *(const float4*)&asd[4 * d];
  float w0 = we[0], w1 = we[1], w2 = we[2], w3 = we[3];
  // per-lane partials; reduced once after the loop
  float den0 = 0.f, den1 = 0.f, acc0 = 0.f, acc1 = 0.f, se0 = 0.f, se1 = 0.f;
  for (int cb = 0; cb < deg; cb += 64) {
    int j = cb + lane;
    int s = 0; unsigned eapk = 0;
    if (j < deg) {
      int2 rc = rec[r0 + j];
      s = rc.x;
      unsigned ep = (unsigned)rc.y;
      float e0 = bf_lo(ep), e1 = bf_hi(ep);
      float4 As = *(const float4*)&asd[4 * s];
      float x0 = As.x + Ad.z + e0 * w0 + e1 * w1;
      float x1 = As.y + Ad.w + e0 * w2 + e1 * w3;
      x0 = x0 >= 0.f ? x0 : 0.2f * x0;
      x1 = x1 >= 0.f ? x1 : 0.2f * x1;
      float ea0 = expf(x0), ea1 = expf(x1);
      eapk = pack_bf2(ea0, ea1);
      den0 += ea0; den1 += ea1; se0 += e0; se1 += e1;
    }
    int m = min(64, deg - cb);
    int j2 = 0;
    for (; j2 + 4 <= m; j2 += 4) {
      int s0 = __shfl(s, j2),     s1 = __shfl(s, j2 + 1);
      int s2 = __shfl(s, j2 + 2), s3 = __shfl(s, j2 + 3);
      unsigned p0 = __shfl(eapk, j2),     p1 = __shfl(eapk, j2 + 1);
      unsigned p2 = __shfl(eapk, j2 + 2), p3 = __shfl(eapk, j2 + 3);
      unsigned q0 = h16[((long long)s0 << 6) | lane];
      unsigned q1 = h16[((long long)s1 << 6) | lane];
      unsigned q2 = h16[((long long)s2 << 6) | lane];
      unsigned q3 = h16[((long long)s3 << 6) | lane];
      acc0 += bf_lo(p0) * bf_lo(q0); acc1 += bf_hi(p0) * bf_hi(q0);
      acc0 += bf_lo(p1) * bf_lo(q1); acc1 += bf_hi(p1) * bf_hi(q1);
      acc0 += bf_lo(p2) * bf_lo(q2); acc1 += bf_hi(p2) * bf_hi(q2);
      acc0 += bf_lo(p3) * bf_lo(q3); acc1 += bf_hi(p3) * bf_hi(q3);
    }
    for (; j2 < m; ++j2) {
      int sj = __shfl(s, j2);
      unsigned pj = __shfl(eapk, j2);
      unsigned q = h16[((long long)sj << 6) | lane];
      acc0 += bf_lo(pj) * bf_lo(q);
      acc1 += bf_hi(pj) * bf_hi(q);
    }
  }
  // reduce den/se partials once
  for (int off = 32; off; off >>= 1) {
    den0 += __shfl_xor(den0, off); den1 += __shfl_xor(den1, off);
    se0  += __shfl_xor(se0, off);  se1  += __shfl_xor(se1, off);
  }
  // self-loop: edge_attr = mean of incident (by dst) eattr; h row from h16.
  float id = 1.0f / fmaxf((float)deg, 1.0f);
  float le0 = se0 * id, le1 = se1 * id;
  float x0 = Ad.x + Ad.z + le0 * w0 + le1 * w1;
  float x1 = Ad.y + Ad.w + le0 * w2 + le1 * w3;
  x0 = x0 >= 0.f ? x0 : 0.2f * x0;
  x1 = x1 >= 0.f ? x1 : 0.2f * x1;
  float eas0 = expf(x0), eas1 = expf(x1);
  den0 += eas0; den1 += eas1;
  unsigned qd = h16[((long long)d << 6) | lane];
  acc0 += eas0 * bf_lo(qd);
  acc1 += eas1 * bf_hi(qd);
  float v = 0.5f * (acc0 / (den0 + 1e-16f) + acc1 / (den1 + 1e-16f)) + bias[lane];
  if (HEAD) {
    float pv[7];
#pragma unroll
    for (int j = 0; j < 5; ++j) pv[j] = v * Wn[lane * 5 + j];
    pv[5] = v * Wec[lane * 2];
    pv[6] = v * Wec[lane * 2 + 1];
    for (int off = 32; off; off >>= 1) {
#pragma unroll
      for (int j = 0; j < 7; ++j) pv[j] += __shfl_down(pv[j], off);
    }
    if (lane == 0) {
      float l[5]; float m = -1e30f;
#pragma unroll
      for (int j = 0; j < 5; ++j) { l[j] = pv[j] + bn[j]; m = fmaxf(m, l[j]); }
      float ssum = 0.f;
#pragma unroll
      for (int j = 0; j < 5; ++j) { l[j] = expf(l[j] - m); ssum += l[j]; }
      float inv = 1.0f / ssum;
#pragma unroll
      for (int j = 0; j < 5; ++j) p_n[5 * d + j] = l[j] * inv;
      fgn[4 * d]     = pv[6] - pv[5];          // q = r1 - r0
      fgn[4 * d + 1] = (ssum - l[0]) * inv;    // nab0 = 1 - p_n[:,0]
      fgn[4 * d + 2] = 0.f;
      fgn[4 * d + 3] = 0.f;
    }
  } else {
    if (RELU) v = fmaxf(v, 0.f);
    out[(long long)d * 64 + lane] = v;
  }
}

// eab after iteration chain: 1 / (1 + exp(-t)/c), c = prod of factors.
__device__ __forceinline__ float fg_eab(float t, float c) {
  return 1.0f / (1.0f + expf(-t) / c);
}

// factor-graph node-pull iteration. One thread per node.
template<int ITER>
__global__ void k_fg_pull(const int* __restrict__ rowptr_d, const int2* __restrict__ rec,
                          const int* __restrict__ rowptr_s, const int* __restrict__ srcnbr,
                          float* __restrict__ p_n, float* __restrict__ fgn,
                          const float* __restrict__ consts, float* __restrict__ out_n,
                          int N, int E) {
  int n = blockIdx.x * blockDim.x + threadIdx.x;
  if (n >= N) return;
  float4 F = *(const float4*)&fgn[4 * n];
  float q = F.x, nab0 = F.y, nab1 = F.z;
  float avg_ef = consts[8], avg_nf = consts[9], dbec = consts[10];
  int rd0 = rowptr_d[n], rd1 = (n + 1 < N) ? rowptr_d[n + 1] : E;
  int rs0 = rowptr_s[n], rs1 = (n + 1 < N) ? rowptr_s[n + 1] : E;
  float s_eab = 0.f;
  for (int j = rd0; j < rd1; ++j) {
    float4 Fo = *(const float4*)&fgn[4 * rec[j].x];
    float t = 0.5f * (q + Fo.x) + dbec;
    float c = 1.0f + fmaxf(nab0, Fo.y) * avg_ef;
    if (ITER == 2) c *= 1.0f + fmaxf(nab1, Fo.z) * avg_ef;
    s_eab += fg_eab(t, c);
  }
  for (int j = rs0; j < rs1; ++j) {
    float4 Fo = *(const float4*)&fgn[4 * srcnbr[j]];
    float t = 0.5f * (q + Fo.x) + dbec;
    float c = 1.0f + fmaxf(nab0, Fo.y) * avg_ef;
    if (ITER == 2) c *= 1.0f + fmaxf(nab1, Fo.z) * avg_ef;
    s_eab += fg_eab(t, c);
  }
  float deg = (float)((rd1 - rd0) + (rs1 - rs0));
  float mean = s_eab / (deg + 1e-6f);
  float f = 1.0f + mean * avg_nf;
  float p0 = p_n[5 * n], p1 = p_n[5 * n + 1], p2 = p_n[5 * n + 2],
        p3 = p_n[5 * n + 3], p4 = p_n[5 * n + 4];
  float rest = (p1 + p2 + p3 + p4) * f;
  float inv = 1.0f / (p0 + rest);
  if (ITER == 1) {
    p_n[5 * n]     = p0 * inv;
    p_n[5 * n + 1] = p1 * f * inv;
    p_n[5 * n + 2] = p2 * f * inv;
    p_n[5 * n + 3] = p3 * f * inv;
    p_n[5 * n + 4] = p4 * f * inv;
    fgn[4 * n + 2] = rest * inv;   // nab1 = 1 - p0'
  } else {
    out_n[5 * n]     = logf(p0 * inv + 1e-9f);
    out_n[5 * n + 1] = logf(p1 * f * inv + 1e-9f);
    out_n[5 * n + 2] = logf(p2 * f * inv + 1e-9f);
    out_n[5 * n + 3] = logf(p3 * f * inv + 1e-9f);
    out_n[5 * n + 4] = logf(p4 * f * inv + 1e-9f);
  }
}

// final edge output: recompute full odds-chain, write log p_e^2. Coalesced.
__global__ void k_fg_edge_out(const int* __restrict__ src, const int* __restrict__ dst,
                              const float* __restrict__ fgn, const float* __restrict__ consts,
                              float* __restrict__ out_e, int E) {
  int e = blockIdx.x * blockDim.x + threadIdx.x;
  if (e >= E) return;
  float avg_ef = consts[8], dbec = consts[10];
  float4 Fs = *(const float4*)&fgn[4 * src[e]];
  float4 Fd = *(const float4*)&fgn[4 * dst[e]];
  float t = 0.5f * (Fs.x + Fd.x) + dbec;
  float c = (1.0f + fmaxf(Fs.y, Fd.y) * avg_ef) * (1.0f + fmaxf(Fs.z, Fd.z) * avg_ef);
  float pe1 = 1.0f / (1.0f + expf(-t) / c);
  float pe0 = 1.0f / (1.0f + c * expf(t));
  *(float2*)&out_e[2 * e] = make_float2(logf(pe0 + 1e-9f), logf(pe1 + 1e-9f));
}

extern "C" void kernel_launch(void* const* d_in, const int* in_sizes, int n_in,
                              void* d_out, int out_size, void* d_ws, size_t ws_size,
                              hipStream_t stream) {
  const float* x      = (const float*)d_in[0];
  const int*   ei     = (const int*)d_in[1];
  const float* eattr  = (const float*)d_in[2];
  const float* W1     = (const float*)d_in[3];
  const float* atts1  = (const float*)d_in[4];
  const float* attd1  = (const float*)d_in[5];
  const float* We1    = (const float*)d_in[6];
  const float* atte1  = (const float*)d_in[7];
  const float* b1     = (const float*)d_in[8];
  const float* W2     = (const float*)d_in[9];
  const float* atts2  = (const float*)d_in[10];
  const float* attd2  = (const float*)d_in[11];
  const float* We2    = (const float*)d_in[12];
  const float* atte2  = (const float*)d_in[13];
  const float* b2     = (const float*)d_in[14];
  const float* Wn     = (const float*)d_in[15];
  const float* bn     = (const float*)d_in[16];
  const float* Wec    = (const float*)d_in[17];
  const float* bec    = (const float*)d_in[18];
  const float* nodefw = (const float*)d_in[19];
  const float* edgefw = (const float*)d_in[20];

  const int N = in_sizes[0] / 128;
  const int E = in_sizes[1] / 2;
  const int* src = ei;
  const int* dst = ei + E;
  const int nbkt = (N + 255) >> BSH;   // 196 (assumes N <= 65536)

  float* out_n = (float*)d_out;
  float* out_e = out_n + (long long)N * 5;

  // ---- workspace carve (f32 units, 16B aligned) ----
  size_t off = 0;
  float* base = (float*)d_ws;
  auto carve = [&](size_t nelem) { float* p = base + off; off += (nelem + 3) & ~(size_t)3; return p; };
  unsigned* h16      = (unsigned*)carve((size_t)N * 64);  // aliases stage_d during prep
  float*    x2       = carve((size_t)N * 64);             // aliases stage_s during prep
  float*    asd      = carve((size_t)N * 4);
  int2*     rec      = (int2*)carve((size_t)E * 2);       // {src, bf16x2 eattr}
  int*      srcnbr   = (int*)carve((size_t)E);
  int*      rowptr_d = (int*)carve((size_t)N);
  int*      rowptr_s = (int*)carve((size_t)N);
  int*      bktcur_d = (int*)carve(256);
  int*      bktcur_s = (int*)carve(256);
  int*      bktbas_d = (int*)carve(260);
  int*      bktbas_s = (int*)carve(260);
  float*    p_n      = carve((size_t)N * 5);
  float*    fgn      = carve((size_t)N * 4);
  float*    consts   = carve(16);
  float*    wext1    = carve(128 * 4);
  float*    wext2    = carve(64 * 4);
  if (off * sizeof(float) > ws_size) return;  // insufficient scratch: fail loudly

  // bucket staging aliases h16/x2 (CSR build completes before they're written):
  // stage_d = E*16B = N*64*4B exactly; stage_s = E*8B <= N*64*4B.
  int4* stage_d = (int4*)h16;
  int2* stage_s = (int2*)x2;

  const int B = 256;
  const int gE  = cdiv_i(E, B);
  const int gN  = cdiv_i(N, B);

  // ---- graph prep: bucketed CSR build (both directions) ----
  hipMemsetAsync(bktcur_d, 0, 256 * 4, stream);
  hipMemsetAsync(bktcur_s, 0, 256 * 4, stream);
  k_prep_consts<<<1, 64, 0, stream>>>(We1, atte1, We2, atte2, nodefw, edgefw, bec, consts);
  k_prep_wext<<<1, 256, 0, stream>>>(W1, atts1, attd1, W2, atts2, attd2, wext1, wext2);
  k_bkt_hist<<<256, 256, 0, stream>>>(src, dst, bktcur_d, bktcur_s, nbkt, E);
  k_bkt_scan<<<1, 256, 0, stream>>>(bktcur_d, bktbas_d, bktcur_s, bktbas_s, nbkt);
  k_bkt_scatter<<<cdiv_i(E, 256 * CBK), 256, 0, stream>>>(src, dst, eattr, bktcur_d, bktcur_s,
                                                          stage_d, stage_s, nbkt, E);
  k_bkt_sort_d<<<nbkt, 256, 0, stream>>>(stage_d, bktbas_d, rowptr_d, rec, N);
  k_bkt_sort_s<<<nbkt, 256, 0, stream>>>(stage_s, bktbas_s, rowptr_s, srcnbr, N);

  // ---- GAT layer 1 (gemm writes h16+asd; pull writes x2) ----
  k_gemm_att<128><<<cdiv_i(N, 64), 256, 0, stream>>>(x, W1, wext1, h16, asd, N);
  k_gat_pull<true, false><<<cdiv_i(N, 4), 256, 0, stream>>>(
      rowptr_d, rec, asd, h16, consts, b1,
      nullptr, nullptr, nullptr, x2, nullptr, nullptr, N, E);

  // ---- GAT layer 2 (+ fused heads) ----
  k_gemm_att<64><<<cdiv_i(N, 64), 256, 0, stream>>>(x2, W2, wext2, h16, asd, N);
  k_gat_pull<false, true><<<cdiv_i(N, 4), 256, 0, stream>>>(
      rowptr_d, rec, asd, h16, consts + 4, b2,
      Wn, bn, Wec, nullptr, p_n, fgn, N, E);

  // ---- factor graph: 2 pull iterations + edge output ----
  k_fg_pull<1><<<gN, B, 0, stream>>>(rowptr_d, rec, rowptr_s, srcnbr,
                                     p_n, fgn, consts, nullptr, N, E);
  k_fg_pull<2><<<gN, B, 0, stream>>>(rowptr_d, rec, rowptr_s, srcnbr,
                                     p_n, fgn, consts, out_n, N, E);
  k_fg_edge_out<<<gE, B, 0, stream>>>(src, dst, fgn, consts, out_e, E);
}

// Round 9
// 314.382 us; speedup vs baseline: 1.1736x; 1.0308x over previous
//
#include <hip/hip_runtime.h>
#include <math.h>

// GraphRespiratory: 2-layer GAT (edge features, concat=False) + factor graph.
// N=50000, E=800000, IN=128, HID=OUT=64, H=2, NC=5, EC=2, NUM_ITER=2, GAMMA=1.
//
// R8 changes vs R7:
//  - Fast transcendentals: v_exp_f32/v_log_f32/v_rcp_f32 based exp/log/rcp
//    (rel err ~1e-7, invisible vs 0.0525 budget) replace IEEE expf/logf/fdiv
//    in gat_pull, fg_pull, edge-out. fg eab restructured to share one rcp.
//  - gat_pull phase B unroll 4 -> 8 (8 gathers in flight).
//  - fg_pull<2> and fg_edge_out merged into one dispatch (block-range split).

static inline int cdiv_i(long long a, long long b) { return (int)((a + b - 1) / b); }

#define BSH 8           // bucket shift: 256 nodes per bucket
#define CBK 8           // edges per thread in bucket scatter (2048/block)

__device__ __forceinline__ float fexp(float x) {
  return __builtin_amdgcn_exp2f(x * 1.44269504088896f);
}
__device__ __forceinline__ float flog(float x) {
  return __builtin_amdgcn_logf(x) * 0.693147180559945f;
}
__device__ __forceinline__ float frcp(float x) {
  return __builtin_amdgcn_rcpf(x);
}

__device__ __forceinline__ unsigned pack_bf2(float a, float b) {
  unsigned ua = __float_as_uint(a), ub = __float_as_uint(b);
  unsigned ra = (ua + 0x7fffu + ((ua >> 16) & 1u)) >> 16;
  unsigned rb = (ub + 0x7fffu + ((ub >> 16) & 1u)) & 0xffff0000u;
  return ra | rb;
}
__device__ __forceinline__ float bf_lo(unsigned v) { return __uint_as_float(v << 16); }
__device__ __forceinline__ float bf_hi(unsigned v) { return __uint_as_float(v & 0xffff0000u); }

// consts: [0..3] w_e1[h][k], [4..7] w_e2[h][k], [8] avg_ef, [9] avg_nf, [10] dbec
__global__ void k_prep_consts(const float* __restrict__ We1, const float* __restrict__ att_e1,
                              const float* __restrict__ We2, const float* __restrict__ att_e2,
                              const float* __restrict__ node_fw, const float* __restrict__ edge_fw,
                              const float* __restrict__ bec, float* __restrict__ consts) {
  if (blockIdx.x != 0 || threadIdx.x != 0) return;
  for (int h = 0; h < 2; ++h) {
    for (int k = 0; k < 2; ++k) {
      float s1 = 0.f, s2 = 0.f;
      for (int c = 0; c < 64; ++c) {
        s1 += We1[k * 128 + h * 64 + c] * att_e1[h * 64 + c];
        s2 += We2[k * 128 + h * 64 + c] * att_e2[h * 64 + c];
      }
      consts[h * 2 + k] = s1;
      consts[4 + h * 2 + k] = s2;
    }
  }
  float ef = 0.f;                      // edge_fw is [EC=2, NC=5]; mean of [1:,1:]
  for (int j = 1; j < 5; ++j) ef += edge_fw[5 + j];
  consts[8] = ef * 0.25f;
  float nf = 0.f;                      // node_fw is [NC=5, EC=2]; mean of [1:,1:]
  for (int i = 1; i < 5; ++i) nf += node_fw[i * 2 + 1];
  consts[9] = nf * 0.25f;
  consts[10] = bec[1] - bec[0];
}

// wext[k][ac]: ac 0/1 = att_src head0/1, 2/3 = att_dst head0/1. One block.
__global__ void k_prep_wext(const float* __restrict__ W1, const float* __restrict__ as1,
                            const float* __restrict__ ad1,
                            const float* __restrict__ W2, const float* __restrict__ as2,
                            const float* __restrict__ ad2,
                            float* __restrict__ wext1, float* __restrict__ wext2) {
  int t = threadIdx.x;
  for (int o = t; o < 128 * 4; o += 256) {
    int k = o >> 2, j = o & 3;
    const float* att = (j < 2 ? as1 : ad1) + (j & 1) * 64;
    const float* wr = W1 + k * 128 + (j & 1) * 64;
    float s = 0.f;
    for (int c = 0; c < 64; ++c) s += wr[c] * att[c];
    wext1[o] = s;
  }
  for (int o = t; o < 64 * 4; o += 256) {
    int k = o >> 2, j = o & 3;
    const float* att = (j < 2 ? as2 : ad2) + (j & 1) * 64;
    const float* wr = W2 + k * 128 + (j & 1) * 64;
    float s = 0.f;
    for (int c = 0; c < 64; ++c) s += wr[c] * att[c];
    wext2[o] = s;
  }
}

// ---- bucketed CSR build ----
__global__ void k_bkt_hist(const int* __restrict__ src, const int* __restrict__ dst,
                           int* __restrict__ hist_d, int* __restrict__ hist_s,
                           int nbkt, int E) {
  __shared__ int hd[256], hs[256];
  int t = threadIdx.x;
  hd[t] = 0; hs[t] = 0;
  __syncthreads();
  for (int e = blockIdx.x * blockDim.x + t; e < E; e += gridDim.x * blockDim.x) {
    atomicAdd(&hd[dst[e] >> BSH], 1);
    atomicAdd(&hs[src[e] >> BSH], 1);
  }
  __syncthreads();
  if (t < nbkt) {
    if (hd[t]) atomicAdd(&hist_d[t], hd[t]);
    if (hs[t]) atomicAdd(&hist_s[t], hs[t]);
  }
}

// one block: exclusive-scan both histograms -> bases (nbkt+1) and cursors (in place)
__global__ void k_bkt_scan(int* __restrict__ cur_d, int* __restrict__ base_d,
                           int* __restrict__ cur_s, int* __restrict__ base_s, int nbkt) {
  __shared__ int l[256];
  int t = threadIdx.x;
  int v = (t < nbkt) ? cur_d[t] : 0;
  l[t] = v; __syncthreads();
  for (int off = 1; off < 256; off <<= 1) {
    int x = (t >= off) ? l[t - off] : 0; __syncthreads();
    l[t] += x; __syncthreads();
  }
  int incl = l[t];
  if (t < nbkt) { base_d[t] = incl - v; cur_d[t] = incl - v; }
  if (t == nbkt - 1) base_d[nbkt] = incl;
  __syncthreads();
  v = (t < nbkt) ? cur_s[t] : 0;
  l[t] = v; __syncthreads();
  for (int off = 1; off < 256; off <<= 1) {
    int x = (t >= off) ? l[t - off] : 0; __syncthreads();
    l[t] += x; __syncthreads();
  }
  incl = l[t];
  if (t < nbkt) { base_s[t] = incl - v; cur_s[t] = incl - v; }
  if (t == nbkt - 1) base_s[nbkt] = incl;
}

// block-staged bucket scatter: 2048 edges/block in regs; LDS per-bucket counts;
// one global atomicAdd per (bucket,block) to reserve; chunky tail writes.
__global__ __launch_bounds__(256)
void k_bkt_scatter(const int* __restrict__ src, const int* __restrict__ dst,
                   const float* __restrict__ eattr2,
                   int* __restrict__ cur_d, int* __restrict__ cur_s,
                   int4* __restrict__ stage_d, int2* __restrict__ stage_s,
                   int nbkt, int E) {
  __shared__ int cd[256], cs[256], bd[256], bs[256];
  int t = threadIdx.x;
  cd[t] = 0; cs[t] = 0;
  __syncthreads();
  int base = blockIdx.x * 256 * CBK;
  int s[CBK], d[CBK]; unsigned ep[CBK];
#pragma unroll
  for (int c = 0; c < CBK; ++c) {
    int e = base + c * 256 + t;
    if (e < E) {
      s[c] = src[e]; d[c] = dst[e];
      float2 ev = *(const float2*)&eattr2[2 * e];
      ep[c] = pack_bf2(ev.x, ev.y);
      atomicAdd(&cd[d[c] >> BSH], 1);
      atomicAdd(&cs[s[c] >> BSH], 1);
    } else s[c] = -1;
  }
  __syncthreads();
  if (t < nbkt) {
    bd[t] = cd[t] ? atomicAdd(&cur_d[t], cd[t]) : 0;
    bs[t] = cs[t] ? atomicAdd(&cur_s[t], cs[t]) : 0;
    cd[t] = 0; cs[t] = 0;
  }
  __syncthreads();
#pragma unroll
  for (int c = 0; c < CBK; ++c) {
    if (s[c] < 0) continue;
    int db = d[c] >> BSH, sb = s[c] >> BSH;
    int pos = bd[db] + atomicAdd(&cd[db], 1);
    stage_d[pos] = make_int4(s[c], d[c], (int)ep[c], 0);
    int pos2 = bs[sb] + atomicAdd(&cs[sb], 1);
    stage_s[pos2] = make_int2(s[c], d[c]);
  }
}

// per-bucket counting sort (dst side): emits rowptr_d + final rec {src, bf16x2 eattr}.
__global__ __launch_bounds__(256)
void k_bkt_sort_d(const int4* __restrict__ stage, const int* __restrict__ base,
                  int* __restrict__ rowptr, int2* __restrict__ rec, int N) {
  int b = blockIdx.x, t = threadIdx.x;
  int nlo = b << BSH;
  int b0 = base[b], b1 = base[b + 1];
  __shared__ int cnt[256], cur[256], l[256];
  cnt[t] = 0;
  __syncthreads();
  for (int j = b0 + t; j < b1; j += 256)
    atomicAdd(&cnt[stage[j].y - nlo], 1);
  __syncthreads();
  int v = cnt[t];
  l[t] = v; __syncthreads();
  for (int off = 1; off < 256; off <<= 1) {
    int x = (t >= off) ? l[t - off] : 0; __syncthreads();
    l[t] += x; __syncthreads();
  }
  int excl = l[t] - v;
  if (nlo + t < N) rowptr[nlo + t] = b0 + excl;
  cur[t] = excl;
  __syncthreads();
  for (int j = b0 + t; j < b1; j += 256) {
    int4 r = stage[j];
    int pos = b0 + atomicAdd(&cur[r.y - nlo], 1);
    rec[pos] = make_int2(r.x, r.z);
  }
}

// per-bucket counting sort (src side): emits rowptr_s + srcnbr (payload = dst).
__global__ __launch_bounds__(256)
void k_bkt_sort_s(const int2* __restrict__ stage, const int* __restrict__ base,
                  int* __restrict__ rowptr, int* __restrict__ srcnbr, int N) {
  int b = blockIdx.x, t = threadIdx.x;
  int nlo = b << BSH;
  int b0 = base[b], b1 = base[b + 1];
  __shared__ int cnt[256], cur[256], l[256];
  cnt[t] = 0;
  __syncthreads();
  for (int j = b0 + t; j < b1; j += 256)
    atomicAdd(&cnt[stage[j].x - nlo], 1);
  __syncthreads();
  int v = cnt[t];
  l[t] = v; __syncthreads();
  for (int off = 1; off < 256; off <<= 1) {
    int x = (t >= off) ? l[t - off] : 0; __syncthreads();
    l[t] += x; __syncthreads();
  }
  int excl = l[t] - v;
  if (nlo + t < N) rowptr[nlo + t] = b0 + excl;
  cur[t] = excl;
  __syncthreads();
  for (int j = b0 + t; j < b1; j += 256) {
    int2 r = stage[j];
    int pos = b0 + atomicAdd(&cur[r.x - nlo], 1);
    srcnbr[pos] = r.y;
  }
}

// Fused GEMM + attention columns. A[N][K] f32, W[K][128] f32, wext[K][4].
// Block: 64 rows x 128 cols, 256 threads. Thread (rg=tid>>6, cg=tid&63) owns
// 16 rows (rg*16..+15) x 2 cols (cg, cg+64 = the h16 head pair).
template<int K>
__global__ __launch_bounds__(256)
void k_gemm_att(const float* __restrict__ A, const float* __restrict__ W,
                const float* __restrict__ wext,
                unsigned* __restrict__ h16, float* __restrict__ asd, int N) {
  constexpr int KC = 32;
  __shared__ float Al[64][KC + 1];
  __shared__ float Wl[KC][128];
  __shared__ float Wx[KC][4];
  int tid = threadIdx.x;
  int row0 = blockIdx.x * 64;
  int cg = tid & 63;
  int rg = tid >> 6;
  int r_att = tid >> 2, ac = tid & 3;
  float acc0[16], acc1[16];
#pragma unroll
  for (int i = 0; i < 16; ++i) { acc0[i] = 0.f; acc1[i] = 0.f; }
  float aacc = 0.f;

  for (int kc = 0; kc < K; kc += KC) {
    for (int i = tid; i < 64 * (KC / 4); i += 256) {
      int r = i >> 3, k4 = (i & 7) * 4;
      int gr = row0 + r;
      float4 v = make_float4(0.f, 0.f, 0.f, 0.f);
      if (gr < N) v = *(const float4*)&A[(long long)gr * K + kc + k4];
      Al[r][k4] = v.x; Al[r][k4 + 1] = v.y; Al[r][k4 + 2] = v.z; Al[r][k4 + 3] = v.w;
    }
    for (int i = tid; i < KC * 32; i += 256)
      *(float4*)&Wl[i >> 5][(i & 31) * 4] = *(const float4*)&W[(kc + (i >> 5)) * 128 + (i & 31) * 4];
    if (tid < KC * 4) Wx[tid >> 2][tid & 3] = wext[(kc + (tid >> 2)) * 4 + (tid & 3)];
    __syncthreads();
#pragma unroll 8
    for (int k = 0; k < KC; ++k) {
      float w0 = Wl[k][cg];
      float w1 = Wl[k][64 + cg];
      aacc += Al[r_att][k] * Wx[k][ac];
#pragma unroll
      for (int i = 0; i < 16; ++i) {
        float a = Al[rg * 16 + i][k];
        acc0[i] += a * w0;
        acc1[i] += a * w1;
      }
    }
    __syncthreads();
  }
#pragma unroll
  for (int i = 0; i < 16; ++i) {
    int gr = row0 + rg * 16 + i;
    if (gr < N) h16[((long long)gr << 6) | cg] = pack_bf2(acc0[i], acc1[i]);
  }
  int gra = row0 + r_att;
  if (gra < N) asd[4 * gra + ac] = aacc;
}

// Fused GAT edge phase, pull-mode. One wave per dst node.
// HEAD: fuse classification/edge heads into the epilogue (no emb store).
template<bool RELU, bool HEAD>
__global__ __launch_bounds__(256)
void k_gat_pull(const int* __restrict__ rowptr, const int2* __restrict__ rec,
                const float* __restrict__ asd, const unsigned* __restrict__ h16,
                const float* __restrict__ we, const float* __restrict__ bias,
                const float* __restrict__ Wn, const float* __restrict__ bn,
                const float* __restrict__ Wec,
                float* __restrict__ out, float* __restrict__ p_n,
                float* __restrict__ fgn, int N, int E) {
  int wv = threadIdx.x >> 6, lane = threadIdx.x & 63;
  int d = blockIdx.x * 4 + wv;
  if (d >= N) return;
  int r0 = rowptr[d];
  int r1 = (d + 1 < N) ? rowptr[d + 1] : E;
  int deg = r1 - r0;
  float4 Ad = *(const float4*)&asd[4 * d];
  float w0 = we[0], w1 = we[1], w2 = we[2], w3 = we[3];
  float den0 = 0.f, den1 = 0.f, acc0 = 0.f, acc1 = 0.f, se0 = 0.f, se1 = 0.f;
  for (int cb = 0; cb < deg; cb += 64) {
    int j = cb + lane;
    int s = 0; unsigned eapk = 0;
    if (j < deg) {
      int2 rc = rec[r0 + j];
      s = rc.x;
      unsigned ep = (unsigned)rc.y;
      float e0 = bf_lo(ep), e1 = bf_hi(ep);
      float4 As = *(const float4*)&asd[4 * s];
      float x0 = As.x + Ad.z + e0 * w0 + e1 * w1;
      float x1 = As.y + Ad.w + e0 * w2 + e1 * w3;
      x0 = x0 >= 0.f ? x0 : 0.2f * x0;
      x1 = x1 >= 0.f ? x1 : 0.2f * x1;
      float ea0 = fexp(x0), ea1 = fexp(x1);
      eapk = pack_bf2(ea0, ea1);
      den0 += ea0; den1 += ea1; se0 += e0; se1 += e1;
    }
    int m = min(64, deg - cb);
    int j2 = 0;
    for (; j2 + 8 <= m; j2 += 8) {
      int sv[8]; unsigned pv[8], qv[8];
#pragma unroll
      for (int u = 0; u < 8; ++u) {
        sv[u] = __shfl(s, j2 + u);
        pv[u] = __shfl(eapk, j2 + u);
      }
#pragma unroll
      for (int u = 0; u < 8; ++u) qv[u] = h16[((long long)sv[u] << 6) | lane];
#pragma unroll
      for (int u = 0; u < 8; ++u) {
        acc0 += bf_lo(pv[u]) * bf_lo(qv[u]);
        acc1 += bf_hi(pv[u]) * bf_hi(qv[u]);
      }
    }
    for (; j2 < m; ++j2) {
      int sj = __shfl(s, j2);
      unsigned pj = __shfl(eapk, j2);
      unsigned q = h16[((long long)sj << 6) | lane];
      acc0 += bf_lo(pj) * bf_lo(q);
      acc1 += bf_hi(pj) * bf_hi(q);
    }
  }
  // reduce den/se partials once
  for (int off = 32; off; off >>= 1) {
    den0 += __shfl_xor(den0, off); den1 += __shfl_xor(den1, off);
    se0  += __shfl_xor(se0, off);  se1  += __shfl_xor(se1, off);
  }
  // self-loop: edge_attr = mean of incident (by dst) eattr; h row from h16.
  float id = frcp(fmaxf((float)deg, 1.0f));
  float le0 = se0 * id, le1 = se1 * id;
  float x0 = Ad.x + Ad.z + le0 * w0 + le1 * w1;
  float x1 = Ad.y + Ad.w + le0 * w2 + le1 * w3;
  x0 = x0 >= 0.f ? x0 : 0.2f * x0;
  x1 = x1 >= 0.f ? x1 : 0.2f * x1;
  float eas0 = fexp(x0), eas1 = fexp(x1);
  den0 += eas0; den1 += eas1;
  unsigned qd = h16[((long long)d << 6) | lane];
  acc0 += eas0 * bf_lo(qd);
  acc1 += eas1 * bf_hi(qd);
  float v = 0.5f * (acc0 * frcp(den0 + 1e-16f) + acc1 * frcp(den1 + 1e-16f)) + bias[lane];
  if (HEAD) {
    float pv[7];
#pragma unroll
    for (int j = 0; j < 5; ++j) pv[j] = v * Wn[lane * 5 + j];
    pv[5] = v * Wec[lane * 2];
    pv[6] = v * Wec[lane * 2 + 1];
    for (int off = 32; off; off >>= 1) {
#pragma unroll
      for (int j = 0; j < 7; ++j) pv[j] += __shfl_down(pv[j], off);
    }
    if (lane == 0) {
      float l[5]; float m = -1e30f;
#pragma unroll
      for (int j = 0; j < 5; ++j) { l[j] = pv[j] + bn[j]; m = fmaxf(m, l[j]); }
      float ssum = 0.f;
#pragma unroll
      for (int j = 0; j < 5; ++j) { l[j] = fexp(l[j] - m); ssum += l[j]; }
      float inv = frcp(ssum);
#pragma unroll
      for (int j = 0; j < 5; ++j) p_n[5 * d + j] = l[j] * inv;
      fgn[4 * d]     = pv[6] - pv[5];          // q = r1 - r0
      fgn[4 * d + 1] = (ssum - l[0]) * inv;    // nab0 = 1 - p_n[:,0]
      fgn[4 * d + 2] = 0.f;
      fgn[4 * d + 3] = 0.f;
    }
  } else {
    if (RELU) v = fmaxf(v, 0.f);
    out[(long long)d * 64 + lane] = v;
  }
}

// eab = c / (c + exp(-t)) : one rcp, shared structure.
__device__ __forceinline__ float fg_eab(float t, float c) {
  return c * frcp(c + fexp(-t));
}

// factor-graph node-pull iteration 1. One thread per node.
__global__ void k_fg_pull1(const int* __restrict__ rowptr_d, const int2* __restrict__ rec,
                           const int* __restrict__ rowptr_s, const int* __restrict__ srcnbr,
                           float* __restrict__ p_n, float* __restrict__ fgn,
                           const float* __restrict__ consts, int N, int E) {
  int n = blockIdx.x * blockDim.x + threadIdx.x;
  if (n >= N) return;
  float4 F = *(const float4*)&fgn[4 * n];
  float q = F.x, nab0 = F.y;
  float avg_ef = consts[8], avg_nf = consts[9], dbec = consts[10];
  int rd0 = rowptr_d[n], rd1 = (n + 1 < N) ? rowptr_d[n + 1] : E;
  int rs0 = rowptr_s[n], rs1 = (n + 1 < N) ? rowptr_s[n + 1] : E;
  float s_eab = 0.f;
  for (int j = rd0; j < rd1; ++j) {
    float4 Fo = *(const float4*)&fgn[4 * rec[j].x];
    float t = 0.5f * (q + Fo.x) + dbec;
    float c = 1.0f + fmaxf(nab0, Fo.y) * avg_ef;
    s_eab += fg_eab(t, c);
  }
  for (int j = rs0; j < rs1; ++j) {
    float4 Fo = *(const float4*)&fgn[4 * srcnbr[j]];
    float t = 0.5f * (q + Fo.x) + dbec;
    float c = 1.0f + fmaxf(nab0, Fo.y) * avg_ef;
    s_eab += fg_eab(t, c);
  }
  float deg = (float)((rd1 - rd0) + (rs1 - rs0));
  float mean = s_eab * frcp(deg + 1e-6f);
  float f = 1.0f + mean * avg_nf;
  float p0 = p_n[5 * n], p1 = p_n[5 * n + 1], p2 = p_n[5 * n + 2],
        p3 = p_n[5 * n + 3], p4 = p_n[5 * n + 4];
  float rest = (p1 + p2 + p3 + p4) * f;
  float inv = frcp(p0 + rest);
  p_n[5 * n]     = p0 * inv;
  p_n[5 * n + 1] = p1 * f * inv;
  p_n[5 * n + 2] = p2 * f * inv;
  p_n[5 * n + 3] = p3 * f * inv;
  p_n[5 * n + 4] = p4 * f * inv;
  fgn[4 * n + 2] = rest * inv;   // nab1 = 1 - p0'
}

// merged final pass: blocks [0, nodeBlocks) = fg iteration 2 (writes out_n);
// blocks [nodeBlocks, ...) = edge output (full odds-chain, writes out_e).
// Both only READ fgn - safe in one dispatch.
__global__ void k_fg_final(const int* __restrict__ rowptr_d, const int2* __restrict__ rec,
                           const int* __restrict__ rowptr_s, const int* __restrict__ srcnbr,
                           const float* __restrict__ p_n, const float* __restrict__ fgn,
                           const float* __restrict__ consts,
                           const int* __restrict__ src, const int* __restrict__ dst,
                           float* __restrict__ out_n, float* __restrict__ out_e,
                           int N, int E, int nodeBlocks) {
  float avg_ef = consts[8], dbec = consts[10];
  if ((int)blockIdx.x < nodeBlocks) {
    int n = blockIdx.x * blockDim.x + threadIdx.x;
    if (n >= N) return;
    float avg_nf = consts[9];
    float4 F = *(const float4*)&fgn[4 * n];
    float q = F.x, nab0 = F.y, nab1 = F.z;
    int rd0 = rowptr_d[n], rd1 = (n + 1 < N) ? rowptr_d[n + 1] : E;
    int rs0 = rowptr_s[n], rs1 = (n + 1 < N) ? rowptr_s[n + 1] : E;
    float s_eab = 0.f;
    for (int j = rd0; j < rd1; ++j) {
      float4 Fo = *(const float4*)&fgn[4 * rec[j].x];
      float t = 0.5f * (q + Fo.x) + dbec;
      float c = (1.0f + fmaxf(nab0, Fo.y) * avg_ef) * (1.0f + fmaxf(nab1, Fo.z) * avg_ef);
      s_eab += fg_eab(t, c);
    }
    for (int j = rs0; j < rs1; ++j) {
      float4 Fo = *(const float4*)&fgn[4 * srcnbr[j]];
      float t = 0.5f * (q + Fo.x) + dbec;
      float c = (1.0f + fmaxf(nab0, Fo.y) * avg_ef) * (1.0f + fmaxf(nab1, Fo.z) * avg_ef);
      s_eab += fg_eab(t, c);
    }
    float deg = (float)((rd1 - rd0) + (rs1 - rs0));
    float mean = s_eab * frcp(deg + 1e-6f);
    float f = 1.0f + mean * avg_nf;
    float p0 = p_n[5 * n], p1 = p_n[5 * n + 1], p2 = p_n[5 * n + 2],
          p3 = p_n[5 * n + 3], p4 = p_n[5 * n + 4];
    float rest = (p1 + p2 + p3 + p4) * f;
    float inv = frcp(p0 + rest);
    out_n[5 * n]     = flog(p0 * inv + 1e-9f);
    out_n[5 * n + 1] = flog(p1 * f * inv + 1e-9f);
    out_n[5 * n + 2] = flog(p2 * f * inv + 1e-9f);
    out_n[5 * n + 3] = flog(p3 * f * inv + 1e-9f);
    out_n[5 * n + 4] = flog(p4 * f * inv + 1e-9f);
  } else {
    int e = (blockIdx.x - nodeBlocks) * blockDim.x + threadIdx.x;
    if (e >= E) return;
    float4 Fs = *(const float4*)&fgn[4 * src[e]];
    float4 Fd = *(const float4*)&fgn[4 * dst[e]];
    float t = 0.5f * (Fs.x + Fd.x) + dbec;
    float c = (1.0f + fmaxf(Fs.y, Fd.y) * avg_ef) * (1.0f + fmaxf(Fs.z, Fd.z) * avg_ef);
    float ei = fexp(-t);
    float r = frcp(c + ei);
    float pe1 = c * r, pe0 = ei * r;
    *(float2*)&out_e[2 * e] = make_float2(flog(pe0 + 1e-9f), flog(pe1 + 1e-9f));
  }
}

extern "C" void kernel_launch(void* const* d_in, const int* in_sizes, int n_in,
                              void* d_out, int out_size, void* d_ws, size_t ws_size,
                              hipStream_t stream) {
  const float* x      = (const float*)d_in[0];
  const int*   ei     = (const int*)d_in[1];
  const float* eattr  = (const float*)d_in[2];
  const float* W1     = (const float*)d_in[3];
  const float* atts1  = (const float*)d_in[4];
  const float* attd1  = (const float*)d_in[5];
  const float* We1    = (const float*)d_in[6];
  const float* atte1  = (const float*)d_in[7];
  const float* b1     = (const float*)d_in[8];
  const float* W2     = (const float*)d_in[9];
  const float* atts2  = (const float*)d_in[10];
  const float* attd2  = (const float*)d_in[11];
  const float* We2    = (const float*)d_in[12];
  const float* atte2  = (const float*)d_in[13];
  const float* b2     = (const float*)d_in[14];
  const float* Wn     = (const float*)d_in[15];
  const float* bn     = (const float*)d_in[16];
  const float* Wec    = (const float*)d_in[17];
  const float* bec    = (const float*)d_in[18];
  const float* nodefw = (const float*)d_in[19];
  const float* edgefw = (const float*)d_in[20];

  const int N = in_sizes[0] / 128;
  const int E = in_sizes[1] / 2;
  const int* src = ei;
  const int* dst = ei + E;
  const int nbkt = (N + 255) >> BSH;   // 196 (assumes N <= 65536)

  float* out_n = (float*)d_out;
  float* out_e = out_n + (long long)N * 5;

  // ---- workspace carve (f32 units, 16B aligned) ----
  size_t off = 0;
  float* base = (float*)d_ws;
  auto carve = [&](size_t nelem) { float* p = base + off; off += (nelem + 3) & ~(size_t)3; return p; };
  unsigned* h16      = (unsigned*)carve((size_t)N * 64);  // aliases stage_d during prep
  float*    x2       = carve((size_t)N * 64);             // aliases stage_s during prep
  float*    asd      = carve((size_t)N * 4);
  int2*     rec      = (int2*)carve((size_t)E * 2);       // {src, bf16x2 eattr}
  int*      srcnbr   = (int*)carve((size_t)E);
  int*      rowptr_d = (int*)carve((size_t)N);
  int*      rowptr_s = (int*)carve((size_t)N);
  int*      bktcur_d = (int*)carve(256);
  int*      bktcur_s = (int*)carve(256);
  int*      bktbas_d = (int*)carve(260);
  int*      bktbas_s = (int*)carve(260);
  float*    p_n      = carve((size_t)N * 5);
  float*    fgn      = carve((size_t)N * 4);
  float*    consts   = carve(16);
  float*    wext1    = carve(128 * 4);
  float*    wext2    = carve(64 * 4);
  if (off * sizeof(float) > ws_size) return;  // insufficient scratch: fail loudly

  // bucket staging aliases h16/x2 (CSR build completes before they're written):
  int4* stage_d = (int4*)h16;
  int2* stage_s = (int2*)x2;

  const int B = 256;
  const int gE  = cdiv_i(E, B);
  const int gN  = cdiv_i(N, B);

  // ---- graph prep: bucketed CSR build (both directions) ----
  hipMemsetAsync(bktcur_d, 0, 256 * 4, stream);
  hipMemsetAsync(bktcur_s, 0, 256 * 4, stream);
  k_prep_consts<<<1, 64, 0, stream>>>(We1, atte1, We2, atte2, nodefw, edgefw, bec, consts);
  k_prep_wext<<<1, 256, 0, stream>>>(W1, atts1, attd1, W2, atts2, attd2, wext1, wext2);
  k_bkt_hist<<<256, 256, 0, stream>>>(src, dst, bktcur_d, bktcur_s, nbkt, E);
  k_bkt_scan<<<1, 256, 0, stream>>>(bktcur_d, bktbas_d, bktcur_s, bktbas_s, nbkt);
  k_bkt_scatter<<<cdiv_i(E, 256 * CBK), 256, 0, stream>>>(src, dst, eattr, bktcur_d, bktcur_s,
                                                          stage_d, stage_s, nbkt, E);
  k_bkt_sort_d<<<nbkt, 256, 0, stream>>>(stage_d, bktbas_d, rowptr_d, rec, N);
  k_bkt_sort_s<<<nbkt, 256, 0, stream>>>(stage_s, bktbas_s, rowptr_s, srcnbr, N);

  // ---- GAT layer 1 (gemm writes h16+asd; pull writes x2) ----
  k_gemm_att<128><<<cdiv_i(N, 64), 256, 0, stream>>>(x, W1, wext1, h16, asd, N);
  k_gat_pull<true, false><<<cdiv_i(N, 4), 256, 0, stream>>>(
      rowptr_d, rec, asd, h16, consts, b1,
      nullptr, nullptr, nullptr, x2, nullptr, nullptr, N, E);

  // ---- GAT layer 2 (+ fused heads) ----
  k_gemm_att<64><<<cdiv_i(N, 64), 256, 0, stream>>>(x2, W2, wext2, h16, asd, N);
  k_gat_pull<false, true><<<cdiv_i(N, 4), 256, 0, stream>>>(
      rowptr_d, rec, asd, h16, consts + 4, b2,
      Wn, bn, Wec, nullptr, p_n, fgn, N, E);

  // ---- factor graph: iter1 + merged (iter2 + edge output) ----
  k_fg_pull1<<<gN, B, 0, stream>>>(rowptr_d, rec, rowptr_s, srcnbr,
                                   p_n, fgn, consts, N, E);
  k_fg_final<<<gN + gE, B, 0, stream>>>(rowptr_d, rec, rowptr_s, srcnbr,
                                        p_n, fgn, consts, src, dst,
                                        out_n, out_e, N, E, gN);
}

// Round 10
// 303.192 us; speedup vs baseline: 1.2169x; 1.0369x over previous
//
#include <hip/hip_runtime.h>
#include <math.h>

// GraphRespiratory: 2-layer GAT (edge features, concat=False) + factor graph.
// N=50000, E=800000, IN=128, HID=OUT=64, H=2, NC=5, EC=2, NUM_ITER=2, GAMMA=1.
//
// R9 changes vs R8:
//  - k_gat_pull phase B: per-wave LDS staging of {src, ea-pack} (ds_write_b64
//    once per edge) + uniform-address int4 broadcast reads (4 ds_read_b128 per
//    8 edges) replace 2 ds_bpermute per edge. Removes the shuffle->gather
//    dependency chain (latency-bound fix).
//  - fg node state packed to 8B: fgn8[n]={f32 q, bf16 nab0, bf16 nab1}.
//    400KB table = L2-resident; halves gather lines in fg_pull1/fg_final.

static inline int cdiv_i(long long a, long long b) { return (int)((a + b - 1) / b); }

#define BSH 8           // bucket shift: 256 nodes per bucket
#define CBK 8           // edges per thread in bucket scatter (2048/block)

__device__ __forceinline__ float fexp(float x) {
  return __builtin_amdgcn_exp2f(x * 1.44269504088896f);
}
__device__ __forceinline__ float flog(float x) {
  return __builtin_amdgcn_logf(x) * 0.693147180559945f;
}
__device__ __forceinline__ float frcp(float x) {
  return __builtin_amdgcn_rcpf(x);
}

__device__ __forceinline__ unsigned pack_bf2(float a, float b) {
  unsigned ua = __float_as_uint(a), ub = __float_as_uint(b);
  unsigned ra = (ua + 0x7fffu + ((ua >> 16) & 1u)) >> 16;
  unsigned rb = (ub + 0x7fffu + ((ub >> 16) & 1u)) & 0xffff0000u;
  return ra | rb;
}
__device__ __forceinline__ float bf_lo(unsigned v) { return __uint_as_float(v << 16); }
__device__ __forceinline__ float bf_hi(unsigned v) { return __uint_as_float(v & 0xffff0000u); }

// consts: [0..3] w_e1[h][k], [4..7] w_e2[h][k], [8] avg_ef, [9] avg_nf, [10] dbec
__global__ void k_prep_consts(const float* __restrict__ We1, const float* __restrict__ att_e1,
                              const float* __restrict__ We2, const float* __restrict__ att_e2,
                              const float* __restrict__ node_fw, const float* __restrict__ edge_fw,
                              const float* __restrict__ bec, float* __restrict__ consts) {
  if (blockIdx.x != 0 || threadIdx.x != 0) return;
  for (int h = 0; h < 2; ++h) {
    for (int k = 0; k < 2; ++k) {
      float s1 = 0.f, s2 = 0.f;
      for (int c = 0; c < 64; ++c) {
        s1 += We1[k * 128 + h * 64 + c] * att_e1[h * 64 + c];
        s2 += We2[k * 128 + h * 64 + c] * att_e2[h * 64 + c];
      }
      consts[h * 2 + k] = s1;
      consts[4 + h * 2 + k] = s2;
    }
  }
  float ef = 0.f;                      // edge_fw is [EC=2, NC=5]; mean of [1:,1:]
  for (int j = 1; j < 5; ++j) ef += edge_fw[5 + j];
  consts[8] = ef * 0.25f;
  float nf = 0.f;                      // node_fw is [NC=5, EC=2]; mean of [1:,1:]
  for (int i = 1; i < 5; ++i) nf += node_fw[i * 2 + 1];
  consts[9] = nf * 0.25f;
  consts[10] = bec[1] - bec[0];
}

// wext[k][ac]: ac 0/1 = att_src head0/1, 2/3 = att_dst head0/1. One block.
__global__ void k_prep_wext(const float* __restrict__ W1, const float* __restrict__ as1,
                            const float* __restrict__ ad1,
                            const float* __restrict__ W2, const float* __restrict__ as2,
                            const float* __restrict__ ad2,
                            float* __restrict__ wext1, float* __restrict__ wext2) {
  int t = threadIdx.x;
  for (int o = t; o < 128 * 4; o += 256) {
    int k = o >> 2, j = o & 3;
    const float* att = (j < 2 ? as1 : ad1) + (j & 1) * 64;
    const float* wr = W1 + k * 128 + (j & 1) * 64;
    float s = 0.f;
    for (int c = 0; c < 64; ++c) s += wr[c] * att[c];
    wext1[o] = s;
  }
  for (int o = t; o < 64 * 4; o += 256) {
    int k = o >> 2, j = o & 3;
    const float* att = (j < 2 ? as2 : ad2) + (j & 1) * 64;
    const float* wr = W2 + k * 128 + (j & 1) * 64;
    float s = 0.f;
    for (int c = 0; c < 64; ++c) s += wr[c] * att[c];
    wext2[o] = s;
  }
}

// ---- bucketed CSR build ----
__global__ void k_bkt_hist(const int* __restrict__ src, const int* __restrict__ dst,
                           int* __restrict__ hist_d, int* __restrict__ hist_s,
                           int nbkt, int E) {
  __shared__ int hd[256], hs[256];
  int t = threadIdx.x;
  hd[t] = 0; hs[t] = 0;
  __syncthreads();
  for (int e = blockIdx.x * blockDim.x + t; e < E; e += gridDim.x * blockDim.x) {
    atomicAdd(&hd[dst[e] >> BSH], 1);
    atomicAdd(&hs[src[e] >> BSH], 1);
  }
  __syncthreads();
  if (t < nbkt) {
    if (hd[t]) atomicAdd(&hist_d[t], hd[t]);
    if (hs[t]) atomicAdd(&hist_s[t], hs[t]);
  }
}

// one block: exclusive-scan both histograms -> bases (nbkt+1) and cursors (in place)
__global__ void k_bkt_scan(int* __restrict__ cur_d, int* __restrict__ base_d,
                           int* __restrict__ cur_s, int* __restrict__ base_s, int nbkt) {
  __shared__ int l[256];
  int t = threadIdx.x;
  int v = (t < nbkt) ? cur_d[t] : 0;
  l[t] = v; __syncthreads();
  for (int off = 1; off < 256; off <<= 1) {
    int x = (t >= off) ? l[t - off] : 0; __syncthreads();
    l[t] += x; __syncthreads();
  }
  int incl = l[t];
  if (t < nbkt) { base_d[t] = incl - v; cur_d[t] = incl - v; }
  if (t == nbkt - 1) base_d[nbkt] = incl;
  __syncthreads();
  v = (t < nbkt) ? cur_s[t] : 0;
  l[t] = v; __syncthreads();
  for (int off = 1; off < 256; off <<= 1) {
    int x = (t >= off) ? l[t - off] : 0; __syncthreads();
    l[t] += x; __syncthreads();
  }
  incl = l[t];
  if (t < nbkt) { base_s[t] = incl - v; cur_s[t] = incl - v; }
  if (t == nbkt - 1) base_s[nbkt] = incl;
}

// block-staged bucket scatter: 2048 edges/block in regs; LDS per-bucket counts;
// one global atomicAdd per (bucket,block) to reserve; chunky tail writes.
__global__ __launch_bounds__(256)
void k_bkt_scatter(const int* __restrict__ src, const int* __restrict__ dst,
                   const float* __restrict__ eattr2,
                   int* __restrict__ cur_d, int* __restrict__ cur_s,
                   int4* __restrict__ stage_d, int2* __restrict__ stage_s,
                   int nbkt, int E) {
  __shared__ int cd[256], cs[256], bd[256], bs[256];
  int t = threadIdx.x;
  cd[t] = 0; cs[t] = 0;
  __syncthreads();
  int base = blockIdx.x * 256 * CBK;
  int s[CBK], d[CBK]; unsigned ep[CBK];
#pragma unroll
  for (int c = 0; c < CBK; ++c) {
    int e = base + c * 256 + t;
    if (e < E) {
      s[c] = src[e]; d[c] = dst[e];
      float2 ev = *(const float2*)&eattr2[2 * e];
      ep[c] = pack_bf2(ev.x, ev.y);
      atomicAdd(&cd[d[c] >> BSH], 1);
      atomicAdd(&cs[s[c] >> BSH], 1);
    } else s[c] = -1;
  }
  __syncthreads();
  if (t < nbkt) {
    bd[t] = cd[t] ? atomicAdd(&cur_d[t], cd[t]) : 0;
    bs[t] = cs[t] ? atomicAdd(&cur_s[t], cs[t]) : 0;
    cd[t] = 0; cs[t] = 0;
  }
  __syncthreads();
#pragma unroll
  for (int c = 0; c < CBK; ++c) {
    if (s[c] < 0) continue;
    int db = d[c] >> BSH, sb = s[c] >> BSH;
    int pos = bd[db] + atomicAdd(&cd[db], 1);
    stage_d[pos] = make_int4(s[c], d[c], (int)ep[c], 0);
    int pos2 = bs[sb] + atomicAdd(&cs[sb], 1);
    stage_s[pos2] = make_int2(s[c], d[c]);
  }
}

// per-bucket counting sort (dst side): emits rowptr_d + final rec {src, bf16x2 eattr}.
__global__ __launch_bounds__(256)
void k_bkt_sort_d(const int4* __restrict__ stage, const int* __restrict__ base,
                  int* __restrict__ rowptr, int2* __restrict__ rec, int N) {
  int b = blockIdx.x, t = threadIdx.x;
  int nlo = b << BSH;
  int b0 = base[b], b1 = base[b + 1];
  __shared__ int cnt[256], cur[256], l[256];
  cnt[t] = 0;
  __syncthreads();
  for (int j = b0 + t; j < b1; j += 256)
    atomicAdd(&cnt[stage[j].y - nlo], 1);
  __syncthreads();
  int v = cnt[t];
  l[t] = v; __syncthreads();
  for (int off = 1; off < 256; off <<= 1) {
    int x = (t >= off) ? l[t - off] : 0; __syncthreads();
    l[t] += x; __syncthreads();
  }
  int excl = l[t] - v;
  if (nlo + t < N) rowptr[nlo + t] = b0 + excl;
  cur[t] = excl;
  __syncthreads();
  for (int j = b0 + t; j < b1; j += 256) {
    int4 r = stage[j];
    int pos = b0 + atomicAdd(&cur[r.y - nlo], 1);
    rec[pos] = make_int2(r.x, r.z);
  }
}

// per-bucket counting sort (src side): emits rowptr_s + srcnbr (payload = dst).
__global__ __launch_bounds__(256)
void k_bkt_sort_s(const int2* __restrict__ stage, const int* __restrict__ base,
                  int* __restrict__ rowptr, int* __restrict__ srcnbr, int N) {
  int b = blockIdx.x, t = threadIdx.x;
  int nlo = b << BSH;
  int b0 = base[b], b1 = base[b + 1];
  __shared__ int cnt[256], cur[256], l[256];
  cnt[t] = 0;
  __syncthreads();
  for (int j = b0 + t; j < b1; j += 256)
    atomicAdd(&cnt[stage[j].x - nlo], 1);
  __syncthreads();
  int v = cnt[t];
  l[t] = v; __syncthreads();
  for (int off = 1; off < 256; off <<= 1) {
    int x = (t >= off) ? l[t - off] : 0; __syncthreads();
    l[t] += x; __syncthreads();
  }
  int excl = l[t] - v;
  if (nlo + t < N) rowptr[nlo + t] = b0 + excl;
  cur[t] = excl;
  __syncthreads();
  for (int j = b0 + t; j < b1; j += 256) {
    int2 r = stage[j];
    int pos = b0 + atomicAdd(&cur[r.x - nlo], 1);
    srcnbr[pos] = r.y;
  }
}

// Fused GEMM + attention columns. A[N][K] f32, W[K][128] f32, wext[K][4].
// Block: 64 rows x 128 cols, 256 threads. Thread (rg=tid>>6, cg=tid&63) owns
// 16 rows (rg*16..+15) x 2 cols (cg, cg+64 = the h16 head pair).
template<int K>
__global__ __launch_bounds__(256)
void k_gemm_att(const float* __restrict__ A, const float* __restrict__ W,
                const float* __restrict__ wext,
                unsigned* __restrict__ h16, float* __restrict__ asd, int N) {
  constexpr int KC = 32;
  __shared__ float Al[64][KC + 1];
  __shared__ float Wl[KC][128];
  __shared__ float Wx[KC][4];
  int tid = threadIdx.x;
  int row0 = blockIdx.x * 64;
  int cg = tid & 63;
  int rg = tid >> 6;
  int r_att = tid >> 2, ac = tid & 3;
  float acc0[16], acc1[16];
#pragma unroll
  for (int i = 0; i < 16; ++i) { acc0[i] = 0.f; acc1[i] = 0.f; }
  float aacc = 0.f;

  for (int kc = 0; kc < K; kc += KC) {
    for (int i = tid; i < 64 * (KC / 4); i += 256) {
      int r = i >> 3, k4 = (i & 7) * 4;
      int gr = row0 + r;
      float4 v = make_float4(0.f, 0.f, 0.f, 0.f);
      if (gr < N) v = *(const float4*)&A[(long long)gr * K + kc + k4];
      Al[r][k4] = v.x; Al[r][k4 + 1] = v.y; Al[r][k4 + 2] = v.z; Al[r][k4 + 3] = v.w;
    }
    for (int i = tid; i < KC * 32; i += 256)
      *(float4*)&Wl[i >> 5][(i & 31) * 4] = *(const float4*)&W[(kc + (i >> 5)) * 128 + (i & 31) * 4];
    if (tid < KC * 4) Wx[tid >> 2][tid & 3] = wext[(kc + (tid >> 2)) * 4 + (tid & 3)];
    __syncthreads();
#pragma unroll 8
    for (int k = 0; k < KC; ++k) {
      float w0 = Wl[k][cg];
      float w1 = Wl[k][64 + cg];
      aacc += Al[r_att][k] * Wx[k][ac];
#pragma unroll
      for (int i = 0; i < 16; ++i) {
        float a = Al[rg * 16 + i][k];
        acc0[i] += a * w0;
        acc1[i] += a * w1;
      }
    }
    __syncthreads();
  }
#pragma unroll
  for (int i = 0; i < 16; ++i) {
    int gr = row0 + rg * 16 + i;
    if (gr < N) h16[((long long)gr << 6) | cg] = pack_bf2(acc0[i], acc1[i]);
  }
  int gra = row0 + r_att;
  if (gra < N) asd[4 * gra + ac] = aacc;
}

// Fused GAT edge phase, pull-mode. One wave per dst node.
// Phase A results staged in per-wave LDS; phase B uses uniform-address int4
// broadcast reads (no bpermute dependency ahead of the gathers).
// HEAD: fuse classification/edge heads into the epilogue (no emb store).
template<bool RELU, bool HEAD>
__global__ __launch_bounds__(256)
void k_gat_pull(const int* __restrict__ rowptr, const int2* __restrict__ rec,
                const float* __restrict__ asd, const unsigned* __restrict__ h16,
                const float* __restrict__ we, const float* __restrict__ bias,
                const float* __restrict__ Wn, const float* __restrict__ bn,
                const float* __restrict__ Wec,
                float* __restrict__ out, float* __restrict__ p_n,
                int2* __restrict__ fgn8, int N, int E) {
  __shared__ int2 ed[4][64];
  int wv = threadIdx.x >> 6, lane = threadIdx.x & 63;
  int d = blockIdx.x * 4 + wv;
  if (d >= N) return;
  int r0 = rowptr[d];
  int r1 = (d + 1 < N) ? rowptr[d + 1] : E;
  int deg = r1 - r0;
  float4 Ad = *(const float4*)&asd[4 * d];
  float w0 = we[0], w1 = we[1], w2 = we[2], w3 = we[3];
  float den0 = 0.f, den1 = 0.f, acc0 = 0.f, acc1 = 0.f, se0 = 0.f, se1 = 0.f;
  for (int cb = 0; cb < deg; cb += 64) {
    int j = cb + lane;
    int s = 0; unsigned eapk = 0;
    if (j < deg) {
      int2 rc = rec[r0 + j];
      s = rc.x;
      unsigned ep = (unsigned)rc.y;
      float e0 = bf_lo(ep), e1 = bf_hi(ep);
      float4 As = *(const float4*)&asd[4 * s];
      float x0 = As.x + Ad.z + e0 * w0 + e1 * w1;
      float x1 = As.y + Ad.w + e0 * w2 + e1 * w3;
      x0 = x0 >= 0.f ? x0 : 0.2f * x0;
      x1 = x1 >= 0.f ? x1 : 0.2f * x1;
      float ea0 = fexp(x0), ea1 = fexp(x1);
      eapk = pack_bf2(ea0, ea1);
      den0 += ea0; den1 += ea1; se0 += e0; se1 += e1;
    }
    ed[wv][lane] = make_int2(s, (int)eapk);   // same-wave LDS: no barrier needed
    int m = min(64, deg - cb);
    int j2 = 0;
    for (; j2 + 8 <= m; j2 += 8) {
      int4 va = *(const int4*)&ed[wv][j2];
      int4 vb = *(const int4*)&ed[wv][j2 + 2];
      int4 vc = *(const int4*)&ed[wv][j2 + 4];
      int4 vd = *(const int4*)&ed[wv][j2 + 6];
      unsigned q0 = h16[((long long)va.x << 6) | lane];
      unsigned q1 = h16[((long long)va.z << 6) | lane];
      unsigned q2 = h16[((long long)vb.x << 6) | lane];
      unsigned q3 = h16[((long long)vb.z << 6) | lane];
      unsigned q4 = h16[((long long)vc.x << 6) | lane];
      unsigned q5 = h16[((long long)vc.z << 6) | lane];
      unsigned q6 = h16[((long long)vd.x << 6) | lane];
      unsigned q7 = h16[((long long)vd.z << 6) | lane];
      acc0 += bf_lo((unsigned)va.y) * bf_lo(q0); acc1 += bf_hi((unsigned)va.y) * bf_hi(q0);
      acc0 += bf_lo((unsigned)va.w) * bf_lo(q1); acc1 += bf_hi((unsigned)va.w) * bf_hi(q1);
      acc0 += bf_lo((unsigned)vb.y) * bf_lo(q2); acc1 += bf_hi((unsigned)vb.y) * bf_hi(q2);
      acc0 += bf_lo((unsigned)vb.w) * bf_lo(q3); acc1 += bf_hi((unsigned)vb.w) * bf_hi(q3);
      acc0 += bf_lo((unsigned)vc.y) * bf_lo(q4); acc1 += bf_hi((unsigned)vc.y) * bf_hi(q4);
      acc0 += bf_lo((unsigned)vc.w) * bf_lo(q5); acc1 += bf_hi((unsigned)vc.w) * bf_hi(q5);
      acc0 += bf_lo((unsigned)vd.y) * bf_lo(q6); acc1 += bf_hi((unsigned)vd.y) * bf_hi(q6);
      acc0 += bf_lo((unsigned)vd.w) * bf_lo(q7); acc1 += bf_hi((unsigned)vd.w) * bf_hi(q7);
    }
    for (; j2 < m; ++j2) {
      int2 v = ed[wv][j2];
      unsigned q = h16[((long long)v.x << 6) | lane];
      acc0 += bf_lo((unsigned)v.y) * bf_lo(q);
      acc1 += bf_hi((unsigned)v.y) * bf_hi(q);
    }
  }
  // reduce den/se partials once
  for (int off = 32; off; off >>= 1) {
    den0 += __shfl_xor(den0, off); den1 += __shfl_xor(den1, off);
    se0  += __shfl_xor(se0, off);  se1  += __shfl_xor(se1, off);
  }
  // self-loop: edge_attr = mean of incident (by dst) eattr; h row from h16.
  float id = frcp(fmaxf((float)deg, 1.0f));
  float le0 = se0 * id, le1 = se1 * id;
  float x0 = Ad.x + Ad.z + le0 * w0 + le1 * w1;
  float x1 = Ad.y + Ad.w + le0 * w2 + le1 * w3;
  x0 = x0 >= 0.f ? x0 : 0.2f * x0;
  x1 = x1 >= 0.f ? x1 : 0.2f * x1;
  float eas0 = fexp(x0), eas1 = fexp(x1);
  den0 += eas0; den1 += eas1;
  unsigned qd = h16[((long long)d << 6) | lane];
  acc0 += eas0 * bf_lo(qd);
  acc1 += eas1 * bf_hi(qd);
  float v = 0.5f * (acc0 * frcp(den0 + 1e-16f) + acc1 * frcp(den1 + 1e-16f)) + bias[lane];
  if (HEAD) {
    float pv[7];
#pragma unroll
    for (int j = 0; j < 5; ++j) pv[j] = v * Wn[lane * 5 + j];
    pv[5] = v * Wec[lane * 2];
    pv[6] = v * Wec[lane * 2 + 1];
    for (int off = 32; off; off >>= 1) {
#pragma unroll
      for (int j = 0; j < 7; ++j) pv[j] += __shfl_down(pv[j], off);
    }
    if (lane == 0) {
      float l[5]; float m = -1e30f;
#pragma unroll
      for (int j = 0; j < 5; ++j) { l[j] = pv[j] + bn[j]; m = fmaxf(m, l[j]); }
      float ssum = 0.f;
#pragma unroll
      for (int j = 0; j < 5; ++j) { l[j] = fexp(l[j] - m); ssum += l[j]; }
      float inv = frcp(ssum);
#pragma unroll
      for (int j = 0; j < 5; ++j) p_n[5 * d + j] = l[j] * inv;
      float nab0 = (ssum - l[0]) * inv;
      fgn8[d] = make_int2(__float_as_int(pv[6] - pv[5]), (int)pack_bf2(nab0, 0.f));
    }
  } else {
    if (RELU) v = fmaxf(v, 0.f);
    out[(long long)d * 64 + lane] = v;
  }
}

// eab = c / (c + exp(-t)) : one rcp, shared structure.
__device__ __forceinline__ float fg_eab(float t, float c) {
  return c * frcp(c + fexp(-t));
}

// factor-graph node-pull iteration 1. One thread per node. fgn8 = {q, bf16x2 nab}.
__global__ void k_fg_pull1(const int* __restrict__ rowptr_d, const int2* __restrict__ rec,
                           const int* __restrict__ rowptr_s, const int* __restrict__ srcnbr,
                           float* __restrict__ p_n, int2* __restrict__ fgn8,
                           const float* __restrict__ consts, int N, int E) {
  int n = blockIdx.x * blockDim.x + threadIdx.x;
  if (n >= N) return;
  int2 F = fgn8[n];
  float q = __uint_as_float((unsigned)F.x);
  float nab0 = bf_lo((unsigned)F.y);
  float avg_ef = consts[8], avg_nf = consts[9], dbec = consts[10];
  int rd0 = rowptr_d[n], rd1 = (n + 1 < N) ? rowptr_d[n + 1] : E;
  int rs0 = rowptr_s[n], rs1 = (n + 1 < N) ? rowptr_s[n + 1] : E;
  float s_eab = 0.f;
  for (int j = rd0; j < rd1; ++j) {
    int2 Fo = fgn8[rec[j].x];
    float t = 0.5f * (q + __uint_as_float((unsigned)Fo.x)) + dbec;
    float c = 1.0f + fmaxf(nab0, bf_lo((unsigned)Fo.y)) * avg_ef;
    s_eab += fg_eab(t, c);
  }
  for (int j = rs0; j < rs1; ++j) {
    int2 Fo = fgn8[srcnbr[j]];
    float t = 0.5f * (q + __uint_as_float((unsigned)Fo.x)) + dbec;
    float c = 1.0f + fmaxf(nab0, bf_lo((unsigned)Fo.y)) * avg_ef;
    s_eab += fg_eab(t, c);
  }
  float deg = (float)((rd1 - rd0) + (rs1 - rs0));
  float mean = s_eab * frcp(deg + 1e-6f);
  float f = 1.0f + mean * avg_nf;
  float p0 = p_n[5 * n], p1 = p_n[5 * n + 1], p2 = p_n[5 * n + 2],
        p3 = p_n[5 * n + 3], p4 = p_n[5 * n + 4];
  float rest = (p1 + p2 + p3 + p4) * f;
  float inv = frcp(p0 + rest);
  p_n[5 * n]     = p0 * inv;
  p_n[5 * n + 1] = p1 * f * inv;
  p_n[5 * n + 2] = p2 * f * inv;
  p_n[5 * n + 3] = p3 * f * inv;
  p_n[5 * n + 4] = p4 * f * inv;
  // update nab1; low half (nab0) bits unchanged -> safe vs concurrent readers
  fgn8[n].y = (int)pack_bf2(nab0, rest * inv);
}

// merged final pass: blocks [0, nodeBlocks) = fg iteration 2 (writes out_n);
// blocks [nodeBlocks, ...) = edge output (full odds-chain, writes out_e).
// Both only READ fgn8 - safe in one dispatch.
__global__ void k_fg_final(const int* __restrict__ rowptr_d, const int2* __restrict__ rec,
                           const int* __restrict__ rowptr_s, const int* __restrict__ srcnbr,
                           const float* __restrict__ p_n, const int2* __restrict__ fgn8,
                           const float* __restrict__ consts,
                           const int* __restrict__ src, const int* __restrict__ dst,
                           float* __restrict__ out_n, float* __restrict__ out_e,
                           int N, int E, int nodeBlocks) {
  float avg_ef = consts[8], dbec = consts[10];
  if ((int)blockIdx.x < nodeBlocks) {
    int n = blockIdx.x * blockDim.x + threadIdx.x;
    if (n >= N) return;
    float avg_nf = consts[9];
    int2 F = fgn8[n];
    float q = __uint_as_float((unsigned)F.x);
    float nab0 = bf_lo((unsigned)F.y), nab1 = bf_hi((unsigned)F.y);
    int rd0 = rowptr_d[n], rd1 = (n + 1 < N) ? rowptr_d[n + 1] : E;
    int rs0 = rowptr_s[n], rs1 = (n + 1 < N) ? rowptr_s[n + 1] : E;
    float s_eab = 0.f;
    for (int j = rd0; j < rd1; ++j) {
      int2 Fo = fgn8[rec[j].x];
      float t = 0.5f * (q + __uint_as_float((unsigned)Fo.x)) + dbec;
      float c = (1.0f + fmaxf(nab0, bf_lo((unsigned)Fo.y)) * avg_ef)
              * (1.0f + fmaxf(nab1, bf_hi((unsigned)Fo.y)) * avg_ef);
      s_eab += fg_eab(t, c);
    }
    for (int j = rs0; j < rs1; ++j) {
      int2 Fo = fgn8[srcnbr[j]];
      float t = 0.5f * (q + __uint_as_float((unsigned)Fo.x)) + dbec;
      float c = (1.0f + fmaxf(nab0, bf_lo((unsigned)Fo.y)) * avg_ef)
              * (1.0f + fmaxf(nab1, bf_hi((unsigned)Fo.y)) * avg_ef);
      s_eab += fg_eab(t, c);
    }
    float deg = (float)((rd1 - rd0) + (rs1 - rs0));
    float mean = s_eab * frcp(deg + 1e-6f);
    float f = 1.0f + mean * avg_nf;
    float p0 = p_n[5 * n], p1 = p_n[5 * n + 1], p2 = p_n[5 * n + 2],
          p3 = p_n[5 * n + 3], p4 = p_n[5 * n + 4];
    float rest = (p1 + p2 + p3 + p4) * f;
    float inv = frcp(p0 + rest);
    out_n[5 * n]     = flog(p0 * inv + 1e-9f);
    out_n[5 * n + 1] = flog(p1 * f * inv + 1e-9f);
    out_n[5 * n + 2] = flog(p2 * f * inv + 1e-9f);
    out_n[5 * n + 3] = flog(p3 * f * inv + 1e-9f);
    out_n[5 * n + 4] = flog(p4 * f * inv + 1e-9f);
  } else {
    int e = (blockIdx.x - nodeBlocks) * blockDim.x + threadIdx.x;
    if (e >= E) return;
    int2 Fs = fgn8[src[e]];
    int2 Fd = fgn8[dst[e]];
    float t = 0.5f * (__uint_as_float((unsigned)Fs.x) + __uint_as_float((unsigned)Fd.x)) + dbec;
    float c = (1.0f + fmaxf(bf_lo((unsigned)Fs.y), bf_lo((unsigned)Fd.y)) * avg_ef)
            * (1.0f + fmaxf(bf_hi((unsigned)Fs.y), bf_hi((unsigned)Fd.y)) * avg_ef);
    float ei = fexp(-t);
    float r = frcp(c + ei);
    float pe1 = c * r, pe0 = ei * r;
    *(float2*)&out_e[2 * e] = make_float2(flog(pe0 + 1e-9f), flog(pe1 + 1e-9f));
  }
}

extern "C" void kernel_launch(void* const* d_in, const int* in_sizes, int n_in,
                              void* d_out, int out_size, void* d_ws, size_t ws_size,
                              hipStream_t stream) {
  const float* x      = (const float*)d_in[0];
  const int*   ei     = (const int*)d_in[1];
  const float* eattr  = (const float*)d_in[2];
  const float* W1     = (const float*)d_in[3];
  const float* atts1  = (const float*)d_in[4];
  const float* attd1  = (const float*)d_in[5];
  const float* We1    = (const float*)d_in[6];
  const float* atte1  = (const float*)d_in[7];
  const float* b1     = (const float*)d_in[8];
  const float* W2     = (const float*)d_in[9];
  const float* atts2  = (const float*)d_in[10];
  const float* attd2  = (const float*)d_in[11];
  const float* We2    = (const float*)d_in[12];
  const float* atte2  = (const float*)d_in[13];
  const float* b2     = (const float*)d_in[14];
  const float* Wn     = (const float*)d_in[15];
  const float* bn     = (const float*)d_in[16];
  const float* Wec    = (const float*)d_in[17];
  const float* bec    = (const float*)d_in[18];
  const float* nodefw = (const float*)d_in[19];
  const float* edgefw = (const float*)d_in[20];

  const int N = in_sizes[0] / 128;
  const int E = in_sizes[1] / 2;
  const int* src = ei;
  const int* dst = ei + E;
  const int nbkt = (N + 255) >> BSH;   // 196 (assumes N <= 65536)

  float* out_n = (float*)d_out;
  float* out_e = out_n + (long long)N * 5;

  // ---- workspace carve (f32 units, 16B aligned) ----
  size_t off = 0;
  float* base = (float*)d_ws;
  auto carve = [&](size_t nelem) { float* p = base + off; off += (nelem + 3) & ~(size_t)3; return p; };
  unsigned* h16      = (unsigned*)carve((size_t)N * 64);  // aliases stage_d during prep
  float*    x2       = carve((size_t)N * 64);             // aliases stage_s during prep
  float*    asd      = carve((size_t)N * 4);
  int2*     rec      = (int2*)carve((size_t)E * 2);       // {src, bf16x2 eattr}
  int*      srcnbr   = (int*)carve((size_t)E);
  int*      rowptr_d = (int*)carve((size_t)N);
  int*      rowptr_s = (int*)carve((size_t)N);
  int*      bktcur_d = (int*)carve(256);
  int*      bktcur_s = (int*)carve(256);
  int*      bktbas_d = (int*)carve(260);
  int*      bktbas_s = (int*)carve(260);
  float*    p_n      = carve((size_t)N * 5);
  int2*     fgn8     = (int2*)carve((size_t)N * 2);
  float*    consts   = carve(16);
  float*    wext1    = carve(128 * 4);
  float*    wext2    = carve(64 * 4);
  if (off * sizeof(float) > ws_size) return;  // insufficient scratch: fail loudly

  // bucket staging aliases h16/x2 (CSR build completes before they're written):
  int4* stage_d = (int4*)h16;
  int2* stage_s = (int2*)x2;

  const int B = 256;
  const int gE  = cdiv_i(E, B);
  const int gN  = cdiv_i(N, B);

  // ---- graph prep: bucketed CSR build (both directions) ----
  hipMemsetAsync(bktcur_d, 0, 256 * 4, stream);
  hipMemsetAsync(bktcur_s, 0, 256 * 4, stream);
  k_prep_consts<<<1, 64, 0, stream>>>(We1, atte1, We2, atte2, nodefw, edgefw, bec, consts);
  k_prep_wext<<<1, 256, 0, stream>>>(W1, atts1, attd1, W2, atts2, attd2, wext1, wext2);
  k_bkt_hist<<<256, 256, 0, stream>>>(src, dst, bktcur_d, bktcur_s, nbkt, E);
  k_bkt_scan<<<1, 256, 0, stream>>>(bktcur_d, bktbas_d, bktcur_s, bktbas_s, nbkt);
  k_bkt_scatter<<<cdiv_i(E, 256 * CBK), 256, 0, stream>>>(src, dst, eattr, bktcur_d, bktcur_s,
                                                          stage_d, stage_s, nbkt, E);
  k_bkt_sort_d<<<nbkt, 256, 0, stream>>>(stage_d, bktbas_d, rowptr_d, rec, N);
  k_bkt_sort_s<<<nbkt, 256, 0, stream>>>(stage_s, bktbas_s, rowptr_s, srcnbr, N);

  // ---- GAT layer 1 (gemm writes h16+asd; pull writes x2) ----
  k_gemm_att<128><<<cdiv_i(N, 64), 256, 0, stream>>>(x, W1, wext1, h16, asd, N);
  k_gat_pull<true, false><<<cdiv_i(N, 4), 256, 0, stream>>>(
      rowptr_d, rec, asd, h16, consts, b1,
      nullptr, nullptr, nullptr, x2, nullptr, nullptr, N, E);

  // ---- GAT layer 2 (+ fused heads) ----
  k_gemm_att<64><<<cdiv_i(N, 64), 256, 0, stream>>>(x2, W2, wext2, h16, asd, N);
  k_gat_pull<false, true><<<cdiv_i(N, 4), 256, 0, stream>>>(
      rowptr_d, rec, asd, h16, consts + 4, b2,
      Wn, bn, Wec, nullptr, p_n, fgn8, N, E);

  // ---- factor graph: iter1 + merged (iter2 + edge output) ----
  k_fg_pull1<<<gN, B, 0, stream>>>(rowptr_d, rec, rowptr_s, srcnbr,
                                   p_n, fgn8, consts, N, E);
  k_fg_final<<<gN + gE, B, 0, stream>>>(rowptr_d, rec, rowptr_s, srcnbr,
                                        p_n, fgn8, consts, src, dst,
                                        out_n, out_e, N, E, gN);
}

// Round 11
// 278.358 us; speedup vs baseline: 1.3254x; 1.0892x over previous
//
#include <hip/hip_runtime.h>
#include <math.h>

// GraphRespiratory: 2-layer GAT (edge features, concat=False) + factor graph.
// N=50000, E=800000, IN=128, HID=OUT=64, H=2, NC=5, EC=2, NUM_ITER=2, GAMMA=1.
//
// R10 changes vs R9:
//  - GEMMs moved to MFMA (v_mfma_f32_16x16x32_bf16), LDS-free: per block 4
//    waves x (16 rows x 128 cols + attention cols). W+wext pre-swizzled once
//    into fragment order (k_prep_wfrag, 54KB, L2-resident); A loaded straight
//    to VGPRs and converted to bf16. Attention dots = 9th col-tile.
//  - Fragment maps (guide §3, m89): A row=lane&15,k=(lane>>4)*8+j;
//    B col=lane&15,same k; D col=lane&15,row=(lane>>4)*4+reg.

static inline int cdiv_i(long long a, long long b) { return (int)((a + b - 1) / b); }

#define BSH 8           // bucket shift: 256 nodes per bucket
#define CBK 8           // edges per thread in bucket scatter (2048/block)

typedef __attribute__((ext_vector_type(8))) short bf16x8s;
typedef __attribute__((ext_vector_type(4))) float f32x4;

__device__ __forceinline__ float fexp(float x) {
  return __builtin_amdgcn_exp2f(x * 1.44269504088896f);
}
__device__ __forceinline__ float flog(float x) {
  return __builtin_amdgcn_logf(x) * 0.693147180559945f;
}
__device__ __forceinline__ float frcp(float x) {
  return __builtin_amdgcn_rcpf(x);
}

__device__ __forceinline__ unsigned short bf16r(float x) {
  unsigned u = __float_as_uint(x);
  return (unsigned short)((u + 0x7fffu + ((u >> 16) & 1u)) >> 16);
}
__device__ __forceinline__ unsigned pack_bf2(float a, float b) {
  unsigned ua = __float_as_uint(a), ub = __float_as_uint(b);
  unsigned ra = (ua + 0x7fffu + ((ua >> 16) & 1u)) >> 16;
  unsigned rb = (ub + 0x7fffu + ((ub >> 16) & 1u)) & 0xffff0000u;
  return ra | rb;
}
__device__ __forceinline__ float bf_lo(unsigned v) { return __uint_as_float(v << 16); }
__device__ __forceinline__ float bf_hi(unsigned v) { return __uint_as_float(v & 0xffff0000u); }

// consts: [0..3] w_e1[h][k], [4..7] w_e2[h][k], [8] avg_ef, [9] avg_nf, [10] dbec
__global__ void k_prep_consts(const float* __restrict__ We1, const float* __restrict__ att_e1,
                              const float* __restrict__ We2, const float* __restrict__ att_e2,
                              const float* __restrict__ node_fw, const float* __restrict__ edge_fw,
                              const float* __restrict__ bec, float* __restrict__ consts) {
  if (blockIdx.x != 0 || threadIdx.x != 0) return;
  for (int h = 0; h < 2; ++h) {
    for (int k = 0; k < 2; ++k) {
      float s1 = 0.f, s2 = 0.f;
      for (int c = 0; c < 64; ++c) {
        s1 += We1[k * 128 + h * 64 + c] * att_e1[h * 64 + c];
        s2 += We2[k * 128 + h * 64 + c] * att_e2[h * 64 + c];
      }
      consts[h * 2 + k] = s1;
      consts[4 + h * 2 + k] = s2;
    }
  }
  float ef = 0.f;                      // edge_fw is [EC=2, NC=5]; mean of [1:,1:]
  for (int j = 1; j < 5; ++j) ef += edge_fw[5 + j];
  consts[8] = ef * 0.25f;
  float nf = 0.f;                      // node_fw is [NC=5, EC=2]; mean of [1:,1:]
  for (int i = 1; i < 5; ++i) nf += node_fw[i * 2 + 1];
  consts[9] = nf * 0.25f;
  consts[10] = bec[1] - bec[0];
}

// wext[k][ac]: ac 0/1 = att_src head0/1, 2/3 = att_dst head0/1. One block.
__global__ void k_prep_wext(const float* __restrict__ W1, const float* __restrict__ as1,
                            const float* __restrict__ ad1,
                            const float* __restrict__ W2, const float* __restrict__ as2,
                            const float* __restrict__ ad2,
                            float* __restrict__ wext1, float* __restrict__ wext2) {
  int t = threadIdx.x;
  for (int o = t; o < 128 * 4; o += 256) {
    int k = o >> 2, j = o & 3;
    const float* att = (j < 2 ? as1 : ad1) + (j & 1) * 64;
    const float* wr = W1 + k * 128 + (j & 1) * 64;
    float s = 0.f;
    for (int c = 0; c < 64; ++c) s += wr[c] * att[c];
    wext1[o] = s;
  }
  for (int o = t; o < 64 * 4; o += 256) {
    int k = o >> 2, j = o & 3;
    const float* att = (j < 2 ? as2 : ad2) + (j & 1) * 64;
    const float* wr = W2 + k * 128 + (j & 1) * 64;
    float s = 0.f;
    for (int c = 0; c < 64; ++c) s += wr[c] * att[c];
    wext2[o] = s;
  }
}

// Pre-swizzle W (+wext as col-tile 8) into MFMA B-fragment order, bf16.
// wf layout: [K/32][9][64 lanes][8 j]; element = W[kc+(lane>>4)*8+j][ct*16+(lane&15)]
__global__ void k_prep_wfrag(const float* __restrict__ W1, const float* __restrict__ wext1,
                             const float* __restrict__ W2, const float* __restrict__ wext2,
                             unsigned short* __restrict__ wf1, unsigned short* __restrict__ wf2) {
  int t = threadIdx.x;
  for (int o = t; o < 4 * 9 * 512; o += 256) {       // K=128
    int kc = o / (9 * 512), rem = o % (9 * 512);
    int ct = rem / 512, li = rem % 512;
    int lane = li >> 3, j = li & 7;
    int k = kc * 32 + ((lane >> 4) << 3) + j, c = lane & 15;
    float v = (ct < 8) ? W1[k * 128 + ct * 16 + c] : (c < 4 ? wext1[k * 4 + c] : 0.f);
    wf1[o] = bf16r(v);
  }
  for (int o = t; o < 2 * 9 * 512; o += 256) {       // K=64
    int kc = o / (9 * 512), rem = o % (9 * 512);
    int ct = rem / 512, li = rem % 512;
    int lane = li >> 3, j = li & 7;
    int k = kc * 32 + ((lane >> 4) << 3) + j, c = lane & 15;
    float v = (ct < 8) ? W2[k * 128 + ct * 16 + c] : (c < 4 ? wext2[k * 4 + c] : 0.f);
    wf2[o] = bf16r(v);
  }
}

// ---- bucketed CSR build ----
__global__ void k_bkt_hist(const int* __restrict__ src, const int* __restrict__ dst,
                           int* __restrict__ hist_d, int* __restrict__ hist_s,
                           int nbkt, int E) {
  __shared__ int hd[256], hs[256];
  int t = threadIdx.x;
  hd[t] = 0; hs[t] = 0;
  __syncthreads();
  for (int e = blockIdx.x * blockDim.x + t; e < E; e += gridDim.x * blockDim.x) {
    atomicAdd(&hd[dst[e] >> BSH], 1);
    atomicAdd(&hs[src[e] >> BSH], 1);
  }
  __syncthreads();
  if (t < nbkt) {
    if (hd[t]) atomicAdd(&hist_d[t], hd[t]);
    if (hs[t]) atomicAdd(&hist_s[t], hs[t]);
  }
}

// one block: exclusive-scan both histograms -> bases (nbkt+1) and cursors (in place)
__global__ void k_bkt_scan(int* __restrict__ cur_d, int* __restrict__ base_d,
                           int* __restrict__ cur_s, int* __restrict__ base_s, int nbkt) {
  __shared__ int l[256];
  int t = threadIdx.x;
  int v = (t < nbkt) ? cur_d[t] : 0;
  l[t] = v; __syncthreads();
  for (int off = 1; off < 256; off <<= 1) {
    int x = (t >= off) ? l[t - off] : 0; __syncthreads();
    l[t] += x; __syncthreads();
  }
  int incl = l[t];
  if (t < nbkt) { base_d[t] = incl - v; cur_d[t] = incl - v; }
  if (t == nbkt - 1) base_d[nbkt] = incl;
  __syncthreads();
  v = (t < nbkt) ? cur_s[t] : 0;
  l[t] = v; __syncthreads();
  for (int off = 1; off < 256; off <<= 1) {
    int x = (t >= off) ? l[t - off] : 0; __syncthreads();
    l[t] += x; __syncthreads();
  }
  incl = l[t];
  if (t < nbkt) { base_s[t] = incl - v; cur_s[t] = incl - v; }
  if (t == nbkt - 1) base_s[nbkt] = incl;
}

// block-staged bucket scatter: 2048 edges/block in regs; LDS per-bucket counts;
// one global atomicAdd per (bucket,block) to reserve; chunky tail writes.
__global__ __launch_bounds__(256)
void k_bkt_scatter(const int* __restrict__ src, const int* __restrict__ dst,
                   const float* __restrict__ eattr2,
                   int* __restrict__ cur_d, int* __restrict__ cur_s,
                   int4* __restrict__ stage_d, int2* __restrict__ stage_s,
                   int nbkt, int E) {
  __shared__ int cd[256], cs[256], bd[256], bs[256];
  int t = threadIdx.x;
  cd[t] = 0; cs[t] = 0;
  __syncthreads();
  int base = blockIdx.x * 256 * CBK;
  int s[CBK], d[CBK]; unsigned ep[CBK];
#pragma unroll
  for (int c = 0; c < CBK; ++c) {
    int e = base + c * 256 + t;
    if (e < E) {
      s[c] = src[e]; d[c] = dst[e];
      float2 ev = *(const float2*)&eattr2[2 * e];
      ep[c] = pack_bf2(ev.x, ev.y);
      atomicAdd(&cd[d[c] >> BSH], 1);
      atomicAdd(&cs[s[c] >> BSH], 1);
    } else s[c] = -1;
  }
  __syncthreads();
  if (t < nbkt) {
    bd[t] = cd[t] ? atomicAdd(&cur_d[t], cd[t]) : 0;
    bs[t] = cs[t] ? atomicAdd(&cur_s[t], cs[t]) : 0;
    cd[t] = 0; cs[t] = 0;
  }
  __syncthreads();
#pragma unroll
  for (int c = 0; c < CBK; ++c) {
    if (s[c] < 0) continue;
    int db = d[c] >> BSH, sb = s[c] >> BSH;
    int pos = bd[db] + atomicAdd(&cd[db], 1);
    stage_d[pos] = make_int4(s[c], d[c], (int)ep[c], 0);
    int pos2 = bs[sb] + atomicAdd(&cs[sb], 1);
    stage_s[pos2] = make_int2(s[c], d[c]);
  }
}

// per-bucket counting sort (dst side): emits rowptr_d + final rec {src, bf16x2 eattr}.
__global__ __launch_bounds__(256)
void k_bkt_sort_d(const int4* __restrict__ stage, const int* __restrict__ base,
                  int* __restrict__ rowptr, int2* __restrict__ rec, int N) {
  int b = blockIdx.x, t = threadIdx.x;
  int nlo = b << BSH;
  int b0 = base[b], b1 = base[b + 1];
  __shared__ int cnt[256], cur[256], l[256];
  cnt[t] = 0;
  __syncthreads();
  for (int j = b0 + t; j < b1; j += 256)
    atomicAdd(&cnt[stage[j].y - nlo], 1);
  __syncthreads();
  int v = cnt[t];
  l[t] = v; __syncthreads();
  for (int off = 1; off < 256; off <<= 1) {
    int x = (t >= off) ? l[t - off] : 0; __syncthreads();
    l[t] += x; __syncthreads();
  }
  int excl = l[t] - v;
  if (nlo + t < N) rowptr[nlo + t] = b0 + excl;
  cur[t] = excl;
  __syncthreads();
  for (int j = b0 + t; j < b1; j += 256) {
    int4 r = stage[j];
    int pos = b0 + atomicAdd(&cur[r.y - nlo], 1);
    rec[pos] = make_int2(r.x, r.z);
  }
}

// per-bucket counting sort (src side): emits rowptr_s + srcnbr (payload = dst).
__global__ __launch_bounds__(256)
void k_bkt_sort_s(const int2* __restrict__ stage, const int* __restrict__ base,
                  int* __restrict__ rowptr, int* __restrict__ srcnbr, int N) {
  int b = blockIdx.x, t = threadIdx.x;
  int nlo = b << BSH;
  int b0 = base[b], b1 = base[b + 1];
  __shared__ int cnt[256], cur[256], l[256];
  cnt[t] = 0;
  __syncthreads();
  for (int j = b0 + t; j < b1; j += 256)
    atomicAdd(&cnt[stage[j].x - nlo], 1);
  __syncthreads();
  int v = cnt[t];
  l[t] = v; __syncthreads();
  for (int off = 1; off < 256; off <<= 1) {
    int x = (t >= off) ? l[t - off] : 0; __syncthreads();
    l[t] += x; __syncthreads();
  }
  int excl = l[t] - v;
  if (nlo + t < N) rowptr[nlo + t] = b0 + excl;
  cur[t] = excl;
  __syncthreads();
  for (int j = b0 + t; j < b1; j += 256) {
    int2 r = stage[j];
    int pos = b0 + atomicAdd(&cur[r.x - nlo], 1);
    srcnbr[pos] = r.y;
  }
}

// MFMA GEMM + attention columns. A[N][K] f32 -> bf16 in-reg; Wf pre-swizzled
// B-fragments (9 col-tiles: 8 of W + 1 of wext). Block = 4 waves x 16 rows.
// Outputs h16[n][64] (packed head pairs) + asd[n][4]. No LDS, no barriers.
template<int K>
__global__ __launch_bounds__(256)
void k_gemm_att_mfma(const float* __restrict__ A, const unsigned short* __restrict__ Wf,
                     unsigned* __restrict__ h16, float* __restrict__ asd, int N) {
  int wv = threadIdx.x >> 6, lane = threadIdx.x & 63;
  int r0 = blockIdx.x * 64 + wv * 16;
  int arow = r0 + (lane & 15);
  int kbase = (lane >> 4) * 8;
  f32x4 acc[9];
#pragma unroll
  for (int ct = 0; ct < 9; ++ct) acc[ct] = (f32x4){0.f, 0.f, 0.f, 0.f};

#pragma unroll
  for (int kc = 0; kc < K; kc += 32) {
    float4 v0 = make_float4(0.f, 0.f, 0.f, 0.f);
    float4 v1 = make_float4(0.f, 0.f, 0.f, 0.f);
    if (arow < N) {
      const float* ap = A + (long long)arow * K + kc + kbase;
      v0 = *(const float4*)ap;
      v1 = *(const float4*)(ap + 4);
    }
    bf16x8s a;
    a[0] = (short)bf16r(v0.x); a[1] = (short)bf16r(v0.y);
    a[2] = (short)bf16r(v0.z); a[3] = (short)bf16r(v0.w);
    a[4] = (short)bf16r(v1.x); a[5] = (short)bf16r(v1.y);
    a[6] = (short)bf16r(v1.z); a[7] = (short)bf16r(v1.w);
    const unsigned short* wp = Wf + (size_t)(kc >> 5) * 9 * 512 + lane * 8;
#pragma unroll
    for (int ct = 0; ct < 9; ++ct) {
      bf16x8s b = *(const bf16x8s*)(wp + ct * 512);
      acc[ct] = __builtin_amdgcn_mfma_f32_16x16x32_bf16(a, b, acc[ct], 0, 0, 0);
    }
  }
  // D layout: col = lane&15, row = (lane>>4)*4 + reg
  int c = lane & 15;
  int orow = r0 + (lane >> 4) * 4;
#pragma unroll
  for (int r = 0; r < 4; ++r) {
    int gr = orow + r;
    if (gr >= N) continue;
#pragma unroll
    for (int ct = 0; ct < 4; ++ct)
      h16[((long long)gr << 6) | (ct * 16 + c)] = pack_bf2(acc[ct][r], acc[ct + 4][r]);
    if (c < 4) asd[gr * 4 + c] = acc[8][r];
  }
}

// Fused GAT edge phase, pull-mode. One wave per dst node.
// Phase A results staged in per-wave LDS; phase B uses uniform-address int4
// broadcast reads. HEAD: fuse heads into the epilogue.
template<bool RELU, bool HEAD>
__global__ __launch_bounds__(256)
void k_gat_pull(const int* __restrict__ rowptr, const int2* __restrict__ rec,
                const float* __restrict__ asd, const unsigned* __restrict__ h16,
                const float* __restrict__ we, const float* __restrict__ bias,
                const float* __restrict__ Wn, const float* __restrict__ bn,
                const float* __restrict__ Wec,
                float* __restrict__ out, float* __restrict__ p_n,
                int2* __restrict__ fgn8, int N, int E) {
  __shared__ int2 ed[4][64];
  int wv = threadIdx.x >> 6, lane = threadIdx.x & 63;
  int d = blockIdx.x * 4 + wv;
  if (d >= N) return;
  int r0 = rowptr[d];
  int r1 = (d + 1 < N) ? rowptr[d + 1] : E;
  int deg = r1 - r0;
  float4 Ad = *(const float4*)&asd[4 * d];
  float w0 = we[0], w1 = we[1], w2 = we[2], w3 = we[3];
  float den0 = 0.f, den1 = 0.f, acc0 = 0.f, acc1 = 0.f, se0 = 0.f, se1 = 0.f;
  for (int cb = 0; cb < deg; cb += 64) {
    int j = cb + lane;
    int s = 0; unsigned eapk = 0;
    if (j < deg) {
      int2 rc = rec[r0 + j];
      s = rc.x;
      unsigned ep = (unsigned)rc.y;
      float e0 = bf_lo(ep), e1 = bf_hi(ep);
      float4 As = *(const float4*)&asd[4 * s];
      float x0 = As.x + Ad.z + e0 * w0 + e1 * w1;
      float x1 = As.y + Ad.w + e0 * w2 + e1 * w3;
      x0 = x0 >= 0.f ? x0 : 0.2f * x0;
      x1 = x1 >= 0.f ? x1 : 0.2f * x1;
      float ea0 = fexp(x0), ea1 = fexp(x1);
      eapk = pack_bf2(ea0, ea1);
      den0 += ea0; den1 += ea1; se0 += e0; se1 += e1;
    }
    ed[wv][lane] = make_int2(s, (int)eapk);   // same-wave LDS: no barrier needed
    int m = min(64, deg - cb);
    int j2 = 0;
    for (; j2 + 8 <= m; j2 += 8) {
      int4 va = *(const int4*)&ed[wv][j2];
      int4 vb = *(const int4*)&ed[wv][j2 + 2];
      int4 vc = *(const int4*)&ed[wv][j2 + 4];
      int4 vd = *(const int4*)&ed[wv][j2 + 6];
      unsigned q0 = h16[((long long)va.x << 6) | lane];
      unsigned q1 = h16[((long long)va.z << 6) | lane];
      unsigned q2 = h16[((long long)vb.x << 6) | lane];
      unsigned q3 = h16[((long long)vb.z << 6) | lane];
      unsigned q4 = h16[((long long)vc.x << 6) | lane];
      unsigned q5 = h16[((long long)vc.z << 6) | lane];
      unsigned q6 = h16[((long long)vd.x << 6) | lane];
      unsigned q7 = h16[((long long)vd.z << 6) | lane];
      acc0 += bf_lo((unsigned)va.y) * bf_lo(q0); acc1 += bf_hi((unsigned)va.y) * bf_hi(q0);
      acc0 += bf_lo((unsigned)va.w) * bf_lo(q1); acc1 += bf_hi((unsigned)va.w) * bf_hi(q1);
      acc0 += bf_lo((unsigned)vb.y) * bf_lo(q2); acc1 += bf_hi((unsigned)vb.y) * bf_hi(q2);
      acc0 += bf_lo((unsigned)vb.w) * bf_lo(q3); acc1 += bf_hi((unsigned)vb.w) * bf_hi(q3);
      acc0 += bf_lo((unsigned)vc.y) * bf_lo(q4); acc1 += bf_hi((unsigned)vc.y) * bf_hi(q4);
      acc0 += bf_lo((unsigned)vc.w) * bf_lo(q5); acc1 += bf_hi((unsigned)vc.w) * bf_hi(q5);
      acc0 += bf_lo((unsigned)vd.y) * bf_lo(q6); acc1 += bf_hi((unsigned)vd.y) * bf_hi(q6);
      acc0 += bf_lo((unsigned)vd.w) * bf_lo(q7); acc1 += bf_hi((unsigned)vd.w) * bf_hi(q7);
    }
    for (; j2 < m; ++j2) {
      int2 v = ed[wv][j2];
      unsigned q = h16[((long long)v.x << 6) | lane];
      acc0 += bf_lo((unsigned)v.y) * bf_lo(q);
      acc1 += bf_hi((unsigned)v.y) * bf_hi(q);
    }
  }
  for (int off = 32; off; off >>= 1) {
    den0 += __shfl_xor(den0, off); den1 += __shfl_xor(den1, off);
    se0  += __shfl_xor(se0, off);  se1  += __shfl_xor(se1, off);
  }
  float id = frcp(fmaxf((float)deg, 1.0f));
  float le0 = se0 * id, le1 = se1 * id;
  float x0 = Ad.x + Ad.z + le0 * w0 + le1 * w1;
  float x1 = Ad.y + Ad.w + le0 * w2 + le1 * w3;
  x0 = x0 >= 0.f ? x0 : 0.2f * x0;
  x1 = x1 >= 0.f ? x1 : 0.2f * x1;
  float eas0 = fexp(x0), eas1 = fexp(x1);
  den0 += eas0; den1 += eas1;
  unsigned qd = h16[((long long)d << 6) | lane];
  acc0 += eas0 * bf_lo(qd);
  acc1 += eas1 * bf_hi(qd);
  float v = 0.5f * (acc0 * frcp(den0 + 1e-16f) + acc1 * frcp(den1 + 1e-16f)) + bias[lane];
  if (HEAD) {
    float pv[7];
#pragma unroll
    for (int j = 0; j < 5; ++j) pv[j] = v * Wn[lane * 5 + j];
    pv[5] = v * Wec[lane * 2];
    pv[6] = v * Wec[lane * 2 + 1];
    for (int off = 32; off; off >>= 1) {
#pragma unroll
      for (int j = 0; j < 7; ++j) pv[j] += __shfl_down(pv[j], off);
    }
    if (lane == 0) {
      float l[5]; float m = -1e30f;
#pragma unroll
      for (int j = 0; j < 5; ++j) { l[j] = pv[j] + bn[j]; m = fmaxf(m, l[j]); }
      float ssum = 0.f;
#pragma unroll
      for (int j = 0; j < 5; ++j) { l[j] = fexp(l[j] - m); ssum += l[j]; }
      float inv = frcp(ssum);
#pragma unroll
      for (int j = 0; j < 5; ++j) p_n[5 * d + j] = l[j] * inv;
      float nab0 = (ssum - l[0]) * inv;
      fgn8[d] = make_int2(__float_as_int(pv[6] - pv[5]), (int)pack_bf2(nab0, 0.f));
    }
  } else {
    if (RELU) v = fmaxf(v, 0.f);
    out[(long long)d * 64 + lane] = v;
  }
}

// eab = c / (c + exp(-t)) : one rcp, shared structure.
__device__ __forceinline__ float fg_eab(float t, float c) {
  return c * frcp(c + fexp(-t));
}

// factor-graph node-pull iteration 1. One thread per node. fgn8 = {q, bf16x2 nab}.
__global__ void k_fg_pull1(const int* __restrict__ rowptr_d, const int2* __restrict__ rec,
                           const int* __restrict__ rowptr_s, const int* __restrict__ srcnbr,
                           float* __restrict__ p_n, int2* __restrict__ fgn8,
                           const float* __restrict__ consts, int N, int E) {
  int n = blockIdx.x * blockDim.x + threadIdx.x;
  if (n >= N) return;
  int2 F = fgn8[n];
  float q = __uint_as_float((unsigned)F.x);
  float nab0 = bf_lo((unsigned)F.y);
  float avg_ef = consts[8], avg_nf = consts[9], dbec = consts[10];
  int rd0 = rowptr_d[n], rd1 = (n + 1 < N) ? rowptr_d[n + 1] : E;
  int rs0 = rowptr_s[n], rs1 = (n + 1 < N) ? rowptr_s[n + 1] : E;
  float s_eab = 0.f;
  for (int j = rd0; j < rd1; ++j) {
    int2 Fo = fgn8[rec[j].x];
    float t = 0.5f * (q + __uint_as_float((unsigned)Fo.x)) + dbec;
    float c = 1.0f + fmaxf(nab0, bf_lo((unsigned)Fo.y)) * avg_ef;
    s_eab += fg_eab(t, c);
  }
  for (int j = rs0; j < rs1; ++j) {
    int2 Fo = fgn8[srcnbr[j]];
    float t = 0.5f * (q + __uint_as_float((unsigned)Fo.x)) + dbec;
    float c = 1.0f + fmaxf(nab0, bf_lo((unsigned)Fo.y)) * avg_ef;
    s_eab += fg_eab(t, c);
  }
  float deg = (float)((rd1 - rd0) + (rs1 - rs0));
  float mean = s_eab * frcp(deg + 1e-6f);
  float f = 1.0f + mean * avg_nf;
  float p0 = p_n[5 * n], p1 = p_n[5 * n + 1], p2 = p_n[5 * n + 2],
        p3 = p_n[5 * n + 3], p4 = p_n[5 * n + 4];
  float rest = (p1 + p2 + p3 + p4) * f;
  float inv = frcp(p0 + rest);
  p_n[5 * n]     = p0 * inv;
  p_n[5 * n + 1] = p1 * f * inv;
  p_n[5 * n + 2] = p2 * f * inv;
  p_n[5 * n + 3] = p3 * f * inv;
  p_n[5 * n + 4] = p4 * f * inv;
  fgn8[n].y = (int)pack_bf2(nab0, rest * inv);
}

// merged final pass: blocks [0, nodeBlocks) = fg iteration 2 (writes out_n);
// blocks [nodeBlocks, ...) = edge output. Both only READ fgn8.
__global__ void k_fg_final(const int* __restrict__ rowptr_d, const int2* __restrict__ rec,
                           const int* __restrict__ rowptr_s, const int* __restrict__ srcnbr,
                           const float* __restrict__ p_n, const int2* __restrict__ fgn8,
                           const float* __restrict__ consts,
                           const int* __restrict__ src, const int* __restrict__ dst,
                           float* __restrict__ out_n, float* __restrict__ out_e,
                           int N, int E, int nodeBlocks) {
  float avg_ef = consts[8], dbec = consts[10];
  if ((int)blockIdx.x < nodeBlocks) {
    int n = blockIdx.x * blockDim.x + threadIdx.x;
    if (n >= N) return;
    float avg_nf = consts[9];
    int2 F = fgn8[n];
    float q = __uint_as_float((unsigned)F.x);
    float nab0 = bf_lo((unsigned)F.y), nab1 = bf_hi((unsigned)F.y);
    int rd0 = rowptr_d[n], rd1 = (n + 1 < N) ? rowptr_d[n + 1] : E;
    int rs0 = rowptr_s[n], rs1 = (n + 1 < N) ? rowptr_s[n + 1] : E;
    float s_eab = 0.f;
    for (int j = rd0; j < rd1; ++j) {
      int2 Fo = fgn8[rec[j].x];
      float t = 0.5f * (q + __uint_as_float((unsigned)Fo.x)) + dbec;
      float c = (1.0f + fmaxf(nab0, bf_lo((unsigned)Fo.y)) * avg_ef)
              * (1.0f + fmaxf(nab1, bf_hi((unsigned)Fo.y)) * avg_ef);
      s_eab += fg_eab(t, c);
    }
    for (int j = rs0; j < rs1; ++j) {
      int2 Fo = fgn8[srcnbr[j]];
      float t = 0.5f * (q + __uint_as_float((unsigned)Fo.x)) + dbec;
      float c = (1.0f + fmaxf(nab0, bf_lo((unsigned)Fo.y)) * avg_ef)
              * (1.0f + fmaxf(nab1, bf_hi((unsigned)Fo.y)) * avg_ef);
      s_eab += fg_eab(t, c);
    }
    float deg = (float)((rd1 - rd0) + (rs1 - rs0));
    float mean = s_eab * frcp(deg + 1e-6f);
    float f = 1.0f + mean * avg_nf;
    float p0 = p_n[5 * n], p1 = p_n[5 * n + 1], p2 = p_n[5 * n + 2],
          p3 = p_n[5 * n + 3], p4 = p_n[5 * n + 4];
    float rest = (p1 + p2 + p3 + p4) * f;
    float inv = frcp(p0 + rest);
    out_n[5 * n]     = flog(p0 * inv + 1e-9f);
    out_n[5 * n + 1] = flog(p1 * f * inv + 1e-9f);
    out_n[5 * n + 2] = flog(p2 * f * inv + 1e-9f);
    out_n[5 * n + 3] = flog(p3 * f * inv + 1e-9f);
    out_n[5 * n + 4] = flog(p4 * f * inv + 1e-9f);
  } else {
    int e = (blockIdx.x - nodeBlocks) * blockDim.x + threadIdx.x;
    if (e >= E) return;
    int2 Fs = fgn8[src[e]];
    int2 Fd = fgn8[dst[e]];
    float t = 0.5f * (__uint_as_float((unsigned)Fs.x) + __uint_as_float((unsigned)Fd.x)) + dbec;
    float c = (1.0f + fmaxf(bf_lo((unsigned)Fs.y), bf_lo((unsigned)Fd.y)) * avg_ef)
            * (1.0f + fmaxf(bf_hi((unsigned)Fs.y), bf_hi((unsigned)Fd.y)) * avg_ef);
    float ei = fexp(-t);
    float r = frcp(c + ei);
    float pe1 = c * r, pe0 = ei * r;
    *(float2*)&out_e[2 * e] = make_float2(flog(pe0 + 1e-9f), flog(pe1 + 1e-9f));
  }
}

extern "C" void kernel_launch(void* const* d_in, const int* in_sizes, int n_in,
                              void* d_out, int out_size, void* d_ws, size_t ws_size,
                              hipStream_t stream) {
  const float* x      = (const float*)d_in[0];
  const int*   ei     = (const int*)d_in[1];
  const float* eattr  = (const float*)d_in[2];
  const float* W1     = (const float*)d_in[3];
  const float* atts1  = (const float*)d_in[4];
  const float* attd1  = (const float*)d_in[5];
  const float* We1    = (const float*)d_in[6];
  const float* atte1  = (const float*)d_in[7];
  const float* b1     = (const float*)d_in[8];
  const float* W2     = (const float*)d_in[9];
  const float* atts2  = (const float*)d_in[10];
  const float* attd2  = (const float*)d_in[11];
  const float* We2    = (const float*)d_in[12];
  const float* atte2  = (const float*)d_in[13];
  const float* b2     = (const float*)d_in[14];
  const float* Wn     = (const float*)d_in[15];
  const float* bn     = (const float*)d_in[16];
  const float* Wec    = (const float*)d_in[17];
  const float* bec    = (const float*)d_in[18];
  const float* nodefw = (const float*)d_in[19];
  const float* edgefw = (const float*)d_in[20];

  const int N = in_sizes[0] / 128;
  const int E = in_sizes[1] / 2;
  const int* src = ei;
  const int* dst = ei + E;
  const int nbkt = (N + 255) >> BSH;   // 196 (assumes N <= 65536)

  float* out_n = (float*)d_out;
  float* out_e = out_n + (long long)N * 5;

  // ---- workspace carve (f32 units, 16B aligned) ----
  size_t off = 0;
  float* base = (float*)d_ws;
  auto carve = [&](size_t nelem) { float* p = base + off; off += (nelem + 3) & ~(size_t)3; return p; };
  unsigned* h16      = (unsigned*)carve((size_t)N * 64);  // aliases stage_d during prep
  float*    x2       = carve((size_t)N * 64);             // aliases stage_s during prep
  float*    asd      = carve((size_t)N * 4);
  int2*     rec      = (int2*)carve((size_t)E * 2);       // {src, bf16x2 eattr}
  int*      srcnbr   = (int*)carve((size_t)E);
  int*      rowptr_d = (int*)carve((size_t)N);
  int*      rowptr_s = (int*)carve((size_t)N);
  int*      bktcur_d = (int*)carve(256);
  int*      bktcur_s = (int*)carve(256);
  int*      bktbas_d = (int*)carve(260);
  int*      bktbas_s = (int*)carve(260);
  float*    p_n      = carve((size_t)N * 5);
  int2*     fgn8     = (int2*)carve((size_t)N * 2);
  float*    consts   = carve(16);
  float*    wext1    = carve(128 * 4);
  float*    wext2    = carve(64 * 4);
  unsigned short* wf1 = (unsigned short*)carve(9216);     // 4*9*512 bf16
  unsigned short* wf2 = (unsigned short*)carve(4608);     // 2*9*512 bf16
  if (off * sizeof(float) > ws_size) return;  // insufficient scratch: fail loudly

  // bucket staging aliases h16/x2 (CSR build completes before they're written):
  int4* stage_d = (int4*)h16;
  int2* stage_s = (int2*)x2;

  const int B = 256;
  const int gE  = cdiv_i(E, B);
  const int gN  = cdiv_i(N, B);

  // ---- graph prep: bucketed CSR build (both directions) ----
  hipMemsetAsync(bktcur_d, 0, 256 * 4, stream);
  hipMemsetAsync(bktcur_s, 0, 256 * 4, stream);
  k_prep_consts<<<1, 64, 0, stream>>>(We1, atte1, We2, atte2, nodefw, edgefw, bec, consts);
  k_prep_wext<<<1, 256, 0, stream>>>(W1, atts1, attd1, W2, atts2, attd2, wext1, wext2);
  k_prep_wfrag<<<1, 256, 0, stream>>>(W1, wext1, W2, wext2, wf1, wf2);
  k_bkt_hist<<<256, 256, 0, stream>>>(src, dst, bktcur_d, bktcur_s, nbkt, E);
  k_bkt_scan<<<1, 256, 0, stream>>>(bktcur_d, bktbas_d, bktcur_s, bktbas_s, nbkt);
  k_bkt_scatter<<<cdiv_i(E, 256 * CBK), 256, 0, stream>>>(src, dst, eattr, bktcur_d, bktcur_s,
                                                          stage_d, stage_s, nbkt, E);
  k_bkt_sort_d<<<nbkt, 256, 0, stream>>>(stage_d, bktbas_d, rowptr_d, rec, N);
  k_bkt_sort_s<<<nbkt, 256, 0, stream>>>(stage_s, bktbas_s, rowptr_s, srcnbr, N);

  // ---- GAT layer 1 (gemm writes h16+asd; pull writes x2) ----
  k_gemm_att_mfma<128><<<cdiv_i(N, 64), 256, 0, stream>>>(x, wf1, h16, asd, N);
  k_gat_pull<true, false><<<cdiv_i(N, 4), 256, 0, stream>>>(
      rowptr_d, rec, asd, h16, consts, b1,
      nullptr, nullptr, nullptr, x2, nullptr, nullptr, N, E);

  // ---- GAT layer 2 (+ fused heads) ----
  k_gemm_att_mfma<64><<<cdiv_i(N, 64), 256, 0, stream>>>(x2, wf2, h16, asd, N);
  k_gat_pull<false, true><<<cdiv_i(N, 4), 256, 0, stream>>>(
      rowptr_d, rec, asd, h16, consts + 4, b2,
      Wn, bn, Wec, nullptr, p_n, fgn8, N, E);

  // ---- factor graph: iter1 + merged (iter2 + edge output) ----
  k_fg_pull1<<<gN, B, 0, stream>>>(rowptr_d, rec, rowptr_s, srcnbr,
                                   p_n, fgn8, consts, N, E);
  k_fg_final<<<gN + gE, B, 0, stream>>>(rowptr_d, rec, rowptr_s, srcnbr,
                                        p_n, fgn8, consts, src, dst,
                                        out_n, out_e, N, E, gN);
}

// Round 12
// 267.602 us; speedup vs baseline: 1.3787x; 1.0402x over previous
//
#include <hip/hip_runtime.h>
#include <math.h>

// GraphRespiratory: 2-layer GAT (edge features, concat=False) + factor graph.
// N=50000, E=800000, IN=128, HID=OUT=64, H=2, NC=5, EC=2, NUM_ITER=2, GAMMA=1.
//
// R11 changes vs R10:
//  - k_gat_pull phase B gather vectorized 4x: each 16-lane group owns one edge
//    of a quad; lane loads uint4 (16B, cols 4g..4g+3) -> one dwordx4 per lane
//    per 4 edges (was one dword per edge). accA/accB[4] per lane; two
//    shfl_xor(16,32) merge edge-subgroups; self-loop added post-reduction.
//    Layer-1 store = float4 (lanes<16); HEAD partials scaled 0.25 (dup groups).
//  - k_prep_wext folded into k_prep_wfrag (wext in LDS); bucket sorts merged
//    into one dispatch (blocks [0,nbkt)=dst, [nbkt,2nbkt)=src).

static inline int cdiv_i(long long a, long long b) { return (int)((a + b - 1) / b); }

#define BSH 8           // bucket shift: 256 nodes per bucket
#define CBK 8           // edges per thread in bucket scatter (2048/block)

typedef __attribute__((ext_vector_type(8))) short bf16x8s;
typedef __attribute__((ext_vector_type(4))) float f32x4;

__device__ __forceinline__ float fexp(float x) {
  return __builtin_amdgcn_exp2f(x * 1.44269504088896f);
}
__device__ __forceinline__ float flog(float x) {
  return __builtin_amdgcn_logf(x) * 0.693147180559945f;
}
__device__ __forceinline__ float frcp(float x) {
  return __builtin_amdgcn_rcpf(x);
}

__device__ __forceinline__ unsigned short bf16r(float x) {
  unsigned u = __float_as_uint(x);
  return (unsigned short)((u + 0x7fffu + ((u >> 16) & 1u)) >> 16);
}
__device__ __forceinline__ unsigned pack_bf2(float a, float b) {
  unsigned ua = __float_as_uint(a), ub = __float_as_uint(b);
  unsigned ra = (ua + 0x7fffu + ((ua >> 16) & 1u)) >> 16;
  unsigned rb = (ub + 0x7fffu + ((ub >> 16) & 1u)) & 0xffff0000u;
  return ra | rb;
}
__device__ __forceinline__ float bf_lo(unsigned v) { return __uint_as_float(v << 16); }
__device__ __forceinline__ float bf_hi(unsigned v) { return __uint_as_float(v & 0xffff0000u); }

// consts: [0..3] w_e1[h][k], [4..7] w_e2[h][k], [8] avg_ef, [9] avg_nf, [10] dbec
__global__ void k_prep_consts(const float* __restrict__ We1, const float* __restrict__ att_e1,
                              const float* __restrict__ We2, const float* __restrict__ att_e2,
                              const float* __restrict__ node_fw, const float* __restrict__ edge_fw,
                              const float* __restrict__ bec, float* __restrict__ consts) {
  if (blockIdx.x != 0 || threadIdx.x != 0) return;
  for (int h = 0; h < 2; ++h) {
    for (int k = 0; k < 2; ++k) {
      float s1 = 0.f, s2 = 0.f;
      for (int c = 0; c < 64; ++c) {
        s1 += We1[k * 128 + h * 64 + c] * att_e1[h * 64 + c];
        s2 += We2[k * 128 + h * 64 + c] * att_e2[h * 64 + c];
      }
      consts[h * 2 + k] = s1;
      consts[4 + h * 2 + k] = s2;
    }
  }
  float ef = 0.f;                      // edge_fw is [EC=2, NC=5]; mean of [1:,1:]
  for (int j = 1; j < 5; ++j) ef += edge_fw[5 + j];
  consts[8] = ef * 0.25f;
  float nf = 0.f;                      // node_fw is [NC=5, EC=2]; mean of [1:,1:]
  for (int i = 1; i < 5; ++i) nf += node_fw[i * 2 + 1];
  consts[9] = nf * 0.25f;
  consts[10] = bec[1] - bec[0];
}

// wext (attention GEMM columns) computed to LDS, then W(+wext) swizzled into
// MFMA B-fragment order, bf16. One block.
// wf layout: [K/32][9][64 lanes][8 j]; element = W[kc+(lane>>4)*8+j][ct*16+(lane&15)]
__global__ __launch_bounds__(256)
void k_prep_wfrag(const float* __restrict__ W1, const float* __restrict__ as1,
                  const float* __restrict__ ad1,
                  const float* __restrict__ W2, const float* __restrict__ as2,
                  const float* __restrict__ ad2,
                  unsigned short* __restrict__ wf1, unsigned short* __restrict__ wf2) {
  __shared__ float wext1[128 * 4], wext2[64 * 4];
  int t = threadIdx.x;
  for (int o = t; o < 128 * 4; o += 256) {
    int k = o >> 2, j = o & 3;
    const float* att = (j < 2 ? as1 : ad1) + (j & 1) * 64;
    const float* wr = W1 + k * 128 + (j & 1) * 64;
    float s = 0.f;
    for (int c = 0; c < 64; ++c) s += wr[c] * att[c];
    wext1[o] = s;
  }
  for (int o = t; o < 64 * 4; o += 256) {
    int k = o >> 2, j = o & 3;
    const float* att = (j < 2 ? as2 : ad2) + (j & 1) * 64;
    const float* wr = W2 + k * 128 + (j & 1) * 64;
    float s = 0.f;
    for (int c = 0; c < 64; ++c) s += wr[c] * att[c];
    wext2[o] = s;
  }
  __syncthreads();
  for (int o = t; o < 4 * 9 * 512; o += 256) {       // K=128
    int kc = o / (9 * 512), rem = o % (9 * 512);
    int ct = rem / 512, li = rem % 512;
    int lane = li >> 3, j = li & 7;
    int k = kc * 32 + ((lane >> 4) << 3) + j, c = lane & 15;
    float v = (ct < 8) ? W1[k * 128 + ct * 16 + c] : (c < 4 ? wext1[k * 4 + c] : 0.f);
    wf1[o] = bf16r(v);
  }
  for (int o = t; o < 2 * 9 * 512; o += 256) {       // K=64
    int kc = o / (9 * 512), rem = o % (9 * 512);
    int ct = rem / 512, li = rem % 512;
    int lane = li >> 3, j = li & 7;
    int k = kc * 32 + ((lane >> 4) << 3) + j, c = lane & 15;
    float v = (ct < 8) ? W2[k * 128 + ct * 16 + c] : (c < 4 ? wext2[k * 4 + c] : 0.f);
    wf2[o] = bf16r(v);
  }
}

// ---- bucketed CSR build ----
__global__ void k_bkt_hist(const int* __restrict__ src, const int* __restrict__ dst,
                           int* __restrict__ hist_d, int* __restrict__ hist_s,
                           int nbkt, int E) {
  __shared__ int hd[256], hs[256];
  int t = threadIdx.x;
  hd[t] = 0; hs[t] = 0;
  __syncthreads();
  for (int e = blockIdx.x * blockDim.x + t; e < E; e += gridDim.x * blockDim.x) {
    atomicAdd(&hd[dst[e] >> BSH], 1);
    atomicAdd(&hs[src[e] >> BSH], 1);
  }
  __syncthreads();
  if (t < nbkt) {
    if (hd[t]) atomicAdd(&hist_d[t], hd[t]);
    if (hs[t]) atomicAdd(&hist_s[t], hs[t]);
  }
}

// one block: exclusive-scan both histograms -> bases (nbkt+1) and cursors (in place)
__global__ void k_bkt_scan(int* __restrict__ cur_d, int* __restrict__ base_d,
                           int* __restrict__ cur_s, int* __restrict__ base_s, int nbkt) {
  __shared__ int l[256];
  int t = threadIdx.x;
  int v = (t < nbkt) ? cur_d[t] : 0;
  l[t] = v; __syncthreads();
  for (int off = 1; off < 256; off <<= 1) {
    int x = (t >= off) ? l[t - off] : 0; __syncthreads();
    l[t] += x; __syncthreads();
  }
  int incl = l[t];
  if (t < nbkt) { base_d[t] = incl - v; cur_d[t] = incl - v; }
  if (t == nbkt - 1) base_d[nbkt] = incl;
  __syncthreads();
  v = (t < nbkt) ? cur_s[t] : 0;
  l[t] = v; __syncthreads();
  for (int off = 1; off < 256; off <<= 1) {
    int x = (t >= off) ? l[t - off] : 0; __syncthreads();
    l[t] += x; __syncthreads();
  }
  incl = l[t];
  if (t < nbkt) { base_s[t] = incl - v; cur_s[t] = incl - v; }
  if (t == nbkt - 1) base_s[nbkt] = incl;
}

// block-staged bucket scatter: 2048 edges/block in regs; LDS per-bucket counts;
// one global atomicAdd per (bucket,block) to reserve; chunky tail writes.
__global__ __launch_bounds__(256)
void k_bkt_scatter(const int* __restrict__ src, const int* __restrict__ dst,
                   const float* __restrict__ eattr2,
                   int* __restrict__ cur_d, int* __restrict__ cur_s,
                   int4* __restrict__ stage_d, int2* __restrict__ stage_s,
                   int nbkt, int E) {
  __shared__ int cd[256], cs[256], bd[256], bs[256];
  int t = threadIdx.x;
  cd[t] = 0; cs[t] = 0;
  __syncthreads();
  int base = blockIdx.x * 256 * CBK;
  int s[CBK], d[CBK]; unsigned ep[CBK];
#pragma unroll
  for (int c = 0; c < CBK; ++c) {
    int e = base + c * 256 + t;
    if (e < E) {
      s[c] = src[e]; d[c] = dst[e];
      float2 ev = *(const float2*)&eattr2[2 * e];
      ep[c] = pack_bf2(ev.x, ev.y);
      atomicAdd(&cd[d[c] >> BSH], 1);
      atomicAdd(&cs[s[c] >> BSH], 1);
    } else s[c] = -1;
  }
  __syncthreads();
  if (t < nbkt) {
    bd[t] = cd[t] ? atomicAdd(&cur_d[t], cd[t]) : 0;
    bs[t] = cs[t] ? atomicAdd(&cur_s[t], cs[t]) : 0;
    cd[t] = 0; cs[t] = 0;
  }
  __syncthreads();
#pragma unroll
  for (int c = 0; c < CBK; ++c) {
    if (s[c] < 0) continue;
    int db = d[c] >> BSH, sb = s[c] >> BSH;
    int pos = bd[db] + atomicAdd(&cd[db], 1);
    stage_d[pos] = make_int4(s[c], d[c], (int)ep[c], 0);
    int pos2 = bs[sb] + atomicAdd(&cs[sb], 1);
    stage_s[pos2] = make_int2(s[c], d[c]);
  }
}

// merged per-bucket counting sorts: blocks [0,nbkt) dst side, [nbkt,2nbkt) src.
__global__ __launch_bounds__(256)
void k_bkt_sort(const int4* __restrict__ stage_d, const int* __restrict__ base_d,
                int* __restrict__ rowptr_d, int2* __restrict__ rec,
                const int2* __restrict__ stage_s, const int* __restrict__ base_s,
                int* __restrict__ rowptr_s, int* __restrict__ srcnbr,
                int N, int nbkt) {
  int t = threadIdx.x;
  __shared__ int cnt[256], cur[256], l[256];
  if ((int)blockIdx.x < nbkt) {
    int b = blockIdx.x;
    int nlo = b << BSH;
    int b0 = base_d[b], b1 = base_d[b + 1];
    cnt[t] = 0;
    __syncthreads();
    for (int j = b0 + t; j < b1; j += 256)
      atomicAdd(&cnt[stage_d[j].y - nlo], 1);
    __syncthreads();
    int v = cnt[t];
    l[t] = v; __syncthreads();
    for (int off = 1; off < 256; off <<= 1) {
      int x = (t >= off) ? l[t - off] : 0; __syncthreads();
      l[t] += x; __syncthreads();
    }
    int excl = l[t] - v;
    if (nlo + t < N) rowptr_d[nlo + t] = b0 + excl;
    cur[t] = excl;
    __syncthreads();
    for (int j = b0 + t; j < b1; j += 256) {
      int4 r = stage_d[j];
      int pos = b0 + atomicAdd(&cur[r.y - nlo], 1);
      rec[pos] = make_int2(r.x, r.z);
    }
  } else {
    int b = blockIdx.x - nbkt;
    int nlo = b << BSH;
    int b0 = base_s[b], b1 = base_s[b + 1];
    cnt[t] = 0;
    __syncthreads();
    for (int j = b0 + t; j < b1; j += 256)
      atomicAdd(&cnt[stage_s[j].x - nlo], 1);
    __syncthreads();
    int v = cnt[t];
    l[t] = v; __syncthreads();
    for (int off = 1; off < 256; off <<= 1) {
      int x = (t >= off) ? l[t - off] : 0; __syncthreads();
      l[t] += x; __syncthreads();
    }
    int excl = l[t] - v;
    if (nlo + t < N) rowptr_s[nlo + t] = b0 + excl;
    cur[t] = excl;
    __syncthreads();
    for (int j = b0 + t; j < b1; j += 256) {
      int2 r = stage_s[j];
      int pos = b0 + atomicAdd(&cur[r.x - nlo], 1);
      srcnbr[pos] = r.y;
    }
  }
}

// MFMA GEMM + attention columns. A[N][K] f32 -> bf16 in-reg; Wf pre-swizzled
// B-fragments (9 col-tiles: 8 of W + 1 of wext). Block = 4 waves x 16 rows.
template<int K>
__global__ __launch_bounds__(256)
void k_gemm_att_mfma(const float* __restrict__ A, const unsigned short* __restrict__ Wf,
                     unsigned* __restrict__ h16, float* __restrict__ asd, int N) {
  int wv = threadIdx.x >> 6, lane = threadIdx.x & 63;
  int r0 = blockIdx.x * 64 + wv * 16;
  int arow = r0 + (lane & 15);
  int kbase = (lane >> 4) * 8;
  f32x4 acc[9];
#pragma unroll
  for (int ct = 0; ct < 9; ++ct) acc[ct] = (f32x4){0.f, 0.f, 0.f, 0.f};

#pragma unroll
  for (int kc = 0; kc < K; kc += 32) {
    float4 v0 = make_float4(0.f, 0.f, 0.f, 0.f);
    float4 v1 = make_float4(0.f, 0.f, 0.f, 0.f);
    if (arow < N) {
      const float* ap = A + (long long)arow * K + kc + kbase;
      v0 = *(const float4*)ap;
      v1 = *(const float4*)(ap + 4);
    }
    bf16x8s a;
    a[0] = (short)bf16r(v0.x); a[1] = (short)bf16r(v0.y);
    a[2] = (short)bf16r(v0.z); a[3] = (short)bf16r(v0.w);
    a[4] = (short)bf16r(v1.x); a[5] = (short)bf16r(v1.y);
    a[6] = (short)bf16r(v1.z); a[7] = (short)bf16r(v1.w);
    const unsigned short* wp = Wf + (size_t)(kc >> 5) * 9 * 512 + lane * 8;
#pragma unroll
    for (int ct = 0; ct < 9; ++ct) {
      bf16x8s b = *(const bf16x8s*)(wp + ct * 512);
      acc[ct] = __builtin_amdgcn_mfma_f32_16x16x32_bf16(a, b, acc[ct], 0, 0, 0);
    }
  }
  // D layout: col = lane&15, row = (lane>>4)*4 + reg
  int c = lane & 15;
  int orow = r0 + (lane >> 4) * 4;
#pragma unroll
  for (int r = 0; r < 4; ++r) {
    int gr = orow + r;
    if (gr >= N) continue;
#pragma unroll
    for (int ct = 0; ct < 4; ++ct)
      h16[((long long)gr << 6) | (ct * 16 + c)] = pack_bf2(acc[ct][r], acc[ct + 4][r]);
    if (c < 4) asd[gr * 4 + c] = acc[8][r];
  }
}

// Fused GAT edge phase, pull-mode. One wave per dst node.
// Phase A (lane=edge) stages {src, ea-pack} in LDS; phase B: each 16-lane group
// owns one edge of a quad, lane loads uint4 (cols 4g..4g+3) -> 1 dwordx4 per
// 4 edges. accA/accB[4] per lane; shfl_xor(16,32) merges edge-subgroups.
template<bool RELU, bool HEAD>
__global__ __launch_bounds__(256)
void k_gat_pull(const int* __restrict__ rowptr, const int2* __restrict__ rec,
                const float* __restrict__ asd, const unsigned* __restrict__ h16,
                const float* __restrict__ we, const float* __restrict__ bias,
                const float* __restrict__ Wn, const float* __restrict__ bn,
                const float* __restrict__ Wec,
                float* __restrict__ out, float* __restrict__ p_n,
                int2* __restrict__ fgn8, int N, int E) {
  __shared__ int2 ed[4][64];
  int wv = threadIdx.x >> 6, lane = threadIdx.x & 63;
  int d = blockIdx.x * 4 + wv;
  if (d >= N) return;
  int r0 = rowptr[d];
  int r1 = (d + 1 < N) ? rowptr[d + 1] : E;
  int deg = r1 - r0;
  float4 Ad = *(const float4*)&asd[4 * d];
  float w0 = we[0], w1 = we[1], w2 = we[2], w3 = we[3];
  int g = lane & 15;        // col group: cols 4g..4g+3
  int eg = lane >> 4;       // edge subgroup 0..3
  float den0 = 0.f, den1 = 0.f, se0 = 0.f, se1 = 0.f;
  float accA[4] = {0.f, 0.f, 0.f, 0.f}, accB[4] = {0.f, 0.f, 0.f, 0.f};
  for (int cb = 0; cb < deg; cb += 64) {
    int j = cb + lane;
    int s = 0; unsigned eapk = 0;
    if (j < deg) {
      int2 rc = rec[r0 + j];
      s = rc.x;
      unsigned ep = (unsigned)rc.y;
      float e0 = bf_lo(ep), e1 = bf_hi(ep);
      float4 As = *(const float4*)&asd[4 * s];
      float x0 = As.x + Ad.z + e0 * w0 + e1 * w1;
      float x1 = As.y + Ad.w + e0 * w2 + e1 * w3;
      x0 = x0 >= 0.f ? x0 : 0.2f * x0;
      x1 = x1 >= 0.f ? x1 : 0.2f * x1;
      float ea0 = fexp(x0), ea1 = fexp(x1);
      eapk = pack_bf2(ea0, ea1);
      den0 += ea0; den1 += ea1; se0 += e0; se1 += e1;
    }
    ed[wv][lane] = make_int2(s, (int)eapk);   // same-wave LDS: no barrier needed
    int m = min(64, deg - cb);
    int j2 = 0;
    for (; j2 + 8 <= m; j2 += 8) {            // 2 quads in flight
      int2 va = ed[wv][j2 + eg];
      int2 vb = ed[wv][j2 + 4 + eg];
      uint4 qa = *(const uint4*)&h16[((long long)va.x << 6) | (g << 2)];
      uint4 qb = *(const uint4*)&h16[((long long)vb.x << 6) | (g << 2)];
      float a0 = bf_lo((unsigned)va.y), a1 = bf_hi((unsigned)va.y);
      float b0 = bf_lo((unsigned)vb.y), b1 = bf_hi((unsigned)vb.y);
      accA[0] += a0 * bf_lo(qa.x); accB[0] += a1 * bf_hi(qa.x);
      accA[1] += a0 * bf_lo(qa.y); accB[1] += a1 * bf_hi(qa.y);
      accA[2] += a0 * bf_lo(qa.z); accB[2] += a1 * bf_hi(qa.z);
      accA[3] += a0 * bf_lo(qa.w); accB[3] += a1 * bf_hi(qa.w);
      accA[0] += b0 * bf_lo(qb.x); accB[0] += b1 * bf_hi(qb.x);
      accA[1] += b0 * bf_lo(qb.y); accB[1] += b1 * bf_hi(qb.y);
      accA[2] += b0 * bf_lo(qb.z); accB[2] += b1 * bf_hi(qb.z);
      accA[3] += b0 * bf_lo(qb.w); accB[3] += b1 * bf_hi(qb.w);
    }
    if (j2 + 4 <= m) {
      int2 va = ed[wv][j2 + eg];
      uint4 qa = *(const uint4*)&h16[((long long)va.x << 6) | (g << 2)];
      float a0 = bf_lo((unsigned)va.y), a1 = bf_hi((unsigned)va.y);
      accA[0] += a0 * bf_lo(qa.x); accB[0] += a1 * bf_hi(qa.x);
      accA[1] += a0 * bf_lo(qa.y); accB[1] += a1 * bf_hi(qa.y);
      accA[2] += a0 * bf_lo(qa.z); accB[2] += a1 * bf_hi(qa.z);
      accA[3] += a0 * bf_lo(qa.w); accB[3] += a1 * bf_hi(qa.w);
      j2 += 4;
    }
    if (eg == 0) {                            // tail <4 edges: group 0 only
      for (; j2 < m; ++j2) {
        int2 v = ed[wv][j2];
        uint4 q = *(const uint4*)&h16[((long long)v.x << 6) | (g << 2)];
        float a0 = bf_lo((unsigned)v.y), a1 = bf_hi((unsigned)v.y);
        accA[0] += a0 * bf_lo(q.x); accB[0] += a1 * bf_hi(q.x);
        accA[1] += a0 * bf_lo(q.y); accB[1] += a1 * bf_hi(q.y);
        accA[2] += a0 * bf_lo(q.z); accB[2] += a1 * bf_hi(q.z);
        accA[3] += a0 * bf_lo(q.w); accB[3] += a1 * bf_hi(q.w);
      }
    }
  }
  // reduce den/se fully; merge acc edge-subgroups (lanes L, L^16, L^32, L^48)
  for (int off = 32; off; off >>= 1) {
    den0 += __shfl_xor(den0, off); den1 += __shfl_xor(den1, off);
    se0  += __shfl_xor(se0, off);  se1  += __shfl_xor(se1, off);
  }
#pragma unroll
  for (int k = 0; k < 4; ++k) {
    accA[k] += __shfl_xor(accA[k], 16); accB[k] += __shfl_xor(accB[k], 16);
    accA[k] += __shfl_xor(accA[k], 32); accB[k] += __shfl_xor(accB[k], 32);
  }
  // self-loop (post-reduction; identical on duplicate lanes)
  float id = frcp(fmaxf((float)deg, 1.0f));
  float le0 = se0 * id, le1 = se1 * id;
  float x0 = Ad.x + Ad.z + le0 * w0 + le1 * w1;
  float x1 = Ad.y + Ad.w + le0 * w2 + le1 * w3;
  x0 = x0 >= 0.f ? x0 : 0.2f * x0;
  x1 = x1 >= 0.f ? x1 : 0.2f * x1;
  float eas0 = fexp(x0), eas1 = fexp(x1);
  den0 += eas0; den1 += eas1;
  uint4 qd = *(const uint4*)&h16[((long long)d << 6) | (g << 2)];
  accA[0] += eas0 * bf_lo(qd.x); accB[0] += eas1 * bf_hi(qd.x);
  accA[1] += eas0 * bf_lo(qd.y); accB[1] += eas1 * bf_hi(qd.y);
  accA[2] += eas0 * bf_lo(qd.z); accB[2] += eas1 * bf_hi(qd.z);
  accA[3] += eas0 * bf_lo(qd.w); accB[3] += eas1 * bf_hi(qd.w);
  float rcp0 = frcp(den0 + 1e-16f), rcp1 = frcp(den1 + 1e-16f);
  float4 bs = *(const float4*)&bias[g << 2];
  float v0 = 0.5f * (accA[0] * rcp0 + accB[0] * rcp1) + bs.x;
  float v1 = 0.5f * (accA[1] * rcp0 + accB[1] * rcp1) + bs.y;
  float v2 = 0.5f * (accA[2] * rcp0 + accB[2] * rcp1) + bs.z;
  float v3 = 0.5f * (accA[3] * rcp0 + accB[3] * rcp1) + bs.w;
  if (HEAD) {
    int c0 = g << 2;
    float pv[7];
#pragma unroll
    for (int j = 0; j < 5; ++j)
      pv[j] = v0 * Wn[c0 * 5 + j] + v1 * Wn[(c0 + 1) * 5 + j]
            + v2 * Wn[(c0 + 2) * 5 + j] + v3 * Wn[(c0 + 3) * 5 + j];
    pv[5] = v0 * Wec[c0 * 2] + v1 * Wec[(c0 + 1) * 2]
          + v2 * Wec[(c0 + 2) * 2] + v3 * Wec[(c0 + 3) * 2];
    pv[6] = v0 * Wec[c0 * 2 + 1] + v1 * Wec[(c0 + 1) * 2 + 1]
          + v2 * Wec[(c0 + 2) * 2 + 1] + v3 * Wec[(c0 + 3) * 2 + 1];
    for (int off = 32; off; off >>= 1) {
#pragma unroll
      for (int j = 0; j < 7; ++j) pv[j] += __shfl_down(pv[j], off);
    }
    if (lane == 0) {
      float l[5]; float m = -1e30f;
#pragma unroll
      for (int j = 0; j < 5; ++j) { l[j] = pv[j] * 0.25f + bn[j]; m = fmaxf(m, l[j]); }
      float ssum = 0.f;
#pragma unroll
      for (int j = 0; j < 5; ++j) { l[j] = fexp(l[j] - m); ssum += l[j]; }
      float inv = frcp(ssum);
#pragma unroll
      for (int j = 0; j < 5; ++j) p_n[5 * d + j] = l[j] * inv;
      float nab0 = (ssum - l[0]) * inv;
      fgn8[d] = make_int2(__float_as_int((pv[6] - pv[5]) * 0.25f), (int)pack_bf2(nab0, 0.f));
    }
  } else {
    if (RELU) {
      v0 = fmaxf(v0, 0.f); v1 = fmaxf(v1, 0.f);
      v2 = fmaxf(v2, 0.f); v3 = fmaxf(v3, 0.f);
    }
    if (lane < 16)
      *(float4*)&out[(long long)d * 64 + (g << 2)] = make_float4(v0, v1, v2, v3);
  }
}

// eab = c / (c + exp(-t)) : one rcp, shared structure.
__device__ __forceinline__ float fg_eab(float t, float c) {
  return c * frcp(c + fexp(-t));
}

// factor-graph node-pull iteration 1. One thread per node. fgn8 = {q, bf16x2 nab}.
__global__ void k_fg_pull1(const int* __restrict__ rowptr_d, const int2* __restrict__ rec,
                           const int* __restrict__ rowptr_s, const int* __restrict__ srcnbr,
                           float* __restrict__ p_n, int2* __restrict__ fgn8,
                           const float* __restrict__ consts, int N, int E) {
  int n = blockIdx.x * blockDim.x + threadIdx.x;
  if (n >= N) return;
  int2 F = fgn8[n];
  float q = __uint_as_float((unsigned)F.x);
  float nab0 = bf_lo((unsigned)F.y);
  float avg_ef = consts[8], avg_nf = consts[9], dbec = consts[10];
  int rd0 = rowptr_d[n], rd1 = (n + 1 < N) ? rowptr_d[n + 1] : E;
  int rs0 = rowptr_s[n], rs1 = (n + 1 < N) ? rowptr_s[n + 1] : E;
  float s_eab = 0.f;
  for (int j = rd0; j < rd1; ++j) {
    int2 Fo = fgn8[rec[j].x];
    float t = 0.5f * (q + __uint_as_float((unsigned)Fo.x)) + dbec;
    float c = 1.0f + fmaxf(nab0, bf_lo((unsigned)Fo.y)) * avg_ef;
    s_eab += fg_eab(t, c);
  }
  for (int j = rs0; j < rs1; ++j) {
    int2 Fo = fgn8[srcnbr[j]];
    float t = 0.5f * (q + __uint_as_float((unsigned)Fo.x)) + dbec;
    float c = 1.0f + fmaxf(nab0, bf_lo((unsigned)Fo.y)) * avg_ef;
    s_eab += fg_eab(t, c);
  }
  float deg = (float)((rd1 - rd0) + (rs1 - rs0));
  float mean = s_eab * frcp(deg + 1e-6f);
  float f = 1.0f + mean * avg_nf;
  float p0 = p_n[5 * n], p1 = p_n[5 * n + 1], p2 = p_n[5 * n + 2],
        p3 = p_n[5 * n + 3], p4 = p_n[5 * n + 4];
  float rest = (p1 + p2 + p3 + p4) * f;
  float inv = frcp(p0 + rest);
  p_n[5 * n]     = p0 * inv;
  p_n[5 * n + 1] = p1 * f * inv;
  p_n[5 * n + 2] = p2 * f * inv;
  p_n[5 * n + 3] = p3 * f * inv;
  p_n[5 * n + 4] = p4 * f * inv;
  fgn8[n].y = (int)pack_bf2(nab0, rest * inv);
}

// merged final pass: blocks [0, nodeBlocks) = fg iteration 2 (writes out_n);
// blocks [nodeBlocks, ...) = edge output. Both only READ fgn8.
__global__ void k_fg_final(const int* __restrict__ rowptr_d, const int2* __restrict__ rec,
                           const int* __restrict__ rowptr_s, const int* __restrict__ srcnbr,
                           const float* __restrict__ p_n, const int2* __restrict__ fgn8,
                           const float* __restrict__ consts,
                           const int* __restrict__ src, const int* __restrict__ dst,
                           float* __restrict__ out_n, float* __restrict__ out_e,
                           int N, int E, int nodeBlocks) {
  float avg_ef = consts[8], dbec = consts[10];
  if ((int)blockIdx.x < nodeBlocks) {
    int n = blockIdx.x * blockDim.x + threadIdx.x;
    if (n >= N) return;
    float avg_nf = consts[9];
    int2 F = fgn8[n];
    float q = __uint_as_float((unsigned)F.x);
    float nab0 = bf_lo((unsigned)F.y), nab1 = bf_hi((unsigned)F.y);
    int rd0 = rowptr_d[n], rd1 = (n + 1 < N) ? rowptr_d[n + 1] : E;
    int rs0 = rowptr_s[n], rs1 = (n + 1 < N) ? rowptr_s[n + 1] : E;
    float s_eab = 0.f;
    for (int j = rd0; j < rd1; ++j) {
      int2 Fo = fgn8[rec[j].x];
      float t = 0.5f * (q + __uint_as_float((unsigned)Fo.x)) + dbec;
      float c = (1.0f + fmaxf(nab0, bf_lo((unsigned)Fo.y)) * avg_ef)
              * (1.0f + fmaxf(nab1, bf_hi((unsigned)Fo.y)) * avg_ef);
      s_eab += fg_eab(t, c);
    }
    for (int j = rs0; j < rs1; ++j) {
      int2 Fo = fgn8[srcnbr[j]];
      float t = 0.5f * (q + __uint_as_float((unsigned)Fo.x)) + dbec;
      float c = (1.0f + fmaxf(nab0, bf_lo((unsigned)Fo.y)) * avg_ef)
              * (1.0f + fmaxf(nab1, bf_hi((unsigned)Fo.y)) * avg_ef);
      s_eab += fg_eab(t, c);
    }
    float deg = (float)((rd1 - rd0) + (rs1 - rs0));
    float mean = s_eab * frcp(deg + 1e-6f);
    float f = 1.0f + mean * avg_nf;
    float p0 = p_n[5 * n], p1 = p_n[5 * n + 1], p2 = p_n[5 * n + 2],
          p3 = p_n[5 * n + 3], p4 = p_n[5 * n + 4];
    float rest = (p1 + p2 + p3 + p4) * f;
    float inv = frcp(p0 + rest);
    out_n[5 * n]     = flog(p0 * inv + 1e-9f);
    out_n[5 * n + 1] = flog(p1 * f * inv + 1e-9f);
    out_n[5 * n + 2] = flog(p2 * f * inv + 1e-9f);
    out_n[5 * n + 3] = flog(p3 * f * inv + 1e-9f);
    out_n[5 * n + 4] = flog(p4 * f * inv + 1e-9f);
  } else {
    int e = (blockIdx.x - nodeBlocks) * blockDim.x + threadIdx.x;
    if (e >= E) return;
    int2 Fs = fgn8[src[e]];
    int2 Fd = fgn8[dst[e]];
    float t = 0.5f * (__uint_as_float((unsigned)Fs.x) + __uint_as_float((unsigned)Fd.x)) + dbec;
    float c = (1.0f + fmaxf(bf_lo((unsigned)Fs.y), bf_lo((unsigned)Fd.y)) * avg_ef)
            * (1.0f + fmaxf(bf_hi((unsigned)Fs.y), bf_hi((unsigned)Fd.y)) * avg_ef);
    float ei = fexp(-t);
    float r = frcp(c + ei);
    float pe1 = c * r, pe0 = ei * r;
    *(float2*)&out_e[2 * e] = make_float2(flog(pe0 + 1e-9f), flog(pe1 + 1e-9f));
  }
}

extern "C" void kernel_launch(void* const* d_in, const int* in_sizes, int n_in,
                              void* d_out, int out_size, void* d_ws, size_t ws_size,
                              hipStream_t stream) {
  const float* x      = (const float*)d_in[0];
  const int*   ei     = (const int*)d_in[1];
  const float* eattr  = (const float*)d_in[2];
  const float* W1     = (const float*)d_in[3];
  const float* atts1  = (const float*)d_in[4];
  const float* attd1  = (const float*)d_in[5];
  const float* We1    = (const float*)d_in[6];
  const float* atte1  = (const float*)d_in[7];
  const float* b1     = (const float*)d_in[8];
  const float* W2     = (const float*)d_in[9];
  const float* atts2  = (const float*)d_in[10];
  const float* attd2  = (const float*)d_in[11];
  const float* We2    = (const float*)d_in[12];
  const float* atte2  = (const float*)d_in[13];
  const float* b2     = (const float*)d_in[14];
  const float* Wn     = (const float*)d_in[15];
  const float* bn     = (const float*)d_in[16];
  const float* Wec    = (const float*)d_in[17];
  const float* bec    = (const float*)d_in[18];
  const float* nodefw = (const float*)d_in[19];
  const float* edgefw = (const float*)d_in[20];

  const int N = in_sizes[0] / 128;
  const int E = in_sizes[1] / 2;
  const int* src = ei;
  const int* dst = ei + E;
  const int nbkt = (N + 255) >> BSH;   // 196 (assumes N <= 65536)

  float* out_n = (float*)d_out;
  float* out_e = out_n + (long long)N * 5;

  // ---- workspace carve (f32 units, 16B aligned) ----
  size_t off = 0;
  float* base = (float*)d_ws;
  auto carve = [&](size_t nelem) { float* p = base + off; off += (nelem + 3) & ~(size_t)3; return p; };
  unsigned* h16      = (unsigned*)carve((size_t)N * 64);  // aliases stage_d during prep
  float*    x2       = carve((size_t)N * 64);             // aliases stage_s during prep
  float*    asd      = carve((size_t)N * 4);
  int2*     rec      = (int2*)carve((size_t)E * 2);       // {src, bf16x2 eattr}
  int*      srcnbr   = (int*)carve((size_t)E);
  int*      rowptr_d = (int*)carve((size_t)N);
  int*      rowptr_s = (int*)carve((size_t)N);
  int*      bktcur_d = (int*)carve(256);
  int*      bktcur_s = (int*)carve(256);
  int*      bktbas_d = (int*)carve(260);
  int*      bktbas_s = (int*)carve(260);
  float*    p_n      = carve((size_t)N * 5);
  int2*     fgn8     = (int2*)carve((size_t)N * 2);
  float*    consts   = carve(16);
  unsigned short* wf1 = (unsigned short*)carve(9216);     // 4*9*512 bf16
  unsigned short* wf2 = (unsigned short*)carve(4608);     // 2*9*512 bf16
  if (off * sizeof(float) > ws_size) return;  // insufficient scratch: fail loudly

  // bucket staging aliases h16/x2 (CSR build completes before they're written):
  int4* stage_d = (int4*)h16;
  int2* stage_s = (int2*)x2;

  const int B = 256;
  const int gE  = cdiv_i(E, B);
  const int gN  = cdiv_i(N, B);

  // ---- graph prep: bucketed CSR build (both directions) ----
  hipMemsetAsync(bktcur_d, 0, 256 * 4, stream);
  hipMemsetAsync(bktcur_s, 0, 256 * 4, stream);
  k_prep_consts<<<1, 64, 0, stream>>>(We1, atte1, We2, atte2, nodefw, edgefw, bec, consts);
  k_prep_wfrag<<<1, 256, 0, stream>>>(W1, atts1, attd1, W2, atts2, attd2, wf1, wf2);
  k_bkt_hist<<<256, 256, 0, stream>>>(src, dst, bktcur_d, bktcur_s, nbkt, E);
  k_bkt_scan<<<1, 256, 0, stream>>>(bktcur_d, bktbas_d, bktcur_s, bktbas_s, nbkt);
  k_bkt_scatter<<<cdiv_i(E, 256 * CBK), 256, 0, stream>>>(src, dst, eattr, bktcur_d, bktcur_s,
                                                          stage_d, stage_s, nbkt, E);
  k_bkt_sort<<<2 * nbkt, 256, 0, stream>>>(stage_d, bktbas_d, rowptr_d, rec,
                                           stage_s, bktbas_s, rowptr_s, srcnbr, N, nbkt);

  // ---- GAT layer 1 (gemm writes h16+asd; pull writes x2) ----
  k_gemm_att_mfma<128><<<cdiv_i(N, 64), 256, 0, stream>>>(x, wf1, h16, asd, N);
  k_gat_pull<true, false><<<cdiv_i(N, 4), 256, 0, stream>>>(
      rowptr_d, rec, asd, h16, consts, b1,
      nullptr, nullptr, nullptr, x2, nullptr, nullptr, N, E);

  // ---- GAT layer 2 (+ fused heads) ----
  k_gemm_att_mfma<64><<<cdiv_i(N, 64), 256, 0, stream>>>(x2, wf2, h16, asd, N);
  k_gat_pull<false, true><<<cdiv_i(N, 4), 256, 0, stream>>>(
      rowptr_d, rec, asd, h16, consts + 4, b2,
      Wn, bn, Wec, nullptr, p_n, fgn8, N, E);

  // ---- factor graph: iter1 + merged (iter2 + edge output) ----
  k_fg_pull1<<<gN, B, 0, stream>>>(rowptr_d, rec, rowptr_s, srcnbr,
                                   p_n, fgn8, consts, N, E);
  k_fg_final<<<gN + gE, B, 0, stream>>>(rowptr_d, rec, rowptr_s, srcnbr,
                                        p_n, fgn8, consts, src, dst,
                                        out_n, out_e, N, E, gN);
}

// Round 13
// 248.659 us; speedup vs baseline: 1.4837x; 1.0762x over previous
//
#include <hip/hip_runtime.h>
#include <math.h>

// GraphRespiratory: 2-layer GAT (edge features, concat=False) + factor graph.
// N=50000, E=800000, IN=128, HID=OUT=64, H=2, NC=5, EC=2, NUM_ITER=2, GAMMA=1.
//
// R12 changes vs R11:
//  - k_gat_pull: one 16-lane GROUP per dst node (4 nodes/wave) instead of one
//    wave/node. Avg deg = E/N = 16, so phase A lane utilization goes 25%->~100%
//    and per-node overhead (reductions, self-loop, epilogue) is shared 4x.
//    Phase B unchanged density: lane=col-quad (uint4), group=edge.
//    Reductions shrink to 4 shfl_xor within the group. Grid = N/16.

static inline int cdiv_i(long long a, long long b) { return (int)((a + b - 1) / b); }

#define BSH 8           // bucket shift: 256 nodes per bucket
#define CBK 8           // edges per thread in bucket scatter (2048/block)

typedef __attribute__((ext_vector_type(8))) short bf16x8s;
typedef __attribute__((ext_vector_type(4))) float f32x4;

__device__ __forceinline__ float fexp(float x) {
  return __builtin_amdgcn_exp2f(x * 1.44269504088896f);
}
__device__ __forceinline__ float flog(float x) {
  return __builtin_amdgcn_logf(x) * 0.693147180559945f;
}
__device__ __forceinline__ float frcp(float x) {
  return __builtin_amdgcn_rcpf(x);
}

__device__ __forceinline__ unsigned short bf16r(float x) {
  unsigned u = __float_as_uint(x);
  return (unsigned short)((u + 0x7fffu + ((u >> 16) & 1u)) >> 16);
}
__device__ __forceinline__ unsigned pack_bf2(float a, float b) {
  unsigned ua = __float_as_uint(a), ub = __float_as_uint(b);
  unsigned ra = (ua + 0x7fffu + ((ua >> 16) & 1u)) >> 16;
  unsigned rb = (ub + 0x7fffu + ((ub >> 16) & 1u)) & 0xffff0000u;
  return ra | rb;
}
__device__ __forceinline__ float bf_lo(unsigned v) { return __uint_as_float(v << 16); }
__device__ __forceinline__ float bf_hi(unsigned v) { return __uint_as_float(v & 0xffff0000u); }

// consts: [0..3] w_e1[h][k], [4..7] w_e2[h][k], [8] avg_ef, [9] avg_nf, [10] dbec
__global__ void k_prep_consts(const float* __restrict__ We1, const float* __restrict__ att_e1,
                              const float* __restrict__ We2, const float* __restrict__ att_e2,
                              const float* __restrict__ node_fw, const float* __restrict__ edge_fw,
                              const float* __restrict__ bec, float* __restrict__ consts) {
  if (blockIdx.x != 0 || threadIdx.x != 0) return;
  for (int h = 0; h < 2; ++h) {
    for (int k = 0; k < 2; ++k) {
      float s1 = 0.f, s2 = 0.f;
      for (int c = 0; c < 64; ++c) {
        s1 += We1[k * 128 + h * 64 + c] * att_e1[h * 64 + c];
        s2 += We2[k * 128 + h * 64 + c] * att_e2[h * 64 + c];
      }
      consts[h * 2 + k] = s1;
      consts[4 + h * 2 + k] = s2;
    }
  }
  float ef = 0.f;                      // edge_fw is [EC=2, NC=5]; mean of [1:,1:]
  for (int j = 1; j < 5; ++j) ef += edge_fw[5 + j];
  consts[8] = ef * 0.25f;
  float nf = 0.f;                      // node_fw is [NC=5, EC=2]; mean of [1:,1:]
  for (int i = 1; i < 5; ++i) nf += node_fw[i * 2 + 1];
  consts[9] = nf * 0.25f;
  consts[10] = bec[1] - bec[0];
}

// wext (attention GEMM columns) computed to LDS, then W(+wext) swizzled into
// MFMA B-fragment order, bf16. One block.
// wf layout: [K/32][9][64 lanes][8 j]; element = W[kc+(lane>>4)*8+j][ct*16+(lane&15)]
__global__ __launch_bounds__(256)
void k_prep_wfrag(const float* __restrict__ W1, const float* __restrict__ as1,
                  const float* __restrict__ ad1,
                  const float* __restrict__ W2, const float* __restrict__ as2,
                  const float* __restrict__ ad2,
                  unsigned short* __restrict__ wf1, unsigned short* __restrict__ wf2) {
  __shared__ float wext1[128 * 4], wext2[64 * 4];
  int t = threadIdx.x;
  for (int o = t; o < 128 * 4; o += 256) {
    int k = o >> 2, j = o & 3;
    const float* att = (j < 2 ? as1 : ad1) + (j & 1) * 64;
    const float* wr = W1 + k * 128 + (j & 1) * 64;
    float s = 0.f;
    for (int c = 0; c < 64; ++c) s += wr[c] * att[c];
    wext1[o] = s;
  }
  for (int o = t; o < 64 * 4; o += 256) {
    int k = o >> 2, j = o & 3;
    const float* att = (j < 2 ? as2 : ad2) + (j & 1) * 64;
    const float* wr = W2 + k * 128 + (j & 1) * 64;
    float s = 0.f;
    for (int c = 0; c < 64; ++c) s += wr[c] * att[c];
    wext2[o] = s;
  }
  __syncthreads();
  for (int o = t; o < 4 * 9 * 512; o += 256) {       // K=128
    int kc = o / (9 * 512), rem = o % (9 * 512);
    int ct = rem / 512, li = rem % 512;
    int lane = li >> 3, j = li & 7;
    int k = kc * 32 + ((lane >> 4) << 3) + j, c = lane & 15;
    float v = (ct < 8) ? W1[k * 128 + ct * 16 + c] : (c < 4 ? wext1[k * 4 + c] : 0.f);
    wf1[o] = bf16r(v);
  }
  for (int o = t; o < 2 * 9 * 512; o += 256) {       // K=64
    int kc = o / (9 * 512), rem = o % (9 * 512);
    int ct = rem / 512, li = rem % 512;
    int lane = li >> 3, j = li & 7;
    int k = kc * 32 + ((lane >> 4) << 3) + j, c = lane & 15;
    float v = (ct < 8) ? W2[k * 128 + ct * 16 + c] : (c < 4 ? wext2[k * 4 + c] : 0.f);
    wf2[o] = bf16r(v);
  }
}

// ---- bucketed CSR build ----
__global__ void k_bkt_hist(const int* __restrict__ src, const int* __restrict__ dst,
                           int* __restrict__ hist_d, int* __restrict__ hist_s,
                           int nbkt, int E) {
  __shared__ int hd[256], hs[256];
  int t = threadIdx.x;
  hd[t] = 0; hs[t] = 0;
  __syncthreads();
  for (int e = blockIdx.x * blockDim.x + t; e < E; e += gridDim.x * blockDim.x) {
    atomicAdd(&hd[dst[e] >> BSH], 1);
    atomicAdd(&hs[src[e] >> BSH], 1);
  }
  __syncthreads();
  if (t < nbkt) {
    if (hd[t]) atomicAdd(&hist_d[t], hd[t]);
    if (hs[t]) atomicAdd(&hist_s[t], hs[t]);
  }
}

// one block: exclusive-scan both histograms -> bases (nbkt+1) and cursors (in place)
__global__ void k_bkt_scan(int* __restrict__ cur_d, int* __restrict__ base_d,
                           int* __restrict__ cur_s, int* __restrict__ base_s, int nbkt) {
  __shared__ int l[256];
  int t = threadIdx.x;
  int v = (t < nbkt) ? cur_d[t] : 0;
  l[t] = v; __syncthreads();
  for (int off = 1; off < 256; off <<= 1) {
    int x = (t >= off) ? l[t - off] : 0; __syncthreads();
    l[t] += x; __syncthreads();
  }
  int incl = l[t];
  if (t < nbkt) { base_d[t] = incl - v; cur_d[t] = incl - v; }
  if (t == nbkt - 1) base_d[nbkt] = incl;
  __syncthreads();
  v = (t < nbkt) ? cur_s[t] : 0;
  l[t] = v; __syncthreads();
  for (int off = 1; off < 256; off <<= 1) {
    int x = (t >= off) ? l[t - off] : 0; __syncthreads();
    l[t] += x; __syncthreads();
  }
  incl = l[t];
  if (t < nbkt) { base_s[t] = incl - v; cur_s[t] = incl - v; }
  if (t == nbkt - 1) base_s[nbkt] = incl;
}

// block-staged bucket scatter: 2048 edges/block in regs; LDS per-bucket counts;
// one global atomicAdd per (bucket,block) to reserve; chunky tail writes.
__global__ __launch_bounds__(256)
void k_bkt_scatter(const int* __restrict__ src, const int* __restrict__ dst,
                   const float* __restrict__ eattr2,
                   int* __restrict__ cur_d, int* __restrict__ cur_s,
                   int4* __restrict__ stage_d, int2* __restrict__ stage_s,
                   int nbkt, int E) {
  __shared__ int cd[256], cs[256], bd[256], bs[256];
  int t = threadIdx.x;
  cd[t] = 0; cs[t] = 0;
  __syncthreads();
  int base = blockIdx.x * 256 * CBK;
  int s[CBK], d[CBK]; unsigned ep[CBK];
#pragma unroll
  for (int c = 0; c < CBK; ++c) {
    int e = base + c * 256 + t;
    if (e < E) {
      s[c] = src[e]; d[c] = dst[e];
      float2 ev = *(const float2*)&eattr2[2 * e];
      ep[c] = pack_bf2(ev.x, ev.y);
      atomicAdd(&cd[d[c] >> BSH], 1);
      atomicAdd(&cs[s[c] >> BSH], 1);
    } else s[c] = -1;
  }
  __syncthreads();
  if (t < nbkt) {
    bd[t] = cd[t] ? atomicAdd(&cur_d[t], cd[t]) : 0;
    bs[t] = cs[t] ? atomicAdd(&cur_s[t], cs[t]) : 0;
    cd[t] = 0; cs[t] = 0;
  }
  __syncthreads();
#pragma unroll
  for (int c = 0; c < CBK; ++c) {
    if (s[c] < 0) continue;
    int db = d[c] >> BSH, sb = s[c] >> BSH;
    int pos = bd[db] + atomicAdd(&cd[db], 1);
    stage_d[pos] = make_int4(s[c], d[c], (int)ep[c], 0);
    int pos2 = bs[sb] + atomicAdd(&cs[sb], 1);
    stage_s[pos2] = make_int2(s[c], d[c]);
  }
}

// merged per-bucket counting sorts: blocks [0,nbkt) dst side, [nbkt,2nbkt) src.
__global__ __launch_bounds__(256)
void k_bkt_sort(const int4* __restrict__ stage_d, const int* __restrict__ base_d,
                int* __restrict__ rowptr_d, int2* __restrict__ rec,
                const int2* __restrict__ stage_s, const int* __restrict__ base_s,
                int* __restrict__ rowptr_s, int* __restrict__ srcnbr,
                int N, int nbkt) {
  int t = threadIdx.x;
  __shared__ int cnt[256], cur[256], l[256];
  if ((int)blockIdx.x < nbkt) {
    int b = blockIdx.x;
    int nlo = b << BSH;
    int b0 = base_d[b], b1 = base_d[b + 1];
    cnt[t] = 0;
    __syncthreads();
    for (int j = b0 + t; j < b1; j += 256)
      atomicAdd(&cnt[stage_d[j].y - nlo], 1);
    __syncthreads();
    int v = cnt[t];
    l[t] = v; __syncthreads();
    for (int off = 1; off < 256; off <<= 1) {
      int x = (t >= off) ? l[t - off] : 0; __syncthreads();
      l[t] += x; __syncthreads();
    }
    int excl = l[t] - v;
    if (nlo + t < N) rowptr_d[nlo + t] = b0 + excl;
    cur[t] = excl;
    __syncthreads();
    for (int j = b0 + t; j < b1; j += 256) {
      int4 r = stage_d[j];
      int pos = b0 + atomicAdd(&cur[r.y - nlo], 1);
      rec[pos] = make_int2(r.x, r.z);
    }
  } else {
    int b = blockIdx.x - nbkt;
    int nlo = b << BSH;
    int b0 = base_s[b], b1 = base_s[b + 1];
    cnt[t] = 0;
    __syncthreads();
    for (int j = b0 + t; j < b1; j += 256)
      atomicAdd(&cnt[stage_s[j].x - nlo], 1);
    __syncthreads();
    int v = cnt[t];
    l[t] = v; __syncthreads();
    for (int off = 1; off < 256; off <<= 1) {
      int x = (t >= off) ? l[t - off] : 0; __syncthreads();
      l[t] += x; __syncthreads();
    }
    int excl = l[t] - v;
    if (nlo + t < N) rowptr_s[nlo + t] = b0 + excl;
    cur[t] = excl;
    __syncthreads();
    for (int j = b0 + t; j < b1; j += 256) {
      int2 r = stage_s[j];
      int pos = b0 + atomicAdd(&cur[r.x - nlo], 1);
      srcnbr[pos] = r.y;
    }
  }
}

// MFMA GEMM + attention columns. A[N][K] f32 -> bf16 in-reg; Wf pre-swizzled
// B-fragments (9 col-tiles: 8 of W + 1 of wext). Block = 4 waves x 16 rows.
template<int K>
__global__ __launch_bounds__(256)
void k_gemm_att_mfma(const float* __restrict__ A, const unsigned short* __restrict__ Wf,
                     unsigned* __restrict__ h16, float* __restrict__ asd, int N) {
  int wv = threadIdx.x >> 6, lane = threadIdx.x & 63;
  int r0 = blockIdx.x * 64 + wv * 16;
  int arow = r0 + (lane & 15);
  int kbase = (lane >> 4) * 8;
  f32x4 acc[9];
#pragma unroll
  for (int ct = 0; ct < 9; ++ct) acc[ct] = (f32x4){0.f, 0.f, 0.f, 0.f};

#pragma unroll
  for (int kc = 0; kc < K; kc += 32) {
    float4 v0 = make_float4(0.f, 0.f, 0.f, 0.f);
    float4 v1 = make_float4(0.f, 0.f, 0.f, 0.f);
    if (arow < N) {
      const float* ap = A + (long long)arow * K + kc + kbase;
      v0 = *(const float4*)ap;
      v1 = *(const float4*)(ap + 4);
    }
    bf16x8s a;
    a[0] = (short)bf16r(v0.x); a[1] = (short)bf16r(v0.y);
    a[2] = (short)bf16r(v0.z); a[3] = (short)bf16r(v0.w);
    a[4] = (short)bf16r(v1.x); a[5] = (short)bf16r(v1.y);
    a[6] = (short)bf16r(v1.z); a[7] = (short)bf16r(v1.w);
    const unsigned short* wp = Wf + (size_t)(kc >> 5) * 9 * 512 + lane * 8;
#pragma unroll
    for (int ct = 0; ct < 9; ++ct) {
      bf16x8s b = *(const bf16x8s*)(wp + ct * 512);
      acc[ct] = __builtin_amdgcn_mfma_f32_16x16x32_bf16(a, b, acc[ct], 0, 0, 0);
    }
  }
  // D layout: col = lane&15, row = (lane>>4)*4 + reg
  int c = lane & 15;
  int orow = r0 + (lane >> 4) * 4;
#pragma unroll
  for (int r = 0; r < 4; ++r) {
    int gr = orow + r;
    if (gr >= N) continue;
#pragma unroll
    for (int ct = 0; ct < 4; ++ct)
      h16[((long long)gr << 6) | (ct * 16 + c)] = pack_bf2(acc[ct][r], acc[ct + 4][r]);
    if (c < 4) asd[gr * 4 + c] = acc[8][r];
  }
}

// Fused GAT edge phase, pull-mode. ONE 16-LANE GROUP PER DST NODE (4/wave).
// Phase A: 16 lanes process 16 edges (coalesced rec reads, asd gather, exp,
// LDS stage). Phase B: lane = col-quad (uint4 of h16 row), group iterates its
// edges. den/se reduced with 4 shfl_xor within the group.
template<bool RELU, bool HEAD>
__global__ __launch_bounds__(256)
void k_gat_pull(const int* __restrict__ rowptr, const int2* __restrict__ rec,
                const float* __restrict__ asd, const unsigned* __restrict__ h16,
                const float* __restrict__ we, const float* __restrict__ bias,
                const float* __restrict__ Wn, const float* __restrict__ bn,
                const float* __restrict__ Wec,
                float* __restrict__ out, float* __restrict__ p_n,
                int2* __restrict__ fgn8, int N, int E) {
  __shared__ int2 ed[4][64];
  int wv = threadIdx.x >> 6, lane = threadIdx.x & 63;
  int g = lane >> 4;        // group (node) within wave
  int tl = lane & 15;       // lane within group = col-quad index
  int d = blockIdx.x * 16 + wv * 4 + g;
  if (d >= N) return;       // whole group exits together (shfl stays in-group)
  int r0 = rowptr[d];
  int r1 = (d + 1 < N) ? rowptr[d + 1] : E;
  int deg = r1 - r0;
  float4 Ad = *(const float4*)&asd[4 * d];
  float w0 = we[0], w1 = we[1], w2 = we[2], w3 = we[3];
  float den0 = 0.f, den1 = 0.f, se0 = 0.f, se1 = 0.f;
  float accA[4] = {0.f, 0.f, 0.f, 0.f}, accB[4] = {0.f, 0.f, 0.f, 0.f};
  int2* edg = &ed[wv][g << 4];
  for (int cb = 0; cb < deg; cb += 16) {
    int j = cb + tl;
    int s = 0; unsigned eapk = 0;
    if (j < deg) {
      int2 rc = rec[r0 + j];
      s = rc.x;
      unsigned ep = (unsigned)rc.y;
      float e0 = bf_lo(ep), e1 = bf_hi(ep);
      float4 As = *(const float4*)&asd[4 * s];
      float x0 = As.x + Ad.z + e0 * w0 + e1 * w1;
      float x1 = As.y + Ad.w + e0 * w2 + e1 * w3;
      x0 = x0 >= 0.f ? x0 : 0.2f * x0;
      x1 = x1 >= 0.f ? x1 : 0.2f * x1;
      float ea0 = fexp(x0), ea1 = fexp(x1);
      eapk = pack_bf2(ea0, ea1);
      den0 += ea0; den1 += ea1; se0 += e0; se1 += e1;
    }
    edg[tl] = make_int2(s, (int)eapk);   // same-wave LDS: no barrier needed
    int m = min(16, deg - cb);
    int j2 = 0;
    for (; j2 + 2 <= m; j2 += 2) {       // 2 edges in flight
      int2 va = edg[j2];
      int2 vb = edg[j2 + 1];
      uint4 qa = *(const uint4*)&h16[((long long)va.x << 6) | (tl << 2)];
      uint4 qb = *(const uint4*)&h16[((long long)vb.x << 6) | (tl << 2)];
      float a0 = bf_lo((unsigned)va.y), a1 = bf_hi((unsigned)va.y);
      float b0 = bf_lo((unsigned)vb.y), b1 = bf_hi((unsigned)vb.y);
      accA[0] += a0 * bf_lo(qa.x); accB[0] += a1 * bf_hi(qa.x);
      accA[1] += a0 * bf_lo(qa.y); accB[1] += a1 * bf_hi(qa.y);
      accA[2] += a0 * bf_lo(qa.z); accB[2] += a1 * bf_hi(qa.z);
      accA[3] += a0 * bf_lo(qa.w); accB[3] += a1 * bf_hi(qa.w);
      accA[0] += b0 * bf_lo(qb.x); accB[0] += b1 * bf_hi(qb.x);
      accA[1] += b0 * bf_lo(qb.y); accB[1] += b1 * bf_hi(qb.y);
      accA[2] += b0 * bf_lo(qb.z); accB[2] += b1 * bf_hi(qb.z);
      accA[3] += b0 * bf_lo(qb.w); accB[3] += b1 * bf_hi(qb.w);
    }
    if (j2 < m) {
      int2 va = edg[j2];
      uint4 qa = *(const uint4*)&h16[((long long)va.x << 6) | (tl << 2)];
      float a0 = bf_lo((unsigned)va.y), a1 = bf_hi((unsigned)va.y);
      accA[0] += a0 * bf_lo(qa.x); accB[0] += a1 * bf_hi(qa.x);
      accA[1] += a0 * bf_lo(qa.y); accB[1] += a1 * bf_hi(qa.y);
      accA[2] += a0 * bf_lo(qa.z); accB[2] += a1 * bf_hi(qa.z);
      accA[3] += a0 * bf_lo(qa.w); accB[3] += a1 * bf_hi(qa.w);
    }
  }
  // reduce den/se within the 16-lane group (offsets stay inside the group)
  for (int off = 8; off; off >>= 1) {
    den0 += __shfl_xor(den0, off); den1 += __shfl_xor(den1, off);
    se0  += __shfl_xor(se0, off);  se1  += __shfl_xor(se1, off);
  }
  // self-loop (identical on all 16 lanes)
  float id = frcp(fmaxf((float)deg, 1.0f));
  float le0 = se0 * id, le1 = se1 * id;
  float x0 = Ad.x + Ad.z + le0 * w0 + le1 * w1;
  float x1 = Ad.y + Ad.w + le0 * w2 + le1 * w3;
  x0 = x0 >= 0.f ? x0 : 0.2f * x0;
  x1 = x1 >= 0.f ? x1 : 0.2f * x1;
  float eas0 = fexp(x0), eas1 = fexp(x1);
  den0 += eas0; den1 += eas1;
  uint4 qd = *(const uint4*)&h16[((long long)d << 6) | (tl << 2)];
  accA[0] += eas0 * bf_lo(qd.x); accB[0] += eas1 * bf_hi(qd.x);
  accA[1] += eas0 * bf_lo(qd.y); accB[1] += eas1 * bf_hi(qd.y);
  accA[2] += eas0 * bf_lo(qd.z); accB[2] += eas1 * bf_hi(qd.z);
  accA[3] += eas0 * bf_lo(qd.w); accB[3] += eas1 * bf_hi(qd.w);
  float rcp0 = frcp(den0 + 1e-16f), rcp1 = frcp(den1 + 1e-16f);
  float4 bs = *(const float4*)&bias[tl << 2];
  float v0 = 0.5f * (accA[0] * rcp0 + accB[0] * rcp1) + bs.x;
  float v1 = 0.5f * (accA[1] * rcp0 + accB[1] * rcp1) + bs.y;
  float v2 = 0.5f * (accA[2] * rcp0 + accB[2] * rcp1) + bs.z;
  float v3 = 0.5f * (accA[3] * rcp0 + accB[3] * rcp1) + bs.w;
  if (HEAD) {
    int c0 = tl << 2;
    float pv[7];
#pragma unroll
    for (int j = 0; j < 5; ++j)
      pv[j] = v0 * Wn[c0 * 5 + j] + v1 * Wn[(c0 + 1) * 5 + j]
            + v2 * Wn[(c0 + 2) * 5 + j] + v3 * Wn[(c0 + 3) * 5 + j];
    pv[5] = v0 * Wec[c0 * 2] + v1 * Wec[(c0 + 1) * 2]
          + v2 * Wec[(c0 + 2) * 2] + v3 * Wec[(c0 + 3) * 2];
    pv[6] = v0 * Wec[c0 * 2 + 1] + v1 * Wec[(c0 + 1) * 2 + 1]
          + v2 * Wec[(c0 + 2) * 2 + 1] + v3 * Wec[(c0 + 3) * 2 + 1];
    for (int off = 8; off; off >>= 1) {
#pragma unroll
      for (int j = 0; j < 7; ++j) pv[j] += __shfl_xor(pv[j], off);
    }
    if (tl == 0) {
      float l[5]; float m = -1e30f;
#pragma unroll
      for (int j = 0; j < 5; ++j) { l[j] = pv[j] + bn[j]; m = fmaxf(m, l[j]); }
      float ssum = 0.f;
#pragma unroll
      for (int j = 0; j < 5; ++j) { l[j] = fexp(l[j] - m); ssum += l[j]; }
      float inv = frcp(ssum);
#pragma unroll
      for (int j = 0; j < 5; ++j) p_n[5 * d + j] = l[j] * inv;
      float nab0 = (ssum - l[0]) * inv;
      fgn8[d] = make_int2(__float_as_int(pv[6] - pv[5]), (int)pack_bf2(nab0, 0.f));
    }
  } else {
    if (RELU) {
      v0 = fmaxf(v0, 0.f); v1 = fmaxf(v1, 0.f);
      v2 = fmaxf(v2, 0.f); v3 = fmaxf(v3, 0.f);
    }
    *(float4*)&out[(long long)d * 64 + (tl << 2)] = make_float4(v0, v1, v2, v3);
  }
}

// eab = c / (c + exp(-t)) : one rcp, shared structure.
__device__ __forceinline__ float fg_eab(float t, float c) {
  return c * frcp(c + fexp(-t));
}

// factor-graph node-pull iteration 1. One thread per node. fgn8 = {q, bf16x2 nab}.
__global__ void k_fg_pull1(const int* __restrict__ rowptr_d, const int2* __restrict__ rec,
                           const int* __restrict__ rowptr_s, const int* __restrict__ srcnbr,
                           float* __restrict__ p_n, int2* __restrict__ fgn8,
                           const float* __restrict__ consts, int N, int E) {
  int n = blockIdx.x * blockDim.x + threadIdx.x;
  if (n >= N) return;
  int2 F = fgn8[n];
  float q = __uint_as_float((unsigned)F.x);
  float nab0 = bf_lo((unsigned)F.y);
  float avg_ef = consts[8], avg_nf = consts[9], dbec = consts[10];
  int rd0 = rowptr_d[n], rd1 = (n + 1 < N) ? rowptr_d[n + 1] : E;
  int rs0 = rowptr_s[n], rs1 = (n + 1 < N) ? rowptr_s[n + 1] : E;
  float s_eab = 0.f;
  for (int j = rd0; j < rd1; ++j) {
    int2 Fo = fgn8[rec[j].x];
    float t = 0.5f * (q + __uint_as_float((unsigned)Fo.x)) + dbec;
    float c = 1.0f + fmaxf(nab0, bf_lo((unsigned)Fo.y)) * avg_ef;
    s_eab += fg_eab(t, c);
  }
  for (int j = rs0; j < rs1; ++j) {
    int2 Fo = fgn8[srcnbr[j]];
    float t = 0.5f * (q + __uint_as_float((unsigned)Fo.x)) + dbec;
    float c = 1.0f + fmaxf(nab0, bf_lo((unsigned)Fo.y)) * avg_ef;
    s_eab += fg_eab(t, c);
  }
  float deg = (float)((rd1 - rd0) + (rs1 - rs0));
  float mean = s_eab * frcp(deg + 1e-6f);
  float f = 1.0f + mean * avg_nf;
  float p0 = p_n[5 * n], p1 = p_n[5 * n + 1], p2 = p_n[5 * n + 2],
        p3 = p_n[5 * n + 3], p4 = p_n[5 * n + 4];
  float rest = (p1 + p2 + p3 + p4) * f;
  float inv = frcp(p0 + rest);
  p_n[5 * n]     = p0 * inv;
  p_n[5 * n + 1] = p1 * f * inv;
  p_n[5 * n + 2] = p2 * f * inv;
  p_n[5 * n + 3] = p3 * f * inv;
  p_n[5 * n + 4] = p4 * f * inv;
  fgn8[n].y = (int)pack_bf2(nab0, rest * inv);
}

// merged final pass: blocks [0, nodeBlocks) = fg iteration 2 (writes out_n);
// blocks [nodeBlocks, ...) = edge output. Both only READ fgn8.
__global__ void k_fg_final(const int* __restrict__ rowptr_d, const int2* __restrict__ rec,
                           const int* __restrict__ rowptr_s, const int* __restrict__ srcnbr,
                           const float* __restrict__ p_n, const int2* __restrict__ fgn8,
                           const float* __restrict__ consts,
                           const int* __restrict__ src, const int* __restrict__ dst,
                           float* __restrict__ out_n, float* __restrict__ out_e,
                           int N, int E, int nodeBlocks) {
  float avg_ef = consts[8], dbec = consts[10];
  if ((int)blockIdx.x < nodeBlocks) {
    int n = blockIdx.x * blockDim.x + threadIdx.x;
    if (n >= N) return;
    float avg_nf = consts[9];
    int2 F = fgn8[n];
    float q = __uint_as_float((unsigned)F.x);
    float nab0 = bf_lo((unsigned)F.y), nab1 = bf_hi((unsigned)F.y);
    int rd0 = rowptr_d[n], rd1 = (n + 1 < N) ? rowptr_d[n + 1] : E;
    int rs0 = rowptr_s[n], rs1 = (n + 1 < N) ? rowptr_s[n + 1] : E;
    float s_eab = 0.f;
    for (int j = rd0; j < rd1; ++j) {
      int2 Fo = fgn8[rec[j].x];
      float t = 0.5f * (q + __uint_as_float((unsigned)Fo.x)) + dbec;
      float c = (1.0f + fmaxf(nab0, bf_lo((unsigned)Fo.y)) * avg_ef)
              * (1.0f + fmaxf(nab1, bf_hi((unsigned)Fo.y)) * avg_ef);
      s_eab += fg_eab(t, c);
    }
    for (int j = rs0; j < rs1; ++j) {
      int2 Fo = fgn8[srcnbr[j]];
      float t = 0.5f * (q + __uint_as_float((unsigned)Fo.x)) + dbec;
      float c = (1.0f + fmaxf(nab0, bf_lo((unsigned)Fo.y)) * avg_ef)
              * (1.0f + fmaxf(nab1, bf_hi((unsigned)Fo.y)) * avg_ef);
      s_eab += fg_eab(t, c);
    }
    float deg = (float)((rd1 - rd0) + (rs1 - rs0));
    float mean = s_eab * frcp(deg + 1e-6f);
    float f = 1.0f + mean * avg_nf;
    float p0 = p_n[5 * n], p1 = p_n[5 * n + 1], p2 = p_n[5 * n + 2],
          p3 = p_n[5 * n + 3], p4 = p_n[5 * n + 4];
    float rest = (p1 + p2 + p3 + p4) * f;
    float inv = frcp(p0 + rest);
    out_n[5 * n]     = flog(p0 * inv + 1e-9f);
    out_n[5 * n + 1] = flog(p1 * f * inv + 1e-9f);
    out_n[5 * n + 2] = flog(p2 * f * inv + 1e-9f);
    out_n[5 * n + 3] = flog(p3 * f * inv + 1e-9f);
    out_n[5 * n + 4] = flog(p4 * f * inv + 1e-9f);
  } else {
    int e = (blockIdx.x - nodeBlocks) * blockDim.x + threadIdx.x;
    if (e >= E) return;
    int2 Fs = fgn8[src[e]];
    int2 Fd = fgn8[dst[e]];
    float t = 0.5f * (__uint_as_float((unsigned)Fs.x) + __uint_as_float((unsigned)Fd.x)) + dbec;
    float c = (1.0f + fmaxf(bf_lo((unsigned)Fs.y), bf_lo((unsigned)Fd.y)) * avg_ef)
            * (1.0f + fmaxf(bf_hi((unsigned)Fs.y), bf_hi((unsigned)Fd.y)) * avg_ef);
    float ei = fexp(-t);
    float r = frcp(c + ei);
    float pe1 = c * r, pe0 = ei * r;
    *(float2*)&out_e[2 * e] = make_float2(flog(pe0 + 1e-9f), flog(pe1 + 1e-9f));
  }
}

extern "C" void kernel_launch(void* const* d_in, const int* in_sizes, int n_in,
                              void* d_out, int out_size, void* d_ws, size_t ws_size,
                              hipStream_t stream) {
  const float* x      = (const float*)d_in[0];
  const int*   ei     = (const int*)d_in[1];
  const float* eattr  = (const float*)d_in[2];
  const float* W1     = (const float*)d_in[3];
  const float* atts1  = (const float*)d_in[4];
  const float* attd1  = (const float*)d_in[5];
  const float* We1    = (const float*)d_in[6];
  const float* atte1  = (const float*)d_in[7];
  const float* b1     = (const float*)d_in[8];
  const float* W2     = (const float*)d_in[9];
  const float* atts2  = (const float*)d_in[10];
  const float* attd2  = (const float*)d_in[11];
  const float* We2    = (const float*)d_in[12];
  const float* atte2  = (const float*)d_in[13];
  const float* b2     = (const float*)d_in[14];
  const float* Wn     = (const float*)d_in[15];
  const float* bn     = (const float*)d_in[16];
  const float* Wec    = (const float*)d_in[17];
  const float* bec    = (const float*)d_in[18];
  const float* nodefw = (const float*)d_in[19];
  const float* edgefw = (const float*)d_in[20];

  const int N = in_sizes[0] / 128;
  const int E = in_sizes[1] / 2;
  const int* src = ei;
  const int* dst = ei + E;
  const int nbkt = (N + 255) >> BSH;   // 196 (assumes N <= 65536)

  float* out_n = (float*)d_out;
  float* out_e = out_n + (long long)N * 5;

  // ---- workspace carve (f32 units, 16B aligned) ----
  size_t off = 0;
  float* base = (float*)d_ws;
  auto carve = [&](size_t nelem) { float* p = base + off; off += (nelem + 3) & ~(size_t)3; return p; };
  unsigned* h16      = (unsigned*)carve((size_t)N * 64);  // aliases stage_d during prep
  float*    x2       = carve((size_t)N * 64);             // aliases stage_s during prep
  float*    asd      = carve((size_t)N * 4);
  int2*     rec      = (int2*)carve((size_t)E * 2);       // {src, bf16x2 eattr}
  int*      srcnbr   = (int*)carve((size_t)E);
  int*      rowptr_d = (int*)carve((size_t)N);
  int*      rowptr_s = (int*)carve((size_t)N);
  int*      bktcur_d = (int*)carve(256);
  int*      bktcur_s = (int*)carve(256);
  int*      bktbas_d = (int*)carve(260);
  int*      bktbas_s = (int*)carve(260);
  float*    p_n      = carve((size_t)N * 5);
  int2*     fgn8     = (int2*)carve((size_t)N * 2);
  float*    consts   = carve(16);
  unsigned short* wf1 = (unsigned short*)carve(9216);     // 4*9*512 bf16
  unsigned short* wf2 = (unsigned short*)carve(4608);     // 2*9*512 bf16
  if (off * sizeof(float) > ws_size) return;  // insufficient scratch: fail loudly

  // bucket staging aliases h16/x2 (CSR build completes before they're written):
  int4* stage_d = (int4*)h16;
  int2* stage_s = (int2*)x2;

  const int B = 256;
  const int gE  = cdiv_i(E, B);
  const int gN  = cdiv_i(N, B);

  // ---- graph prep: bucketed CSR build (both directions) ----
  hipMemsetAsync(bktcur_d, 0, 256 * 4, stream);
  hipMemsetAsync(bktcur_s, 0, 256 * 4, stream);
  k_prep_consts<<<1, 64, 0, stream>>>(We1, atte1, We2, atte2, nodefw, edgefw, bec, consts);
  k_prep_wfrag<<<1, 256, 0, stream>>>(W1, atts1, attd1, W2, atts2, attd2, wf1, wf2);
  k_bkt_hist<<<256, 256, 0, stream>>>(src, dst, bktcur_d, bktcur_s, nbkt, E);
  k_bkt_scan<<<1, 256, 0, stream>>>(bktcur_d, bktbas_d, bktcur_s, bktbas_s, nbkt);
  k_bkt_scatter<<<cdiv_i(E, 256 * CBK), 256, 0, stream>>>(src, dst, eattr, bktcur_d, bktcur_s,
                                                          stage_d, stage_s, nbkt, E);
  k_bkt_sort<<<2 * nbkt, 256, 0, stream>>>(stage_d, bktbas_d, rowptr_d, rec,
                                           stage_s, bktbas_s, rowptr_s, srcnbr, N, nbkt);

  // ---- GAT layer 1 (gemm writes h16+asd; pull writes x2) ----
  k_gemm_att_mfma<128><<<cdiv_i(N, 64), 256, 0, stream>>>(x, wf1, h16, asd, N);
  k_gat_pull<true, false><<<cdiv_i(N, 16), 256, 0, stream>>>(
      rowptr_d, rec, asd, h16, consts, b1,
      nullptr, nullptr, nullptr, x2, nullptr, nullptr, N, E);

  // ---- GAT layer 2 (+ fused heads) ----
  k_gemm_att_mfma<64><<<cdiv_i(N, 64), 256, 0, stream>>>(x2, wf2, h16, asd, N);
  k_gat_pull<false, true><<<cdiv_i(N, 16), 256, 0, stream>>>(
      rowptr_d, rec, asd, h16, consts + 4, b2,
      Wn, bn, Wec, nullptr, p_n, fgn8, N, E);

  // ---- factor graph: iter1 + merged (iter2 + edge output) ----
  k_fg_pull1<<<gN, B, 0, stream>>>(rowptr_d, rec, rowptr_s, srcnbr,
                                   p_n, fgn8, consts, N, E);
  k_fg_final<<<gN + gE, B, 0, stream>>>(rowptr_d, rec, rowptr_s, srcnbr,
                                        p_n, fgn8, consts, src, dst,
                                        out_n, out_e, N, E, gN);
}

// Round 14
// 219.459 us; speedup vs baseline: 1.6812x; 1.1331x over previous
//
#include <hip/hip_runtime.h>
#include <math.h>

// GraphRespiratory: 2-layer GAT (edge features, concat=False) + factor graph.
// N=50000, E=800000, IN=128, HID=OUT=64, H=2, NC=5, EC=2, NUM_ITER=2, GAMMA=1.
//
// R13 changes vs R12:
//  - hipMemsetAsync fills removed: bucket cursors zeroed inside the merged
//    k_prep kernel (consts + wext + wfrag + cursor zero in ONE dispatch).
//  - Factor-graph node kernels use 4 LANES PER NODE (stride-4 edge split +
//    2 shfl_xor reduce): 50k->200k threads (~3->12 waves/CU), serial gather
//    chain 32->8. Fixes the TLP shortage of one-thread-per-node.

static inline int cdiv_i(long long a, long long b) { return (int)((a + b - 1) / b); }

#define BSH 8           // bucket shift: 256 nodes per bucket
#define CBK 8           // edges per thread in bucket scatter (2048/block)

typedef __attribute__((ext_vector_type(8))) short bf16x8s;
typedef __attribute__((ext_vector_type(4))) float f32x4;

__device__ __forceinline__ float fexp(float x) {
  return __builtin_amdgcn_exp2f(x * 1.44269504088896f);
}
__device__ __forceinline__ float flog(float x) {
  return __builtin_amdgcn_logf(x) * 0.693147180559945f;
}
__device__ __forceinline__ float frcp(float x) {
  return __builtin_amdgcn_rcpf(x);
}

__device__ __forceinline__ unsigned short bf16r(float x) {
  unsigned u = __float_as_uint(x);
  return (unsigned short)((u + 0x7fffu + ((u >> 16) & 1u)) >> 16);
}
__device__ __forceinline__ unsigned pack_bf2(float a, float b) {
  unsigned ua = __float_as_uint(a), ub = __float_as_uint(b);
  unsigned ra = (ua + 0x7fffu + ((ua >> 16) & 1u)) >> 16;
  unsigned rb = (ub + 0x7fffu + ((ub >> 16) & 1u)) & 0xffff0000u;
  return ra | rb;
}
__device__ __forceinline__ float bf_lo(unsigned v) { return __uint_as_float(v << 16); }
__device__ __forceinline__ float bf_hi(unsigned v) { return __uint_as_float(v & 0xffff0000u); }

// Merged prep (ONE block): zero bucket cursors; consts; wext (LDS); wfrag.
// consts: [0..3] w_e1[h][k], [4..7] w_e2[h][k], [8] avg_ef, [9] avg_nf, [10] dbec
// wf layout: [K/32][9][64 lanes][8 j]; element = W[kc+(lane>>4)*8+j][ct*16+(lane&15)]
__global__ __launch_bounds__(256)
void k_prep(const float* __restrict__ W1, const float* __restrict__ as1,
            const float* __restrict__ ad1, const float* __restrict__ atte1,
            const float* __restrict__ We1,
            const float* __restrict__ W2, const float* __restrict__ as2,
            const float* __restrict__ ad2, const float* __restrict__ atte2,
            const float* __restrict__ We2,
            const float* __restrict__ node_fw, const float* __restrict__ edge_fw,
            const float* __restrict__ bec, float* __restrict__ consts,
            unsigned short* __restrict__ wf1, unsigned short* __restrict__ wf2,
            int* __restrict__ cur_d, int* __restrict__ cur_s) {
  __shared__ float wext1[128 * 4], wext2[64 * 4];
  int t = threadIdx.x;
  cur_d[t] = 0; cur_s[t] = 0;
  if (t == 0) {
    for (int h = 0; h < 2; ++h)
      for (int k = 0; k < 2; ++k) {
        float s1 = 0.f, s2 = 0.f;
        for (int c = 0; c < 64; ++c) {
          s1 += We1[k * 128 + h * 64 + c] * atte1[h * 64 + c];
          s2 += We2[k * 128 + h * 64 + c] * atte2[h * 64 + c];
        }
        consts[h * 2 + k] = s1;
        consts[4 + h * 2 + k] = s2;
      }
    float ef = 0.f;                    // edge_fw is [EC=2, NC=5]; mean of [1:,1:]
    for (int j = 1; j < 5; ++j) ef += edge_fw[5 + j];
    consts[8] = ef * 0.25f;
    float nf = 0.f;                    // node_fw is [NC=5, EC=2]; mean of [1:,1:]
    for (int i = 1; i < 5; ++i) nf += node_fw[i * 2 + 1];
    consts[9] = nf * 0.25f;
    consts[10] = bec[1] - bec[0];
  }
  for (int o = t; o < 128 * 4; o += 256) {
    int k = o >> 2, j = o & 3;
    const float* att = (j < 2 ? as1 : ad1) + (j & 1) * 64;
    const float* wr = W1 + k * 128 + (j & 1) * 64;
    float s = 0.f;
    for (int c = 0; c < 64; ++c) s += wr[c] * att[c];
    wext1[o] = s;
  }
  for (int o = t; o < 64 * 4; o += 256) {
    int k = o >> 2, j = o & 3;
    const float* att = (j < 2 ? as2 : ad2) + (j & 1) * 64;
    const float* wr = W2 + k * 128 + (j & 1) * 64;
    float s = 0.f;
    for (int c = 0; c < 64; ++c) s += wr[c] * att[c];
    wext2[o] = s;
  }
  __syncthreads();
  for (int o = t; o < 4 * 9 * 512; o += 256) {       // K=128
    int kc = o / (9 * 512), rem = o % (9 * 512);
    int ct = rem / 512, li = rem % 512;
    int lane = li >> 3, j = li & 7;
    int k = kc * 32 + ((lane >> 4) << 3) + j, c = lane & 15;
    float v = (ct < 8) ? W1[k * 128 + ct * 16 + c] : (c < 4 ? wext1[k * 4 + c] : 0.f);
    wf1[o] = bf16r(v);
  }
  for (int o = t; o < 2 * 9 * 512; o += 256) {       // K=64
    int kc = o / (9 * 512), rem = o % (9 * 512);
    int ct = rem / 512, li = rem % 512;
    int lane = li >> 3, j = li & 7;
    int k = kc * 32 + ((lane >> 4) << 3) + j, c = lane & 15;
    float v = (ct < 8) ? W2[k * 128 + ct * 16 + c] : (c < 4 ? wext2[k * 4 + c] : 0.f);
    wf2[o] = bf16r(v);
  }
}

// ---- bucketed CSR build ----
__global__ void k_bkt_hist(const int* __restrict__ src, const int* __restrict__ dst,
                           int* __restrict__ hist_d, int* __restrict__ hist_s,
                           int nbkt, int E) {
  __shared__ int hd[256], hs[256];
  int t = threadIdx.x;
  hd[t] = 0; hs[t] = 0;
  __syncthreads();
  for (int e = blockIdx.x * blockDim.x + t; e < E; e += gridDim.x * blockDim.x) {
    atomicAdd(&hd[dst[e] >> BSH], 1);
    atomicAdd(&hs[src[e] >> BSH], 1);
  }
  __syncthreads();
  if (t < nbkt) {
    if (hd[t]) atomicAdd(&hist_d[t], hd[t]);
    if (hs[t]) atomicAdd(&hist_s[t], hs[t]);
  }
}

// one block: exclusive-scan both histograms -> bases (nbkt+1) and cursors (in place)
__global__ void k_bkt_scan(int* __restrict__ cur_d, int* __restrict__ base_d,
                           int* __restrict__ cur_s, int* __restrict__ base_s, int nbkt) {
  __shared__ int l[256];
  int t = threadIdx.x;
  int v = (t < nbkt) ? cur_d[t] : 0;
  l[t] = v; __syncthreads();
  for (int off = 1; off < 256; off <<= 1) {
    int x = (t >= off) ? l[t - off] : 0; __syncthreads();
    l[t] += x; __syncthreads();
  }
  int incl = l[t];
  if (t < nbkt) { base_d[t] = incl - v; cur_d[t] = incl - v; }
  if (t == nbkt - 1) base_d[nbkt] = incl;
  __syncthreads();
  v = (t < nbkt) ? cur_s[t] : 0;
  l[t] = v; __syncthreads();
  for (int off = 1; off < 256; off <<= 1) {
    int x = (t >= off) ? l[t - off] : 0; __syncthreads();
    l[t] += x; __syncthreads();
  }
  incl = l[t];
  if (t < nbkt) { base_s[t] = incl - v; cur_s[t] = incl - v; }
  if (t == nbkt - 1) base_s[nbkt] = incl;
}

// block-staged bucket scatter: 2048 edges/block in regs; LDS per-bucket counts;
// one global atomicAdd per (bucket,block) to reserve; chunky tail writes.
__global__ __launch_bounds__(256)
void k_bkt_scatter(const int* __restrict__ src, const int* __restrict__ dst,
                   const float* __restrict__ eattr2,
                   int* __restrict__ cur_d, int* __restrict__ cur_s,
                   int4* __restrict__ stage_d, int2* __restrict__ stage_s,
                   int nbkt, int E) {
  __shared__ int cd[256], cs[256], bd[256], bs[256];
  int t = threadIdx.x;
  cd[t] = 0; cs[t] = 0;
  __syncthreads();
  int base = blockIdx.x * 256 * CBK;
  int s[CBK], d[CBK]; unsigned ep[CBK];
#pragma unroll
  for (int c = 0; c < CBK; ++c) {
    int e = base + c * 256 + t;
    if (e < E) {
      s[c] = src[e]; d[c] = dst[e];
      float2 ev = *(const float2*)&eattr2[2 * e];
      ep[c] = pack_bf2(ev.x, ev.y);
      atomicAdd(&cd[d[c] >> BSH], 1);
      atomicAdd(&cs[s[c] >> BSH], 1);
    } else s[c] = -1;
  }
  __syncthreads();
  if (t < nbkt) {
    bd[t] = cd[t] ? atomicAdd(&cur_d[t], cd[t]) : 0;
    bs[t] = cs[t] ? atomicAdd(&cur_s[t], cs[t]) : 0;
    cd[t] = 0; cs[t] = 0;
  }
  __syncthreads();
#pragma unroll
  for (int c = 0; c < CBK; ++c) {
    if (s[c] < 0) continue;
    int db = d[c] >> BSH, sb = s[c] >> BSH;
    int pos = bd[db] + atomicAdd(&cd[db], 1);
    stage_d[pos] = make_int4(s[c], d[c], (int)ep[c], 0);
    int pos2 = bs[sb] + atomicAdd(&cs[sb], 1);
    stage_s[pos2] = make_int2(s[c], d[c]);
  }
}

// merged per-bucket counting sorts: blocks [0,nbkt) dst side, [nbkt,2nbkt) src.
__global__ __launch_bounds__(256)
void k_bkt_sort(const int4* __restrict__ stage_d, const int* __restrict__ base_d,
                int* __restrict__ rowptr_d, int2* __restrict__ rec,
                const int2* __restrict__ stage_s, const int* __restrict__ base_s,
                int* __restrict__ rowptr_s, int* __restrict__ srcnbr,
                int N, int nbkt) {
  int t = threadIdx.x;
  __shared__ int cnt[256], cur[256], l[256];
  if ((int)blockIdx.x < nbkt) {
    int b = blockIdx.x;
    int nlo = b << BSH;
    int b0 = base_d[b], b1 = base_d[b + 1];
    cnt[t] = 0;
    __syncthreads();
    for (int j = b0 + t; j < b1; j += 256)
      atomicAdd(&cnt[stage_d[j].y - nlo], 1);
    __syncthreads();
    int v = cnt[t];
    l[t] = v; __syncthreads();
    for (int off = 1; off < 256; off <<= 1) {
      int x = (t >= off) ? l[t - off] : 0; __syncthreads();
      l[t] += x; __syncthreads();
    }
    int excl = l[t] - v;
    if (nlo + t < N) rowptr_d[nlo + t] = b0 + excl;
    cur[t] = excl;
    __syncthreads();
    for (int j = b0 + t; j < b1; j += 256) {
      int4 r = stage_d[j];
      int pos = b0 + atomicAdd(&cur[r.y - nlo], 1);
      rec[pos] = make_int2(r.x, r.z);
    }
  } else {
    int b = blockIdx.x - nbkt;
    int nlo = b << BSH;
    int b0 = base_s[b], b1 = base_s[b + 1];
    cnt[t] = 0;
    __syncthreads();
    for (int j = b0 + t; j < b1; j += 256)
      atomicAdd(&cnt[stage_s[j].x - nlo], 1);
    __syncthreads();
    int v = cnt[t];
    l[t] = v; __syncthreads();
    for (int off = 1; off < 256; off <<= 1) {
      int x = (t >= off) ? l[t - off] : 0; __syncthreads();
      l[t] += x; __syncthreads();
    }
    int excl = l[t] - v;
    if (nlo + t < N) rowptr_s[nlo + t] = b0 + excl;
    cur[t] = excl;
    __syncthreads();
    for (int j = b0 + t; j < b1; j += 256) {
      int2 r = stage_s[j];
      int pos = b0 + atomicAdd(&cur[r.x - nlo], 1);
      srcnbr[pos] = r.y;
    }
  }
}

// MFMA GEMM + attention columns. A[N][K] f32 -> bf16 in-reg; Wf pre-swizzled
// B-fragments (9 col-tiles: 8 of W + 1 of wext). Block = 4 waves x 16 rows.
template<int K>
__global__ __launch_bounds__(256)
void k_gemm_att_mfma(const float* __restrict__ A, const unsigned short* __restrict__ Wf,
                     unsigned* __restrict__ h16, float* __restrict__ asd, int N) {
  int wv = threadIdx.x >> 6, lane = threadIdx.x & 63;
  int r0 = blockIdx.x * 64 + wv * 16;
  int arow = r0 + (lane & 15);
  int kbase = (lane >> 4) * 8;
  f32x4 acc[9];
#pragma unroll
  for (int ct = 0; ct < 9; ++ct) acc[ct] = (f32x4){0.f, 0.f, 0.f, 0.f};

#pragma unroll
  for (int kc = 0; kc < K; kc += 32) {
    float4 v0 = make_float4(0.f, 0.f, 0.f, 0.f);
    float4 v1 = make_float4(0.f, 0.f, 0.f, 0.f);
    if (arow < N) {
      const float* ap = A + (long long)arow * K + kc + kbase;
      v0 = *(const float4*)ap;
      v1 = *(const float4*)(ap + 4);
    }
    bf16x8s a;
    a[0] = (short)bf16r(v0.x); a[1] = (short)bf16r(v0.y);
    a[2] = (short)bf16r(v0.z); a[3] = (short)bf16r(v0.w);
    a[4] = (short)bf16r(v1.x); a[5] = (short)bf16r(v1.y);
    a[6] = (short)bf16r(v1.z); a[7] = (short)bf16r(v1.w);
    const unsigned short* wp = Wf + (size_t)(kc >> 5) * 9 * 512 + lane * 8;
#pragma unroll
    for (int ct = 0; ct < 9; ++ct) {
      bf16x8s b = *(const bf16x8s*)(wp + ct * 512);
      acc[ct] = __builtin_amdgcn_mfma_f32_16x16x32_bf16(a, b, acc[ct], 0, 0, 0);
    }
  }
  // D layout: col = lane&15, row = (lane>>4)*4 + reg
  int c = lane & 15;
  int orow = r0 + (lane >> 4) * 4;
#pragma unroll
  for (int r = 0; r < 4; ++r) {
    int gr = orow + r;
    if (gr >= N) continue;
#pragma unroll
    for (int ct = 0; ct < 4; ++ct)
      h16[((long long)gr << 6) | (ct * 16 + c)] = pack_bf2(acc[ct][r], acc[ct + 4][r]);
    if (c < 4) asd[gr * 4 + c] = acc[8][r];
  }
}

// Fused GAT edge phase, pull-mode. ONE 16-LANE GROUP PER DST NODE (4/wave).
template<bool RELU, bool HEAD>
__global__ __launch_bounds__(256)
void k_gat_pull(const int* __restrict__ rowptr, const int2* __restrict__ rec,
                const float* __restrict__ asd, const unsigned* __restrict__ h16,
                const float* __restrict__ we, const float* __restrict__ bias,
                const float* __restrict__ Wn, const float* __restrict__ bn,
                const float* __restrict__ Wec,
                float* __restrict__ out, float* __restrict__ p_n,
                int2* __restrict__ fgn8, int N, int E) {
  __shared__ int2 ed[4][64];
  int wv = threadIdx.x >> 6, lane = threadIdx.x & 63;
  int g = lane >> 4;        // group (node) within wave
  int tl = lane & 15;       // lane within group = col-quad index
  int d = blockIdx.x * 16 + wv * 4 + g;
  if (d >= N) return;       // whole group exits together (shfl stays in-group)
  int r0 = rowptr[d];
  int r1 = (d + 1 < N) ? rowptr[d + 1] : E;
  int deg = r1 - r0;
  float4 Ad = *(const float4*)&asd[4 * d];
  float w0 = we[0], w1 = we[1], w2 = we[2], w3 = we[3];
  float den0 = 0.f, den1 = 0.f, se0 = 0.f, se1 = 0.f;
  float accA[4] = {0.f, 0.f, 0.f, 0.f}, accB[4] = {0.f, 0.f, 0.f, 0.f};
  int2* edg = &ed[wv][g << 4];
  for (int cb = 0; cb < deg; cb += 16) {
    int j = cb + tl;
    int s = 0; unsigned eapk = 0;
    if (j < deg) {
      int2 rc = rec[r0 + j];
      s = rc.x;
      unsigned ep = (unsigned)rc.y;
      float e0 = bf_lo(ep), e1 = bf_hi(ep);
      float4 As = *(const float4*)&asd[4 * s];
      float x0 = As.x + Ad.z + e0 * w0 + e1 * w1;
      float x1 = As.y + Ad.w + e0 * w2 + e1 * w3;
      x0 = x0 >= 0.f ? x0 : 0.2f * x0;
      x1 = x1 >= 0.f ? x1 : 0.2f * x1;
      float ea0 = fexp(x0), ea1 = fexp(x1);
      eapk = pack_bf2(ea0, ea1);
      den0 += ea0; den1 += ea1; se0 += e0; se1 += e1;
    }
    edg[tl] = make_int2(s, (int)eapk);   // same-wave LDS: no barrier needed
    int m = min(16, deg - cb);
    int j2 = 0;
    for (; j2 + 2 <= m; j2 += 2) {       // 2 edges in flight
      int2 va = edg[j2];
      int2 vb = edg[j2 + 1];
      uint4 qa = *(const uint4*)&h16[((long long)va.x << 6) | (tl << 2)];
      uint4 qb = *(const uint4*)&h16[((long long)vb.x << 6) | (tl << 2)];
      float a0 = bf_lo((unsigned)va.y), a1 = bf_hi((unsigned)va.y);
      float b0 = bf_lo((unsigned)vb.y), b1 = bf_hi((unsigned)vb.y);
      accA[0] += a0 * bf_lo(qa.x); accB[0] += a1 * bf_hi(qa.x);
      accA[1] += a0 * bf_lo(qa.y); accB[1] += a1 * bf_hi(qa.y);
      accA[2] += a0 * bf_lo(qa.z); accB[2] += a1 * bf_hi(qa.z);
      accA[3] += a0 * bf_lo(qa.w); accB[3] += a1 * bf_hi(qa.w);
      accA[0] += b0 * bf_lo(qb.x); accB[0] += b1 * bf_hi(qb.x);
      accA[1] += b0 * bf_lo(qb.y); accB[1] += b1 * bf_hi(qb.y);
      accA[2] += b0 * bf_lo(qb.z); accB[2] += b1 * bf_hi(qb.z);
      accA[3] += b0 * bf_lo(qb.w); accB[3] += b1 * bf_hi(qb.w);
    }
    if (j2 < m) {
      int2 va = edg[j2];
      uint4 qa = *(const uint4*)&h16[((long long)va.x << 6) | (tl << 2)];
      float a0 = bf_lo((unsigned)va.y), a1 = bf_hi((unsigned)va.y);
      accA[0] += a0 * bf_lo(qa.x); accB[0] += a1 * bf_hi(qa.x);
      accA[1] += a0 * bf_lo(qa.y); accB[1] += a1 * bf_hi(qa.y);
      accA[2] += a0 * bf_lo(qa.z); accB[2] += a1 * bf_hi(qa.z);
      accA[3] += a0 * bf_lo(qa.w); accB[3] += a1 * bf_hi(qa.w);
    }
  }
  // reduce den/se within the 16-lane group
  for (int off = 8; off; off >>= 1) {
    den0 += __shfl_xor(den0, off); den1 += __shfl_xor(den1, off);
    se0  += __shfl_xor(se0, off);  se1  += __shfl_xor(se1, off);
  }
  // self-loop (identical on all 16 lanes)
  float id = frcp(fmaxf((float)deg, 1.0f));
  float le0 = se0 * id, le1 = se1 * id;
  float x0 = Ad.x + Ad.z + le0 * w0 + le1 * w1;
  float x1 = Ad.y + Ad.w + le0 * w2 + le1 * w3;
  x0 = x0 >= 0.f ? x0 : 0.2f * x0;
  x1 = x1 >= 0.f ? x1 : 0.2f * x1;
  float eas0 = fexp(x0), eas1 = fexp(x1);
  den0 += eas0; den1 += eas1;
  uint4 qd = *(const uint4*)&h16[((long long)d << 6) | (tl << 2)];
  accA[0] += eas0 * bf_lo(qd.x); accB[0] += eas1 * bf_hi(qd.x);
  accA[1] += eas0 * bf_lo(qd.y); accB[1] += eas1 * bf_hi(qd.y);
  accA[2] += eas0 * bf_lo(qd.z); accB[2] += eas1 * bf_hi(qd.z);
  accA[3] += eas0 * bf_lo(qd.w); accB[3] += eas1 * bf_hi(qd.w);
  float rcp0 = frcp(den0 + 1e-16f), rcp1 = frcp(den1 + 1e-16f);
  float4 bs = *(const float4*)&bias[tl << 2];
  float v0 = 0.5f * (accA[0] * rcp0 + accB[0] * rcp1) + bs.x;
  float v1 = 0.5f * (accA[1] * rcp0 + accB[1] * rcp1) + bs.y;
  float v2 = 0.5f * (accA[2] * rcp0 + accB[2] * rcp1) + bs.z;
  float v3 = 0.5f * (accA[3] * rcp0 + accB[3] * rcp1) + bs.w;
  if (HEAD) {
    int c0 = tl << 2;
    float pv[7];
#pragma unroll
    for (int j = 0; j < 5; ++j)
      pv[j] = v0 * Wn[c0 * 5 + j] + v1 * Wn[(c0 + 1) * 5 + j]
            + v2 * Wn[(c0 + 2) * 5 + j] + v3 * Wn[(c0 + 3) * 5 + j];
    pv[5] = v0 * Wec[c0 * 2] + v1 * Wec[(c0 + 1) * 2]
          + v2 * Wec[(c0 + 2) * 2] + v3 * Wec[(c0 + 3) * 2];
    pv[6] = v0 * Wec[c0 * 2 + 1] + v1 * Wec[(c0 + 1) * 2 + 1]
          + v2 * Wec[(c0 + 2) * 2 + 1] + v3 * Wec[(c0 + 3) * 2 + 1];
    for (int off = 8; off; off >>= 1) {
#pragma unroll
      for (int j = 0; j < 7; ++j) pv[j] += __shfl_xor(pv[j], off);
    }
    if (tl == 0) {
      float l[5]; float m = -1e30f;
#pragma unroll
      for (int j = 0; j < 5; ++j) { l[j] = pv[j] + bn[j]; m = fmaxf(m, l[j]); }
      float ssum = 0.f;
#pragma unroll
      for (int j = 0; j < 5; ++j) { l[j] = fexp(l[j] - m); ssum += l[j]; }
      float inv = frcp(ssum);
#pragma unroll
      for (int j = 0; j < 5; ++j) p_n[5 * d + j] = l[j] * inv;
      float nab0 = (ssum - l[0]) * inv;
      fgn8[d] = make_int2(__float_as_int(pv[6] - pv[5]), (int)pack_bf2(nab0, 0.f));
    }
  } else {
    if (RELU) {
      v0 = fmaxf(v0, 0.f); v1 = fmaxf(v1, 0.f);
      v2 = fmaxf(v2, 0.f); v3 = fmaxf(v3, 0.f);
    }
    *(float4*)&out[(long long)d * 64 + (tl << 2)] = make_float4(v0, v1, v2, v3);
  }
}

// eab = c / (c + exp(-t)) : one rcp, shared structure.
__device__ __forceinline__ float fg_eab(float t, float c) {
  return c * frcp(c + fexp(-t));
}

// factor-graph node-pull iteration 1. FOUR LANES PER NODE (stride-4 edge split).
__global__ void k_fg_pull1(const int* __restrict__ rowptr_d, const int2* __restrict__ rec,
                           const int* __restrict__ rowptr_s, const int* __restrict__ srcnbr,
                           float* __restrict__ p_n, int2* __restrict__ fgn8,
                           const float* __restrict__ consts, int N, int E) {
  int gid = blockIdx.x * blockDim.x + threadIdx.x;
  int n = gid >> 2, q = gid & 3;
  if (n >= N) return;
  int2 F = fgn8[n];
  float qv = __uint_as_float((unsigned)F.x);
  float nab0 = bf_lo((unsigned)F.y);
  float avg_ef = consts[8], avg_nf = consts[9], dbec = consts[10];
  int rd0 = rowptr_d[n], rd1 = (n + 1 < N) ? rowptr_d[n + 1] : E;
  int rs0 = rowptr_s[n], rs1 = (n + 1 < N) ? rowptr_s[n + 1] : E;
  float s_eab = 0.f;
  for (int j = rd0 + q; j < rd1; j += 4) {
    int2 Fo = fgn8[rec[j].x];
    float t = 0.5f * (qv + __uint_as_float((unsigned)Fo.x)) + dbec;
    float c = 1.0f + fmaxf(nab0, bf_lo((unsigned)Fo.y)) * avg_ef;
    s_eab += fg_eab(t, c);
  }
  for (int j = rs0 + q; j < rs1; j += 4) {
    int2 Fo = fgn8[srcnbr[j]];
    float t = 0.5f * (qv + __uint_as_float((unsigned)Fo.x)) + dbec;
    float c = 1.0f + fmaxf(nab0, bf_lo((unsigned)Fo.y)) * avg_ef;
    s_eab += fg_eab(t, c);
  }
  s_eab += __shfl_xor(s_eab, 1);
  s_eab += __shfl_xor(s_eab, 2);
  if (q) return;
  float deg = (float)((rd1 - rd0) + (rs1 - rs0));
  float mean = s_eab * frcp(deg + 1e-6f);
  float f = 1.0f + mean * avg_nf;
  float p0 = p_n[5 * n], p1 = p_n[5 * n + 1], p2 = p_n[5 * n + 2],
        p3 = p_n[5 * n + 3], p4 = p_n[5 * n + 4];
  float rest = (p1 + p2 + p3 + p4) * f;
  float inv = frcp(p0 + rest);
  p_n[5 * n]     = p0 * inv;
  p_n[5 * n + 1] = p1 * f * inv;
  p_n[5 * n + 2] = p2 * f * inv;
  p_n[5 * n + 3] = p3 * f * inv;
  p_n[5 * n + 4] = p4 * f * inv;
  fgn8[n].y = (int)pack_bf2(nab0, rest * inv);
}

// merged final pass: blocks [0, nodeBlocks) = fg iteration 2 (4 lanes/node,
// writes out_n); blocks [nodeBlocks, ...) = edge output. Both only READ fgn8.
__global__ void k_fg_final(const int* __restrict__ rowptr_d, const int2* __restrict__ rec,
                           const int* __restrict__ rowptr_s, const int* __restrict__ srcnbr,
                           const float* __restrict__ p_n, const int2* __restrict__ fgn8,
                           const float* __restrict__ consts,
                           const int* __restrict__ src, const int* __restrict__ dst,
                           float* __restrict__ out_n, float* __restrict__ out_e,
                           int N, int E, int nodeBlocks) {
  float avg_ef = consts[8], dbec = consts[10];
  if ((int)blockIdx.x < nodeBlocks) {
    int gid = blockIdx.x * blockDim.x + threadIdx.x;
    int n = gid >> 2, q = gid & 3;
    if (n >= N) return;
    float avg_nf = consts[9];
    int2 F = fgn8[n];
    float qv = __uint_as_float((unsigned)F.x);
    float nab0 = bf_lo((unsigned)F.y), nab1 = bf_hi((unsigned)F.y);
    int rd0 = rowptr_d[n], rd1 = (n + 1 < N) ? rowptr_d[n + 1] : E;
    int rs0 = rowptr_s[n], rs1 = (n + 1 < N) ? rowptr_s[n + 1] : E;
    float s_eab = 0.f;
    for (int j = rd0 + q; j < rd1; j += 4) {
      int2 Fo = fgn8[rec[j].x];
      float t = 0.5f * (qv + __uint_as_float((unsigned)Fo.x)) + dbec;
      float c = (1.0f + fmaxf(nab0, bf_lo((unsigned)Fo.y)) * avg_ef)
              * (1.0f + fmaxf(nab1, bf_hi((unsigned)Fo.y)) * avg_ef);
      s_eab += fg_eab(t, c);
    }
    for (int j = rs0 + q; j < rs1; j += 4) {
      int2 Fo = fgn8[srcnbr[j]];
      float t = 0.5f * (qv + __uint_as_float((unsigned)Fo.x)) + dbec;
      float c = (1.0f + fmaxf(nab0, bf_lo((unsigned)Fo.y)) * avg_ef)
              * (1.0f + fmaxf(nab1, bf_hi((unsigned)Fo.y)) * avg_ef);
      s_eab += fg_eab(t, c);
    }
    s_eab += __shfl_xor(s_eab, 1);
    s_eab += __shfl_xor(s_eab, 2);
    if (q) return;
    float deg = (float)((rd1 - rd0) + (rs1 - rs0));
    float mean = s_eab * frcp(deg + 1e-6f);
    float f = 1.0f + mean * avg_nf;
    float p0 = p_n[5 * n], p1 = p_n[5 * n + 1], p2 = p_n[5 * n + 2],
          p3 = p_n[5 * n + 3], p4 = p_n[5 * n + 4];
    float rest = (p1 + p2 + p3 + p4) * f;
    float inv = frcp(p0 + rest);
    out_n[5 * n]     = flog(p0 * inv + 1e-9f);
    out_n[5 * n + 1] = flog(p1 * f * inv + 1e-9f);
    out_n[5 * n + 2] = flog(p2 * f * inv + 1e-9f);
    out_n[5 * n + 3] = flog(p3 * f * inv + 1e-9f);
    out_n[5 * n + 4] = flog(p4 * f * inv + 1e-9f);
  } else {
    int e = (blockIdx.x - nodeBlocks) * blockDim.x + threadIdx.x;
    if (e >= E) return;
    int2 Fs = fgn8[src[e]];
    int2 Fd = fgn8[dst[e]];
    float t = 0.5f * (__uint_as_float((unsigned)Fs.x) + __uint_as_float((unsigned)Fd.x)) + dbec;
    float c = (1.0f + fmaxf(bf_lo((unsigned)Fs.y), bf_lo((unsigned)Fd.y)) * avg_ef)
            * (1.0f + fmaxf(bf_hi((unsigned)Fs.y), bf_hi((unsigned)Fd.y)) * avg_ef);
    float ei = fexp(-t);
    float r = frcp(c + ei);
    float pe1 = c * r, pe0 = ei * r;
    *(float2*)&out_e[2 * e] = make_float2(flog(pe0 + 1e-9f), flog(pe1 + 1e-9f));
  }
}

extern "C" void kernel_launch(void* const* d_in, const int* in_sizes, int n_in,
                              void* d_out, int out_size, void* d_ws, size_t ws_size,
                              hipStream_t stream) {
  const float* x      = (const float*)d_in[0];
  const int*   ei     = (const int*)d_in[1];
  const float* eattr  = (const float*)d_in[2];
  const float* W1     = (const float*)d_in[3];
  const float* atts1  = (const float*)d_in[4];
  const float* attd1  = (const float*)d_in[5];
  const float* We1    = (const float*)d_in[6];
  const float* atte1  = (const float*)d_in[7];
  const float* b1     = (const float*)d_in[8];
  const float* W2     = (const float*)d_in[9];
  const float* atts2  = (const float*)d_in[10];
  const float* attd2  = (const float*)d_in[11];
  const float* We2    = (const float*)d_in[12];
  const float* atte2  = (const float*)d_in[13];
  const float* b2     = (const float*)d_in[14];
  const float* Wn     = (const float*)d_in[15];
  const float* bn     = (const float*)d_in[16];
  const float* Wec    = (const float*)d_in[17];
  const float* bec    = (const float*)d_in[18];
  const float* nodefw = (const float*)d_in[19];
  const float* edgefw = (const float*)d_in[20];

  const int N = in_sizes[0] / 128;
  const int E = in_sizes[1] / 2;
  const int* src = ei;
  const int* dst = ei + E;
  const int nbkt = (N + 255) >> BSH;   // 196 (assumes N <= 65536)

  float* out_n = (float*)d_out;
  float* out_e = out_n + (long long)N * 5;

  // ---- workspace carve (f32 units, 16B aligned) ----
  size_t off = 0;
  float* base = (float*)d_ws;
  auto carve = [&](size_t nelem) { float* p = base + off; off += (nelem + 3) & ~(size_t)3; return p; };
  unsigned* h16      = (unsigned*)carve((size_t)N * 64);  // aliases stage_d during prep
  float*    x2       = carve((size_t)N * 64);             // aliases stage_s during prep
  float*    asd      = carve((size_t)N * 4);
  int2*     rec      = (int2*)carve((size_t)E * 2);       // {src, bf16x2 eattr}
  int*      srcnbr   = (int*)carve((size_t)E);
  int*      rowptr_d = (int*)carve((size_t)N);
  int*      rowptr_s = (int*)carve((size_t)N);
  int*      bktcur_d = (int*)carve(256);
  int*      bktcur_s = (int*)carve(256);
  int*      bktbas_d = (int*)carve(260);
  int*      bktbas_s = (int*)carve(260);
  float*    p_n      = carve((size_t)N * 5);
  int2*     fgn8     = (int2*)carve((size_t)N * 2);
  float*    consts   = carve(16);
  unsigned short* wf1 = (unsigned short*)carve(9216);     // 4*9*512 bf16
  unsigned short* wf2 = (unsigned short*)carve(4608);     // 2*9*512 bf16
  if (off * sizeof(float) > ws_size) return;  // insufficient scratch: fail loudly

  // bucket staging aliases h16/x2 (CSR build completes before they're written):
  int4* stage_d = (int4*)h16;
  int2* stage_s = (int2*)x2;

  const int B = 256;
  const int gE  = cdiv_i(E, B);
  const int gN4 = cdiv_i((long long)N * 4, B);   // 4 lanes per node

  // ---- graph prep: merged prep (zeroes cursors) + bucketed CSR build ----
  k_prep<<<1, 256, 0, stream>>>(W1, atts1, attd1, atte1, We1,
                                W2, atts2, attd2, atte2, We2,
                                nodefw, edgefw, bec, consts, wf1, wf2,
                                bktcur_d, bktcur_s);
  k_bkt_hist<<<256, 256, 0, stream>>>(src, dst, bktcur_d, bktcur_s, nbkt, E);
  k_bkt_scan<<<1, 256, 0, stream>>>(bktcur_d, bktbas_d, bktcur_s, bktbas_s, nbkt);
  k_bkt_scatter<<<cdiv_i(E, 256 * CBK), 256, 0, stream>>>(src, dst, eattr, bktcur_d, bktcur_s,
                                                          stage_d, stage_s, nbkt, E);
  k_bkt_sort<<<2 * nbkt, 256, 0, stream>>>(stage_d, bktbas_d, rowptr_d, rec,
                                           stage_s, bktbas_s, rowptr_s, srcnbr, N, nbkt);

  // ---- GAT layer 1 (gemm writes h16+asd; pull writes x2) ----
  k_gemm_att_mfma<128><<<cdiv_i(N, 64), 256, 0, stream>>>(x, wf1, h16, asd, N);
  k_gat_pull<true, false><<<cdiv_i(N, 16), 256, 0, stream>>>(
      rowptr_d, rec, asd, h16, consts, b1,
      nullptr, nullptr, nullptr, x2, nullptr, nullptr, N, E);

  // ---- GAT layer 2 (+ fused heads) ----
  k_gemm_att_mfma<64><<<cdiv_i(N, 64), 256, 0, stream>>>(x2, wf2, h16, asd, N);
  k_gat_pull<false, true><<<cdiv_i(N, 16), 256, 0, stream>>>(
      rowptr_d, rec, asd, h16, consts + 4, b2,
      Wn, bn, Wec, nullptr, p_n, fgn8, N, E);

  // ---- factor graph: iter1 + merged (iter2 + edge output) ----
  k_fg_pull1<<<gN4, B, 0, stream>>>(rowptr_d, rec, rowptr_s, srcnbr,
                                    p_n, fgn8, consts, N, E);
  k_fg_final<<<gN4 + gE, B, 0, stream>>>(rowptr_d, rec, rowptr_s, srcnbr,
                                         p_n, fgn8, consts, src, dst,
                                         out_n, out_e, N, E, gN4);
}